// Round 1
// baseline (5516.996 us; speedup 1.0000x reference)
//
#include <hip/hip_runtime.h>
#include <hip/hip_bf16.h>
#include <math.h>

#define D_   512
#define F_   2048
#define V_   16384
#define H_   8
#define DH_  64
#define S_   512
#define B_   2
#define M_   1024            // B*S rows
#define MD_  (M_ * D_)       // 524288
#define MF_  (M_ * F_)       // 2097152
#define BHSS_ (B_ * H_ * S_ * S_)  // 4194304
#define GAMMA_ 0.1f
#define SCALE_ 0.125f        // 1/sqrt(64)

// ---------------- reduction helpers (blockDim.x == 256) ----------------
__device__ __forceinline__ float blk_sum(float v, float* sh) {
#pragma unroll
    for (int o = 32; o > 0; o >>= 1) v += __shfl_down(v, o, 64);
    int lane = threadIdx.x & 63, w = threadIdx.x >> 6;
    if (lane == 0) sh[w] = v;
    __syncthreads();
    float r = sh[0] + sh[1] + sh[2] + sh[3];
    __syncthreads();
    return r;
}

__device__ __forceinline__ float blk_max(float v, float* sh) {
#pragma unroll
    for (int o = 32; o > 0; o >>= 1) v = fmaxf(v, __shfl_down(v, o, 64));
    int lane = threadIdx.x & 63, w = threadIdx.x >> 6;
    if (lane == 0) sh[w] = v;
    __syncthreads();
    float r = fmaxf(fmaxf(sh[0], sh[1]), fmaxf(sh[2], sh[3]));
    __syncthreads();
    return r;
}

// ---------------- generic tiled GEMM ----------------
// C[m,n] = alpha * sum_k Aacc(m,k)*Bacc(k,n) (+ bias[n]) (+ C if acc)
// Aacc(m,k) = TA ? A[k*lda+m] : A[m*lda+k];  Bacc analogous.
// M,N multiples of 64; K multiple of 16 (no bounds checks). Grid: (N/64, M/64, batch)
template <int TA, int TB>
__global__ __launch_bounds__(256)
void gemm_kernel(const float* __restrict__ A, const float* __restrict__ B,
                 float* __restrict__ C, const float* __restrict__ bias,
                 int K, int lda, int ldb, int ldc,
                 int sA, int sB, int sC, float alpha, int acc)
{
    __shared__ float As[16][68];
    __shared__ float Bs[16][68];
    const int bz = blockIdx.z;
    A += (size_t)bz * sA;
    B += (size_t)bz * sB;
    C += (size_t)bz * sC;
    const int n0 = blockIdx.x * 64, m0 = blockIdx.y * 64;
    const int tid = threadIdx.x;
    const int tx = (tid & 15) << 2, ty = (tid >> 4) << 2;
    float acc4[4][4] = {{0.f}};

    for (int k0 = 0; k0 < K; k0 += 16) {
#pragma unroll
        for (int i = 0; i < 4; ++i) {
            int idx = tid + i * 256;
            if (TA == 0) {
                int kk = idx & 15, mm = idx >> 4;
                As[kk][mm] = A[(size_t)(m0 + mm) * lda + (k0 + kk)];
            } else {
                int mm = idx & 63, kk = idx >> 6;
                As[kk][mm] = A[(size_t)(k0 + kk) * lda + (m0 + mm)];
            }
            if (TB == 0) {
                int nn = idx & 63, kk = idx >> 6;
                Bs[kk][nn] = B[(size_t)(k0 + kk) * ldb + (n0 + nn)];
            } else {
                int kk = idx & 15, nn = idx >> 4;
                Bs[kk][nn] = B[(size_t)(n0 + nn) * ldb + (k0 + kk)];
            }
        }
        __syncthreads();
#pragma unroll
        for (int kk = 0; kk < 16; ++kk) {
            float4 av = *(const float4*)&As[kk][ty];
            float4 bv = *(const float4*)&Bs[kk][tx];
            acc4[0][0] += av.x * bv.x; acc4[0][1] += av.x * bv.y; acc4[0][2] += av.x * bv.z; acc4[0][3] += av.x * bv.w;
            acc4[1][0] += av.y * bv.x; acc4[1][1] += av.y * bv.y; acc4[1][2] += av.y * bv.z; acc4[1][3] += av.y * bv.w;
            acc4[2][0] += av.z * bv.x; acc4[2][1] += av.z * bv.y; acc4[2][2] += av.z * bv.z; acc4[2][3] += av.z * bv.w;
            acc4[3][0] += av.w * bv.x; acc4[3][1] += av.w * bv.y; acc4[3][2] += av.w * bv.z; acc4[3][3] += av.w * bv.w;
        }
        __syncthreads();
    }

#pragma unroll
    for (int i = 0; i < 4; ++i) {
        int m = m0 + ty + i;
#pragma unroll
        for (int j = 0; j < 4; ++j) {
            int n = n0 + tx + j;
            float v = alpha * acc4[i][j];
            if (bias) v += bias[n];
            size_t ci = (size_t)m * ldc + n;
            if (acc) v += C[ci];
            C[ci] = v;
        }
    }
}

// ---------------- LayerNorm forward (D=512, grid=rows, block=256) ----------------
__global__ __launch_bounds__(256)
void ln_fwd_kernel(const float* __restrict__ x, const float* __restrict__ s,
                   const float* __restrict__ bb, float* __restrict__ h)
{
    __shared__ float sh[4];
    int row = blockIdx.x, t = threadIdx.x;
    const float* xr = x + (size_t)row * D_;
    float x0 = xr[t], x1 = xr[t + 256];
    float m = blk_sum(x0 + x1, sh) * (1.f / D_);
    float d0 = x0 - m, d1 = x1 - m;
    float var = blk_sum(d0 * d0 + d1 * d1, sh) * (1.f / D_);
    float r = rsqrtf(var + 1e-5f);
    float* hr = h + (size_t)row * D_;
    hr[t]       = d0 * r * s[t]       + bb[t];
    hr[t + 256] = d1 * r * s[t + 256] + bb[t + 256];
}

// ---------------- causal softmax over rows of (B*H*S, S) ----------------
__global__ __launch_bounds__(256)
void softmax_causal_kernel(float* __restrict__ a)
{
    __shared__ float sh[4];
    int row = blockIdx.x, t = threadIdx.x;
    int q = row & (S_ - 1);
    float* p = a + (size_t)row * S_;
    int k1 = t + 256;
    float v0 = (t <= q)  ? p[t]  : -3.402823466e38f;
    float v1 = (k1 <= q) ? p[k1] : -3.402823466e38f;
    float mx = blk_max(fmaxf(v0, v1), sh);
    float e0 = (t <= q)  ? expf(v0 - mx) : 0.f;
    float e1 = (k1 <= q) ? expf(v1 - mx) : 0.f;
    float sm = blk_sum(e0 + e1, sh);
    float inv = 1.f / sm;
    p[t] = e0 * inv;
    p[k1] = e1 * inv;
}

// ---------------- layout permutes: (B,S,H,dh) <-> (B,H,S,dh), float4 over dh ----------------
__global__ void perm_to_bhsd(const float4* __restrict__ in, float4* __restrict__ o)
{
    int t = blockIdx.x * blockDim.x + threadIdx.x;   // B*S*H*16 = 131072
    int d4 = t & 15, r = t >> 4;
    int hh = r & (H_ - 1), r2 = r >> 3;
    int ss = r2 & (S_ - 1), bb = r2 >> 9;
    o[(((size_t)(bb * H_ + hh) * S_ + ss) << 4) + d4] =
        in[(((size_t)(bb * S_ + ss) * H_ + hh) << 4) + d4];
}

__global__ void perm_to_bshd(const float4* __restrict__ in, float4* __restrict__ o)
{
    int t = blockIdx.x * blockDim.x + threadIdx.x;
    int d4 = t & 15, r = t >> 4;
    int hh = r & (H_ - 1), r2 = r >> 3;
    int ss = r2 & (S_ - 1), bb = r2 >> 9;
    o[(((size_t)(bb * S_ + ss) * H_ + hh) << 4) + d4] =
        in[(((size_t)(bb * H_ + hh) * S_ + ss) << 4) + d4];
}

// ---------------- elementwise ----------------
__global__ void gelu_kernel(const float* __restrict__ p, float* __restrict__ o, int n)
{
    for (int i = blockIdx.x * blockDim.x + threadIdx.x; i < n; i += gridDim.x * blockDim.x) {
        float x = p[i];
        float u = 0.7978845608028654f * (x + 0.044715f * x * x * x);
        o[i] = 0.5f * x * (1.f + tanhf(u));
    }
}

__global__ void sub_kernel(float4* __restrict__ o, const float4* __restrict__ a,
                           const float4* __restrict__ b, int n4)
{
    for (int i = blockIdx.x * blockDim.x + threadIdx.x; i < n4; i += gridDim.x * blockDim.x) {
        float4 x = a[i], y = b[i];
        o[i] = make_float4(x.x - y.x, x.y - y.y, x.z - y.z, x.w - y.w);
    }
}

// o = a + GAMMA*(b - c)   (c may be null -> o = a + GAMMA*b)
__global__ void axpy_kernel(float4* __restrict__ o, const float4* __restrict__ a,
                            const float4* __restrict__ b, const float4* __restrict__ c, int n4)
{
    for (int i = blockIdx.x * blockDim.x + threadIdx.x; i < n4; i += gridDim.x * blockDim.x) {
        float4 av = a[i], bv = b[i], r;
        if (c) {
            float4 cv = c[i];
            r = make_float4(av.x + GAMMA_ * (bv.x - cv.x), av.y + GAMMA_ * (bv.y - cv.y),
                            av.z + GAMMA_ * (bv.z - cv.z), av.w + GAMMA_ * (bv.w - cv.w));
        } else {
            r = make_float4(av.x + GAMMA_ * bv.x, av.y + GAMMA_ * bv.y,
                            av.z + GAMMA_ * bv.z, av.w + GAMMA_ * bv.w);
        }
        o[i] = r;
    }
}

__global__ void embed_kernel(const float4* __restrict__ we, const float4* __restrict__ pe,
                             const int* __restrict__ ids, float4* __restrict__ o)
{
    int t = blockIdx.x * blockDim.x + threadIdx.x;  // 1024*128 = 131072
    int d4 = t & 127, row = t >> 7;
    int ss = row & (S_ - 1);
    int id = ids[row];
    id = id < 0 ? 0 : (id > V_ - 1 ? V_ - 1 : id);
    float4 a = we[(size_t)id * 128 + d4];
    float4 b = pe[(size_t)ss * 128 + d4];
    o[(size_t)row * 128 + d4] = make_float4(a.x + b.x, a.y + b.y, a.z + b.z, a.w + b.w);
}

__global__ void onehot_sub_kernel(float* __restrict__ logits, const int* __restrict__ tgt)
{
    int r = blockIdx.x * blockDim.x + threadIdx.x;
    if (r < M_) {
        int t = tgt[r];
        t = t < 0 ? 0 : (t > V_ - 1 ? V_ - 1 : t);
        logits[(size_t)r * V_ + t] -= 1.f;
    }
}

// ---------------- host orchestration ----------------
extern "C" void kernel_launch(void* const* d_in, const int* in_sizes, int n_in,
                              void* d_out, int out_size, void* d_ws, size_t ws_size,
                              hipStream_t stream)
{
    (void)in_sizes; (void)n_in; (void)out_size;
    const float* word_emb = (const float*)d_in[0];
    const float* pos_emb  = (const float*)d_in[1];
    const float* Wq  = (const float*)d_in[2];
    const float* Wk  = (const float*)d_in[3];
    const float* Wv  = (const float*)d_in[4];
    const float* bq  = (const float*)d_in[5];
    const float* bk  = (const float*)d_in[6];
    const float* bv  = (const float*)d_in[7];
    const float* Wo  = (const float*)d_in[8];
    const float* bo  = (const float*)d_in[9];
    const float* ln1_s = (const float*)d_in[10];
    const float* ln1_b = (const float*)d_in[11];
    const float* ln2_s = (const float*)d_in[12];
    const float* ln2_b = (const float*)d_in[13];
    const float* W1  = (const float*)d_in[14];
    const float* b1  = (const float*)d_in[15];
    const float* W2  = (const float*)d_in[16];
    const float* b2  = (const float*)d_in[17];
    const float* Wout = (const float*)d_in[18];
    const float* bout = (const float*)d_in[19];
    const int* input_ids  = (const int*)d_in[20];
    const int* target_ids = (const int*)d_in[21];
    float* out = (float*)d_out;

    // workspace carve-up (floats)
    float* w = (float*)d_ws;
    auto alloc = [&](size_t n) { float* p = w; w += n; return p; };
    float* mu_emb = alloc(MD_);
    float* bufA   = alloc(MF_);
    float* bufB   = alloc(MF_);
    float* x15    = alloc(MF_);
    float* x16    = alloc(MD_);
    float* hbuf   = alloc(MD_);
    float* tflat  = alloc(MD_);
    float* tq     = alloc(MD_);
    float* tk     = alloc(MD_);
    float* tv     = alloc(MD_);
    float* tctx   = alloc(MD_);
    float* attnA  = alloc(BHSS_);
    float* pre    = alloc(MF_);
    float* xA     = alloc(MD_);
    float* xB     = alloc(MD_);
    float* xC     = alloc(MD_);
    float* eb     = alloc(MD_);
    float* ec     = alloc(MD_);
    float* td     = alloc(MD_);
    float* mu16c  = alloc(MD_);
    float* tmpF   = alloc(MF_);
    float* x15b   = alloc(MF_);
    size_t need_bytes = (size_t)(w - (float*)d_ws) * sizeof(float);
    if (need_bytes > ws_size) return;  // ws too small: leaves d_out zeroed (diagnosable)

    auto gemm = [&](int TA, int TB, const float* A, const float* Bm, float* C, const float* bias,
                    int M, int N, int K, int lda, int ldb, int ldc,
                    int sA, int sB, int sC, int batch, float alpha, int acc) {
        dim3 g(N / 64, M / 64, batch), b(256);
        if (!TA && !TB)
            gemm_kernel<0, 0><<<g, b, 0, stream>>>(A, Bm, C, bias, K, lda, ldb, ldc, sA, sB, sC, alpha, acc);
        else if (!TA && TB)
            gemm_kernel<0, 1><<<g, b, 0, stream>>>(A, Bm, C, bias, K, lda, ldb, ldc, sA, sB, sC, alpha, acc);
        else
            gemm_kernel<1, 0><<<g, b, 0, stream>>>(A, Bm, C, bias, K, lda, ldb, ldc, sA, sB, sC, alpha, acc);
    };

    auto fwd_layer = [&](int l, const float* xin, float* mout) {
        int b = l >> 2, tt = l & 3;
        if (tt == 0) {  // attention
            ln_fwd_kernel<<<M_, 256, 0, stream>>>(xin, ln1_s + b * D_, ln1_b + b * D_, hbuf);
            gemm(0, 0, hbuf, Wq + (size_t)b * D_ * D_, tflat, bq + b * D_,
                 M_, D_, D_, D_, D_, D_, 0, 0, 0, 1, 1.f, 0);
            perm_to_bhsd<<<512, 256, 0, stream>>>((const float4*)tflat, (float4*)tq);
            gemm(0, 0, hbuf, Wk + (size_t)b * D_ * D_, tflat, bk + b * D_,
                 M_, D_, D_, D_, D_, D_, 0, 0, 0, 1, 1.f, 0);
            perm_to_bhsd<<<512, 256, 0, stream>>>((const float4*)tflat, (float4*)tk);
            gemm(0, 0, hbuf, Wv + (size_t)b * D_ * D_, tflat, bv + b * D_,
                 M_, D_, D_, D_, D_, D_, 0, 0, 0, 1, 1.f, 0);
            perm_to_bhsd<<<512, 256, 0, stream>>>((const float4*)tflat, (float4*)tv);
            // scores = scale * q @ k^T   per (b,h)
            gemm(0, 1, tq, tk, attnA, nullptr, S_, S_, DH_, DH_, DH_, S_,
                 S_ * DH_, S_ * DH_, S_ * S_, B_ * H_, SCALE_, 0);
            softmax_causal_kernel<<<B_ * H_ * S_, 256, 0, stream>>>(attnA);
            // ctx = a @ v
            gemm(0, 0, attnA, tv, tctx, nullptr, S_, DH_, S_, S_, DH_, DH_,
                 S_ * S_, S_ * DH_, S_ * DH_, B_ * H_, 1.f, 0);
            perm_to_bshd<<<512, 256, 0, stream>>>((const float4*)tctx, (float4*)mout);
        } else if (tt == 1) {  // x @ Wo + bo
            gemm(0, 0, xin, Wo + (size_t)b * D_ * D_, mout, bo + b * D_,
                 M_, D_, D_, D_, D_, D_, 0, 0, 0, 1, 1.f, 0);
        } else if (tt == 2) {  // gelu(LN(x) @ W1 + b1)
            ln_fwd_kernel<<<M_, 256, 0, stream>>>(xin, ln2_s + b * D_, ln2_b + b * D_, hbuf);
            gemm(0, 0, hbuf, W1 + (size_t)b * D_ * F_, pre, b1 + b * F_,
                 M_, F_, D_, D_, F_, F_, 0, 0, 0, 1, 1.f, 0);
            gelu_kernel<<<2048, 256, 0, stream>>>(pre, mout, MF_);
        } else {  // x @ W2 + b2
            gemm(0, 0, xin, W2 + (size_t)b * F_ * D_, mout, b2 + b * D_,
                 M_, D_, F_, F_, D_, D_, 0, 0, 0, 1, 1.f, 0);
        }
    };

    // ---- bottom prediction + forward sweep (xs[l+1] = g_l(xs[l])) ----
    embed_kernel<<<512, 256, 0, stream>>>((const float4*)word_emb, (const float4*)pos_emb,
                                          input_ids, (float4*)mu_emb);
    {
        const float* x = mu_emb;
        for (int l = 0; l < 16; ++l) {
            float* outp;
            if (l == 14) outp = x15;
            else if (l == 15) outp = x16;
            else outp = (l & 1) ? bufB : bufA;
            fwd_layer(l, x, outp);
            x = outp;
        }
    }

    // ---- exact PC tail (only nonzero-eps chain matters for T=3) ----
    auto top_fwd = [&](const float* x) {
        gemm(0, 0, x, Wout, out, bout, M_, V_, D_, D_, V_, V_, 0, 0, 0, 1, 1.f, 0);
    };
    auto top_vjp = [&](float* tdst) {  // td = (logits - onehot) @ Wout^T ; clobbers `out`
        onehot_sub_kernel<<<4, 256, 0, stream>>>(out, target_ids);
        gemm(0, 1, out, Wout, tdst, nullptr, M_, D_, V_, V_, V_, D_, 0, 0, 0, 1, 1.f, 0);
    };
    const int nMD4 = MD_ / 4, nMF4 = MF_ / 4;

    // iter 1: x16a = x16 + g*vjT(gtop(x16)-target)
    top_fwd(x16);
    top_vjp(td);
    axpy_kernel<<<512, 256, 0, stream>>>((float4*)xA, (const float4*)x16, (const float4*)td, nullptr, nMD4);
    // eps16 for iter 2 (= x16a - x16, since g15(x15) == x16 bit-exactly)
    sub_kernel<<<512, 256, 0, stream>>>((float4*)eb, (const float4*)xA, (const float4*)x16, nMD4);
    // iter 2: x16b = x16a + g*(vjT(...) - eps16) ; x15b = x15 + g*(eps16 @ W2[3]^T)
    top_fwd(xA);
    top_vjp(td);
    axpy_kernel<<<512, 256, 0, stream>>>((float4*)xB, (const float4*)xA, (const float4*)td, (const float4*)eb, nMD4);
    gemm(0, 1, eb, W2 + (size_t)3 * F_ * D_, tmpF, nullptr, M_, F_, D_, D_, D_, F_, 0, 0, 0, 1, 1.f, 0);
    axpy_kernel<<<2048, 256, 0, stream>>>((float4*)x15b, (const float4*)x15, (const float4*)tmpF, nullptr, nMF4);
    // iter 3: eps16' = x16b - g15(x15b); x16c = x16b + g*(vjT(...) - eps16')
    gemm(0, 0, x15b, W2 + (size_t)3 * F_ * D_, mu16c, b2 + 3 * D_, M_, D_, F_, F_, D_, D_, 0, 0, 0, 1, 1.f, 0);
    sub_kernel<<<512, 256, 0, stream>>>((float4*)ec, (const float4*)xB, (const float4*)mu16c, nMD4);
    top_fwd(xB);
    top_vjp(td);
    axpy_kernel<<<512, 256, 0, stream>>>((float4*)xC, (const float4*)xB, (const float4*)td, (const float4*)ec, nMD4);
    // final output: g_top(x16 after 3 updates)
    top_fwd(xC);
}

// Round 2
// 1021.917 us; speedup vs baseline: 5.3987x; 5.3987x over previous
//
#include <hip/hip_runtime.h>
#include <hip/hip_bf16.h>
#include <math.h>

#define D_   512
#define F_   2048
#define V_   16384
#define H_   8
#define DH_  64
#define S_   512
#define B_   2
#define M_   1024
#define MD_  (M_ * D_)
#define MF_  (M_ * F_)
#define BHSS_ (B_ * H_ * S_ * S_)
#define GAMMA_ 0.1f

typedef unsigned int u32;
typedef unsigned short u16;
typedef __attribute__((ext_vector_type(4))) float f32x4;
typedef __attribute__((ext_vector_type(8))) short s16x8;
typedef __attribute__((ext_vector_type(4))) u16 u16x4;

__device__ __forceinline__ u16 f2b(float f) {
    __hip_bfloat16 h = __float2bfloat16(f);   // RTNE
    return *reinterpret_cast<u16*>(&h);
}

__device__ __forceinline__ void gl_lds16(const void* g, void* l) {
    __builtin_amdgcn_global_load_lds((const __attribute__((address_space(1))) u32*)g,
                                     (__attribute__((address_space(3))) u32*)l, 16, 0, 0);
}

__device__ __forceinline__ float gelu_f(float v) {
    float u = 0.7978845608028654f * (v + 0.044715f * v * v * v);
    return 0.5f * v * (1.f + tanhf(u));
}

// block reduction helpers (blockDim.x == 256)
__device__ __forceinline__ float blk_sum(float v, float* sh) {
#pragma unroll
    for (int o = 32; o > 0; o >>= 1) v += __shfl_down(v, o, 64);
    int lane = threadIdx.x & 63, w = threadIdx.x >> 6;
    if (lane == 0) sh[w] = v;
    __syncthreads();
    float r = sh[0] + sh[1] + sh[2] + sh[3];
    __syncthreads();
    return r;
}
__device__ __forceinline__ float blk_max(float v, float* sh) {
#pragma unroll
    for (int o = 32; o > 0; o >>= 1) v = fmaxf(v, __shfl_down(v, o, 64));
    int lane = threadIdx.x & 63, w = threadIdx.x >> 6;
    if (lane == 0) sh[w] = v;
    __syncthreads();
    float r = fmaxf(fmaxf(sh[0], sh[1]), fmaxf(sh[2], sh[3]));
    __syncthreads();
    return r;
}

// ================= MFMA GEMM (NT: A is MxK row-major, B is NxK row-major, bf16) ===========
// C[m,n] = sum_k A[m,k]*B[n,k]. BK=32 per step. 256 threads = 4 waves.
// Epilogues:
#define E_F32   0   // Cf[m*ldc+n] = alpha*acc (+bias);  optional Cb (same layout)
#define E_QKV   1   // Cb at (B,H,S,dh) from (m=(b,s), n=(h,d)); +bias
#define E_VT    2   // Cb at (B,H,dh,S); +bias
#define E_CTX   3   // batched z=(b*8+h): Cb[(b*512+s)*512 + h*64 + d]
#define E_GELU  4   // g=gelu(acc+bias): Cf (optional) and Cb, layout m*ldc+n
#define E_TD    5   // o = base + 0.1*(acc + cvec[n] - woutF[n*V + tcl[m]] - subv); Cf opt, Cb
#define E_X15B  6   // Cb = bf16(base + 0.1*acc)
#define E_EC    7   // Cf = base - (acc + bias[n])

template<int BM, int BN, int FM, int FN, int EPI>
__global__ __launch_bounds__(256)
void mfma_gemm(const u16* __restrict__ A, const u16* __restrict__ B,
               float* __restrict__ Cf, u16* __restrict__ Cb,
               const float* __restrict__ bias,
               int K, int lda, int ldb, int ldc,
               long sA, long sB, long sC, long sKz, float alpha,
               const float* __restrict__ base, const float* __restrict__ subv,
               const float* __restrict__ cvec, const float* __restrict__ woutF,
               const int* __restrict__ tcl)
{
    constexpr int WC = BN / (FN * 16);
    static_assert((BM / (FM * 16)) * WC == 4, "4 waves");
    __shared__ __align__(16) u16 Asl[BM * 32];
    __shared__ __align__(16) u16 Bsl[BN * 32];
    const int t = threadIdx.x, l = t & 63, wid = t >> 6;
    const int m0 = blockIdx.y * BM, n0 = blockIdx.x * BN;
    const long z = blockIdx.z;
    A += z * sA + z * sKz;
    B += z * sB + z * sKz;
    if (Cf) Cf += z * sC;

    f32x4 acc[FM][FN] = {};
    const int rm = (wid / WC) * (FM * 16), cn = (wid % WC) * (FN * 16);
    const int kb = (l >> 4) * 8;        // k-offset within 32 for this lane
    const int lr = l & 15;              // fragment row/col index

    for (int k0 = 0; k0 < K; k0 += 32) {
#pragma unroll
        for (int i = 0; i < BM / 64; ++i)
            gl_lds16(A + (size_t)(m0 + i * 64 + (t >> 2)) * lda + k0 + (t & 3) * 8,
                     &Asl[(i * 64 + (t >> 2)) * 32 + (t & 3) * 8]);
#pragma unroll
        for (int i = 0; i < BN / 64; ++i)
            gl_lds16(B + (size_t)(n0 + i * 64 + (t >> 2)) * ldb + k0 + (t & 3) * 8,
                     &Bsl[(i * 64 + (t >> 2)) * 32 + (t & 3) * 8]);
        __syncthreads();
        s16x8 av[FM], bv[FN];
#pragma unroll
        for (int fm = 0; fm < FM; ++fm)
            av[fm] = *(const s16x8*)&Asl[(rm + fm * 16 + lr) * 32 + kb];
#pragma unroll
        for (int fn = 0; fn < FN; ++fn)
            bv[fn] = *(const s16x8*)&Bsl[(cn + fn * 16 + lr) * 32 + kb];
#pragma unroll
        for (int fm = 0; fm < FM; ++fm)
#pragma unroll
            for (int fn = 0; fn < FN; ++fn)
                acc[fm][fn] = __builtin_amdgcn_mfma_f32_16x16x32_bf16(av[fm], bv[fn], acc[fm][fn], 0, 0, 0);
        __syncthreads();
    }

    // epilogue: C/D frag layout col = l&15, row = (l>>4)*4 + r   [m89-verified]
#pragma unroll
    for (int fm = 0; fm < FM; ++fm)
#pragma unroll
        for (int fn = 0; fn < FN; ++fn)
#pragma unroll
            for (int r = 0; r < 4; ++r) {
                const int gm = m0 + rm + fm * 16 + (l >> 4) * 4 + r;
                const int gn = n0 + cn + fn * 16 + lr;
                float v = acc[fm][fn][r];
                if constexpr (EPI == E_F32) {
                    v *= alpha;
                    if (bias) v += bias[gn];
                    size_t idx = (size_t)gm * ldc + gn;
                    Cf[idx] = v;
                    if (Cb) Cb[idx] = f2b(v);
                } else if constexpr (EPI == E_QKV) {
                    v += bias[gn];
                    int b = gm >> 9, s = gm & (S_ - 1), h = gn >> 6, d = gn & 63;
                    Cb[(((size_t)(b * H_ + h) * S_ + s) << 6) + d] = f2b(v);
                } else if constexpr (EPI == E_VT) {
                    v += bias[gn];
                    int b = gm >> 9, s = gm & (S_ - 1), h = gn >> 6, d = gn & 63;
                    Cb[(((size_t)(b * H_ + h) * DH_ + d) << 9) + s] = f2b(v);
                } else if constexpr (EPI == E_CTX) {
                    int b = (int)(z >> 3), h = (int)(z & 7);
                    Cb[((size_t)(b * S_ + gm) * D_) + h * DH_ + gn] = f2b(v);
                } else if constexpr (EPI == E_GELU) {
                    v += bias[gn];
                    float g = gelu_f(v);
                    size_t idx = (size_t)gm * ldc + gn;
                    if (Cf) Cf[idx] = g;
                    Cb[idx] = f2b(g);
                } else if constexpr (EPI == E_TD) {
                    size_t idx = (size_t)gm * ldc + gn;
                    float o = base[idx] + GAMMA_ * (v + cvec[gn]
                              - woutF[(size_t)gn * V_ + tcl[gm]]
                              - (subv ? subv[idx] : 0.f));
                    if (Cf) Cf[idx] = o;
                    Cb[idx] = f2b(o);
                } else if constexpr (EPI == E_X15B) {
                    size_t idx = (size_t)gm * ldc + gn;
                    Cb[idx] = f2b(base[idx] + GAMMA_ * v);
                } else if constexpr (EPI == E_EC) {
                    size_t idx = (size_t)gm * ldc + gn;
                    Cf[idx] = base[idx] - (v + bias[gn]);
                }
            }
}

// ============ converters / small kernels ============
// f32 (R x C, +z*R*C) -> bf16 transposed (C x R, +z*R*C)
__global__ __launch_bounds__(256)
void transpose_cvt(const float* __restrict__ in, u16* __restrict__ out, int R, int C)
{
    __shared__ float tile[32][33];
    long z = blockIdx.z;
    in += z * (long)R * C; out += z * (long)R * C;
    int c0 = blockIdx.x * 32, r0 = blockIdx.y * 32;
    int tr = threadIdx.x >> 3, tc4 = (threadIdx.x & 7) * 4;
    const float4 v = *(const float4*)&in[(size_t)(r0 + tr) * C + c0 + tc4];
    tile[tr][tc4 + 0] = v.x; tile[tr][tc4 + 1] = v.y;
    tile[tr][tc4 + 2] = v.z; tile[tr][tc4 + 3] = v.w;
    __syncthreads();
    u16x4 o;
    o.x = f2b(tile[tc4 + 0][tr]); o.y = f2b(tile[tc4 + 1][tr]);
    o.z = f2b(tile[tc4 + 2][tr]); o.w = f2b(tile[tc4 + 3][tr]);
    *(u16x4*)&out[(size_t)(c0 + tr) * R + r0 + tc4] = o;
}

__global__ void cvt_bf16(const float4* __restrict__ in, u16* __restrict__ out, int n4)
{
    for (int i = blockIdx.x * blockDim.x + threadIdx.x; i < n4; i += gridDim.x * blockDim.x) {
        float4 v = in[i];
        u16x4 o; o.x = f2b(v.x); o.y = f2b(v.y); o.z = f2b(v.z); o.w = f2b(v.w);
        *(u16x4*)&out[i * 4] = o;
    }
}

__global__ __launch_bounds__(256)
void cvec_kernel(const float* __restrict__ Wout, const float* __restrict__ bout,
                 float* __restrict__ c)
{
    __shared__ float sh[4];
    int d = blockIdx.x;
    const float* row = Wout + (size_t)d * V_;
    float s = 0.f;
    for (int v = threadIdx.x * 4; v < V_; v += 1024) {
        float4 a = *(const float4*)&row[v];
        float4 b = *(const float4*)&bout[v];
        s += a.x * b.x + a.y * b.y + a.z * b.z + a.w * b.w;
    }
    float r = blk_sum(s, sh);
    if (threadIdx.x == 0) c[d] = r;
}

__global__ void gred_kernel(const float* __restrict__ P, u16* __restrict__ G)
{
    int i = blockIdx.x * blockDim.x + threadIdx.x;
    if (i < D_ * D_) {
        float s = 0.f;
#pragma unroll
        for (int zz = 0; zz < 8; ++zz) s += P[(size_t)zz * D_ * D_ + i];
        G[i] = f2b(s);
    }
}

__global__ void tclip_k(const int* __restrict__ t, int* __restrict__ o)
{
    int i = blockIdx.x * blockDim.x + threadIdx.x;
    if (i < M_) { int v = t[i]; o[i] = v < 0 ? 0 : (v > V_ - 1 ? V_ - 1 : v); }
}

__global__ void embed_kernel(const float4* __restrict__ we, const float4* __restrict__ pe,
                             const int* __restrict__ ids, float4* __restrict__ o)
{
    int t = blockIdx.x * blockDim.x + threadIdx.x;  // M*128
    int d4 = t & 127, row = t >> 7;
    int ss = row & (S_ - 1);
    int id = ids[row];
    id = id < 0 ? 0 : (id > V_ - 1 ? V_ - 1 : id);
    float4 a = we[(size_t)id * 128 + d4];
    float4 b = pe[(size_t)ss * 128 + d4];
    o[(size_t)row * 128 + d4] = make_float4(a.x + b.x, a.y + b.y, a.z + b.z, a.w + b.w);
}

__global__ __launch_bounds__(256)
void ln_fwd_kernel(const float* __restrict__ x, const float* __restrict__ s,
                   const float* __restrict__ bb, u16* __restrict__ h)
{
    __shared__ float sh[4];
    int row = blockIdx.x, t = threadIdx.x;
    const float* xr = x + (size_t)row * D_;
    float x0 = xr[t], x1 = xr[t + 256];
    float m = blk_sum(x0 + x1, sh) * (1.f / D_);
    float d0 = x0 - m, d1 = x1 - m;
    float var = blk_sum(d0 * d0 + d1 * d1, sh) * (1.f / D_);
    float r = rsqrtf(var + 1e-5f);
    u16* hr = h + (size_t)row * D_;
    hr[t]       = f2b(d0 * r * s[t]       + bb[t]);
    hr[t + 256] = f2b(d1 * r * s[t + 256] + bb[t + 256]);
}

__global__ __launch_bounds__(256)
void softmax_causal_kernel(const float* __restrict__ a, u16* __restrict__ p)
{
    __shared__ float sh[4];
    int row = blockIdx.x, t = threadIdx.x;
    int q = row & (S_ - 1);
    const float* ar = a + (size_t)row * S_;
    u16* pr = p + (size_t)row * S_;
    int k1 = t + 256;
    float v0 = (t <= q)  ? ar[t]  : -3.402823466e38f;
    float v1 = (k1 <= q) ? ar[k1] : -3.402823466e38f;
    float mx = blk_max(fmaxf(v0, v1), sh);
    float e0 = (t <= q)  ? expf(v0 - mx) : 0.f;
    float e1 = (k1 <= q) ? expf(v1 - mx) : 0.f;
    float sm = blk_sum(e0 + e1, sh);
    float inv = 1.f / sm;
    pr[t]  = f2b(e0 * inv);
    pr[k1] = f2b(e1 * inv);
}

// eb = a - b (f32), eb_b = bf16(eb)
__global__ void sub_fused_kernel(const float4* __restrict__ a, const float4* __restrict__ b,
                                 float4* __restrict__ o, u16* __restrict__ ob, int n4)
{
    for (int i = blockIdx.x * blockDim.x + threadIdx.x; i < n4; i += gridDim.x * blockDim.x) {
        float4 x = a[i], y = b[i];
        float4 r = make_float4(x.x - y.x, x.y - y.y, x.z - y.z, x.w - y.w);
        o[i] = r;
        u16x4 ov; ov.x = f2b(r.x); ov.y = f2b(r.y); ov.z = f2b(r.z); ov.w = f2b(r.w);
        *(u16x4*)&ob[i * 4] = ov;
    }
}

// ================= host =================
extern "C" void kernel_launch(void* const* d_in, const int* in_sizes, int n_in,
                              void* d_out, int out_size, void* d_ws, size_t ws_size,
                              hipStream_t stream)
{
    (void)in_sizes; (void)n_in; (void)out_size;
    const float* Wq  = (const float*)d_in[2];
    const float* Wk  = (const float*)d_in[3];
    const float* Wv  = (const float*)d_in[4];
    const float* bq  = (const float*)d_in[5];
    const float* bk  = (const float*)d_in[6];
    const float* bv  = (const float*)d_in[7];
    const float* Wo  = (const float*)d_in[8];
    const float* bo  = (const float*)d_in[9];
    const float* ln1_s = (const float*)d_in[10];
    const float* ln1_b = (const float*)d_in[11];
    const float* ln2_s = (const float*)d_in[12];
    const float* ln2_b = (const float*)d_in[13];
    const float* W1  = (const float*)d_in[14];
    const float* b1  = (const float*)d_in[15];
    const float* W2  = (const float*)d_in[16];
    const float* b2  = (const float*)d_in[17];
    const float* Wout = (const float*)d_in[18];
    const float* bout = (const float*)d_in[19];
    const int* input_ids  = (const int*)d_in[20];
    const int* target_ids = (const int*)d_in[21];
    float* out = (float*)d_out;

    // ---- workspace carve (persistent + union region) ----
    char* wsb = (char*)d_ws;
    size_t off = 0;
    auto alloc = [&](size_t bytes) -> void* {
        off = (off + 255) & ~(size_t)255;
        void* p = wsb + off; off += bytes; return p;
    };
    u16* wqT   = (u16*)alloc((size_t)4 * D_ * D_ * 2);
    u16* wkT   = (u16*)alloc((size_t)4 * D_ * D_ * 2);
    u16* wvT   = (u16*)alloc((size_t)4 * D_ * D_ * 2);
    u16* woT   = (u16*)alloc((size_t)4 * D_ * D_ * 2);
    u16* w1T   = (u16*)alloc((size_t)4 * D_ * F_ * 2);
    u16* w2T   = (u16*)alloc((size_t)4 * D_ * F_ * 2);
    u16* w2d   = (u16*)alloc((size_t)F_ * D_ * 2);
    u16* woutT = (u16*)alloc((size_t)V_ * D_ * 2);
    u16* G_b   = (u16*)alloc((size_t)D_ * D_ * 2);
    float* bufA = (float*)alloc((size_t)MF_ * 4);
    float* bufB = (float*)alloc((size_t)MD_ * 4);
    u16* h_b    = (u16*)alloc((size_t)MD_ * 2);
    u16* gelu_b = (u16*)alloc((size_t)MF_ * 2);
    u16* x16_b  = (u16*)alloc((size_t)MD_ * 2);
    float* cvec = (float*)alloc(D_ * 4);
    int* tcl    = (int*)alloc(M_ * 4);
    size_t uStart = (off + 255) & ~(size_t)255;
    // phase G
    off = uStart;
    u16* woutD  = (u16*)alloc((size_t)V_ * D_ * 2);
    float* Gpart = (float*)alloc((size_t)8 * D_ * D_ * 4);
    size_t endG = off;
    // phase attention
    off = uStart;
    float* attnA = (float*)alloc((size_t)BHSS_ * 4);
    u16* probs   = (u16*)alloc((size_t)BHSS_ * 2);
    u16* q_b     = (u16*)alloc((size_t)MD_ * 2);
    u16* k_b     = (u16*)alloc((size_t)MD_ * 2);
    u16* v_b     = (u16*)alloc((size_t)MD_ * 2);
    u16* ctx_b   = (u16*)alloc((size_t)MD_ * 2);
    size_t endA = off;
    // phase tail
    off = uStart;
    float* xA  = (float*)alloc((size_t)MD_ * 4);
    float* xB  = (float*)alloc((size_t)MD_ * 4);
    float* eb  = (float*)alloc((size_t)MD_ * 4);
    float* ec  = (float*)alloc((size_t)MD_ * 4);
    u16* xA_b  = (u16*)alloc((size_t)MD_ * 2);
    u16* xB_b  = (u16*)alloc((size_t)MD_ * 2);
    u16* xC_b  = (u16*)alloc((size_t)MD_ * 2);
    u16* eb_b  = (u16*)alloc((size_t)MD_ * 2);
    u16* x15b_b = (u16*)alloc((size_t)MF_ * 2);
    size_t endT = off;
    size_t need = endG > endA ? endG : endA;
    if (endT > need) need = endT;
    if (need > ws_size) return;  // loud failure (d_out stays poisoned)

    dim3 blk(256);

    // ---- one-time precompute ----
    tclip_k<<<dim3(4), blk, 0, stream>>>(target_ids, tcl);
    cvec_kernel<<<dim3(D_), blk, 0, stream>>>(Wout, bout, cvec);
    transpose_cvt<<<dim3(16, 16, 4), blk, 0, stream>>>(Wq, wqT, D_, D_);
    transpose_cvt<<<dim3(16, 16, 4), blk, 0, stream>>>(Wk, wkT, D_, D_);
    transpose_cvt<<<dim3(16, 16, 4), blk, 0, stream>>>(Wv, wvT, D_, D_);
    transpose_cvt<<<dim3(16, 16, 4), blk, 0, stream>>>(Wo, woT, D_, D_);
    transpose_cvt<<<dim3(64, 16, 4), blk, 0, stream>>>(W1, w1T, D_, F_);
    transpose_cvt<<<dim3(16, 64, 4), blk, 0, stream>>>(W2, w2T, F_, D_);
    transpose_cvt<<<dim3(512, 16, 1), blk, 0, stream>>>(Wout, woutT, D_, V_);
    cvt_bf16<<<dim3(1024), blk, 0, stream>>>((const float4*)(W2 + (size_t)3 * F_ * D_), w2d, F_ * D_ / 4);
    cvt_bf16<<<dim3(2048), blk, 0, stream>>>((const float4*)Wout, woutD, V_ * D_ / 4);
    // G = Wout @ Wout^T via split-K(8 x 2048), then reduce to bf16
    mfma_gemm<128, 128, 4, 4, E_F32><<<dim3(4, 4, 8), blk, 0, stream>>>(
        woutD, woutD, Gpart, nullptr, nullptr, 2048, V_, V_, D_,
        0, 0, (long)D_ * D_, 2048, 1.f, nullptr, nullptr, nullptr, nullptr, nullptr);
    gred_kernel<<<dim3(1024), blk, 0, stream>>>(Gpart, G_b);

    // ---- forward sweep ----
    embed_kernel<<<dim3(512), blk, 0, stream>>>((const float4*)d_in[0], (const float4*)d_in[1],
                                                input_ids, (float4*)bufB);
    for (int b = 0; b < 4; ++b) {
        const size_t wDD = (size_t)b * D_ * D_, wDF = (size_t)b * D_ * F_;
        // --- attention: x in bufB ---
        ln_fwd_kernel<<<dim3(M_), blk, 0, stream>>>(bufB, ln1_s + b * D_, ln1_b + b * D_, h_b);
        mfma_gemm<128, 128, 4, 4, E_QKV><<<dim3(4, 8, 1), blk, 0, stream>>>(
            h_b, wqT + wDD, nullptr, q_b, bq + b * D_, D_, D_, D_, 0,
            0, 0, 0, 0, 1.f, nullptr, nullptr, nullptr, nullptr, nullptr);
        mfma_gemm<128, 128, 4, 4, E_QKV><<<dim3(4, 8, 1), blk, 0, stream>>>(
            h_b, wkT + wDD, nullptr, k_b, bk + b * D_, D_, D_, D_, 0,
            0, 0, 0, 0, 1.f, nullptr, nullptr, nullptr, nullptr, nullptr);
        mfma_gemm<128, 128, 4, 4, E_VT><<<dim3(4, 8, 1), blk, 0, stream>>>(
            h_b, wvT + wDD, nullptr, v_b, bv + b * D_, D_, D_, D_, 0,
            0, 0, 0, 0, 1.f, nullptr, nullptr, nullptr, nullptr, nullptr);
        // scores = 0.125 * q @ k^T (batched over B*H)
        mfma_gemm<128, 128, 4, 4, E_F32><<<dim3(4, 4, 16), blk, 0, stream>>>(
            q_b, k_b, attnA, nullptr, nullptr, DH_, DH_, DH_, S_,
            (long)S_ * DH_, (long)S_ * DH_, (long)S_ * S_, 0, 0.125f,
            nullptr, nullptr, nullptr, nullptr, nullptr);
        softmax_causal_kernel<<<dim3(B_ * H_ * S_), blk, 0, stream>>>(attnA, probs);
        // ctx = probs @ v  (B = v^T per head), fused permute to (B,S,D) bf16
        mfma_gemm<128, 64, 4, 2, E_CTX><<<dim3(1, 4, 16), blk, 0, stream>>>(
            probs, v_b, nullptr, ctx_b, nullptr, S_, S_, S_, 0,
            (long)S_ * S_, (long)S_ * DH_, 0, 0, 1.f, nullptr, nullptr, nullptr, nullptr, nullptr);
        // x2 = ctx @ Wo + bo  -> bufB (f32)
        mfma_gemm<128, 128, 4, 4, E_F32><<<dim3(4, 8, 1), blk, 0, stream>>>(
            ctx_b, woT + wDD, bufB, nullptr, bo + b * D_, D_, D_, D_, D_,
            0, 0, 0, 0, 1.f, nullptr, nullptr, nullptr, nullptr, nullptr);
        // --- FFN ---
        ln_fwd_kernel<<<dim3(M_), blk, 0, stream>>>(bufB, ln2_s + b * D_, ln2_b + b * D_, h_b);
        // x3 = gelu(h @ W1 + b1): bf16 always; f32 copy only needed for b==3 (x15)
        mfma_gemm<128, 128, 4, 4, E_GELU><<<dim3(16, 8, 1), blk, 0, stream>>>(
            h_b, w1T + wDF, (b == 3) ? bufA : nullptr, gelu_b, b1 + b * F_, D_, D_, D_, F_,
            0, 0, 0, 0, 1.f, nullptr, nullptr, nullptr, nullptr, nullptr);
        // x4 = x3 @ W2 + b2 -> bufB (f32); b==3 also writes x16 bf16
        mfma_gemm<128, 128, 4, 4, E_F32><<<dim3(4, 8, 1), blk, 0, stream>>>(
            gelu_b, w2T + wDF, bufB, (b == 3) ? x16_b : nullptr, b2 + b * D_, F_, F_, F_, D_,
            0, 0, 0, 0, 1.f, nullptr, nullptr, nullptr, nullptr, nullptr);
    }
    // now: x15 f32 = bufA, x16 f32 = bufB, x16 bf16 = x16_b

    // ---- PC tail (exact: only top-layer eps chain is nonzero for T=3) ----
    const int nMD4 = MD_ / 4;
    // iter 1: xA = x16 + g*(x16@G + cvec - gather(Wout[:,t]))
    mfma_gemm<128, 128, 4, 4, E_TD><<<dim3(4, 8, 1), blk, 0, stream>>>(
        x16_b, G_b, xA, xA_b, nullptr, D_, D_, D_, D_,
        0, 0, 0, 0, 1.f, bufB, nullptr, cvec, Wout, tcl);
    // eb = xA - x16
    sub_fused_kernel<<<dim3(512), blk, 0, stream>>>((const float4*)xA, (const float4*)bufB,
                                                    (float4*)eb, eb_b, nMD4);
    // iter 2: xB = xA + g*(xA@G + cvec - gth - eb)
    mfma_gemm<128, 128, 4, 4, E_TD><<<dim3(4, 8, 1), blk, 0, stream>>>(
        xA_b, G_b, xB, xB_b, nullptr, D_, D_, D_, D_,
        0, 0, 0, 0, 1.f, xA, eb, cvec, Wout, tcl);
    // x15b = x15 + g*(eb @ W2[3]^T)   (bf16 only)
    mfma_gemm<128, 128, 4, 4, E_X15B><<<dim3(16, 8, 1), blk, 0, stream>>>(
        eb_b, w2d, nullptr, x15b_b, nullptr, D_, D_, D_, F_,
        0, 0, 0, 0, 1.f, bufA, nullptr, nullptr, nullptr, nullptr);
    // ec = xB - (x15b @ W2[3] + b2[3])
    mfma_gemm<128, 128, 4, 4, E_EC><<<dim3(4, 8, 1), blk, 0, stream>>>(
        x15b_b, w2T + (size_t)3 * D_ * F_, ec, nullptr, b2 + 3 * D_, F_, F_, F_, D_,
        0, 0, 0, 0, 1.f, xB, nullptr, nullptr, nullptr, nullptr);
    // iter 3: xC = xB + g*(xB@G + cvec - gth - ec)   (bf16 only)
    mfma_gemm<128, 128, 4, 4, E_TD><<<dim3(4, 8, 1), blk, 0, stream>>>(
        xB_b, G_b, nullptr, xC_b, nullptr, D_, D_, D_, D_,
        0, 0, 0, 0, 1.f, xB, ec, cvec, Wout, tcl);
    // final: out = xC @ Wout + bout
    mfma_gemm<128, 128, 4, 4, E_F32><<<dim3(128, 8, 1), blk, 0, stream>>>(
        xC_b, woutT, out, nullptr, bout, D_, D_, D_, V_,
        0, 0, 0, 0, 1.f, nullptr, nullptr, nullptr, nullptr, nullptr);
}

// Round 3
// 658.694 us; speedup vs baseline: 8.3757x; 1.5514x over previous
//
#include <hip/hip_runtime.h>
#include <hip/hip_bf16.h>
#include <math.h>

#define D_   512
#define F_   2048
#define V_   16384
#define H_   8
#define DH_  64
#define S_   512
#define B_   2
#define M_   1024
#define MD_  (M_ * D_)
#define MF_  (M_ * F_)
#define GAMMA_ 0.1f

typedef unsigned int u32;
typedef unsigned short u16;
typedef __attribute__((ext_vector_type(4))) float f32x4;
typedef __attribute__((ext_vector_type(8))) short s16x8;
typedef __attribute__((ext_vector_type(4))) u16 u16x4;

__device__ __forceinline__ u16 f2b(float f) {
    __hip_bfloat16 h = __float2bfloat16(f);   // RTNE
    return *reinterpret_cast<u16*>(&h);
}

__device__ __forceinline__ void gl_lds16(const void* g, void* l) {
    __builtin_amdgcn_global_load_lds((const __attribute__((address_space(1))) u32*)g,
                                     (__attribute__((address_space(3))) u32*)l, 16, 0, 0);
}

__device__ __forceinline__ float gelu_f(float v) {
    float u = 0.7978845608028654f * (v + 0.044715f * v * v * v);
    return 0.5f * v * (1.f + tanhf(u));
}

// block reduction helpers (blockDim.x == 256)
__device__ __forceinline__ float blk_sum(float v, float* sh) {
#pragma unroll
    for (int o = 32; o > 0; o >>= 1) v += __shfl_down(v, o, 64);
    int lane = threadIdx.x & 63, w = threadIdx.x >> 6;
    if (lane == 0) sh[w] = v;
    __syncthreads();
    float r = sh[0] + sh[1] + sh[2] + sh[3];
    __syncthreads();
    return r;
}

// ================= MFMA GEMM (NT: A is MxK row-major, B is NxK row-major, bf16) ===========
#define E_F32   0   // Cf = acc*alpha (+bias); optional Cb
#define E_GELU  1   // g=gelu(acc+bias): Cf (optional) and Cb
#define E_TD    2   // dlt=g*(acc+cvec[n]-woutF[n*V+tcl[m]]-subv); o=base+dlt; Cf?,Cb; ebF?,ebB?=dlt
#define E_X15B  3   // Cb = bf16(base + g*acc)
#define E_EC    4   // Cf = base - (acc + bias[n])
#define E_QKV3  5   // fused QKV scatter: n<512->Q(B,H,S,dh), <1024->K, else->V^T(B,H,dh,S); +bias

template<int BM, int BN, int FM, int FN, int EPI>
__global__ __launch_bounds__(256)
void mfma_gemm(const u16* __restrict__ A, const u16* __restrict__ B,
               float* __restrict__ Cf, u16* __restrict__ Cb,
               u16* __restrict__ Cb2, u16* __restrict__ Cb3,
               const float* __restrict__ bias,
               int K, int lda, int ldb, int ldc,
               long sC, long sKz, float alpha,
               const float* __restrict__ base, const float* __restrict__ subv,
               const float* __restrict__ cvec, const float* __restrict__ woutF,
               const int* __restrict__ tcl,
               float* __restrict__ ebF, u16* __restrict__ ebB)
{
    constexpr int WC = BN / (FN * 16);
    static_assert((BM / (FM * 16)) * WC == 4, "4 waves");
    __shared__ __align__(16) u16 Asl[BM * 32];
    __shared__ __align__(16) u16 Bsl[BN * 32];
    const int t = threadIdx.x, l = t & 63, wid = t >> 6;
    const int m0 = blockIdx.y * BM, n0 = blockIdx.x * BN;
    const long z = blockIdx.z;
    A += z * sKz;
    B += z * sKz;
    if (Cf) Cf += z * sC;

    f32x4 acc[FM][FN] = {};
    const int rm = (wid / WC) * (FM * 16), cn = (wid % WC) * (FN * 16);
    const int kb = (l >> 4) * 8;
    const int lr = l & 15;

    for (int k0 = 0; k0 < K; k0 += 32) {
#pragma unroll
        for (int i = 0; i < BM / 64; ++i)
            gl_lds16(A + (size_t)(m0 + i * 64 + (t >> 2)) * lda + k0 + (t & 3) * 8,
                     &Asl[(i * 64 + (t >> 2)) * 32 + (t & 3) * 8]);
#pragma unroll
        for (int i = 0; i < BN / 64; ++i)
            gl_lds16(B + (size_t)(n0 + i * 64 + (t >> 2)) * ldb + k0 + (t & 3) * 8,
                     &Bsl[(i * 64 + (t >> 2)) * 32 + (t & 3) * 8]);
        __syncthreads();
        s16x8 av[FM], bv[FN];
#pragma unroll
        for (int fm = 0; fm < FM; ++fm)
            av[fm] = *(const s16x8*)&Asl[(rm + fm * 16 + lr) * 32 + kb];
#pragma unroll
        for (int fn = 0; fn < FN; ++fn)
            bv[fn] = *(const s16x8*)&Bsl[(cn + fn * 16 + lr) * 32 + kb];
#pragma unroll
        for (int fm = 0; fm < FM; ++fm)
#pragma unroll
            for (int fn = 0; fn < FN; ++fn)
                acc[fm][fn] = __builtin_amdgcn_mfma_f32_16x16x32_bf16(av[fm], bv[fn], acc[fm][fn], 0, 0, 0);
        __syncthreads();
    }

    // C/D frag layout: col = l&15, row = (l>>4)*4 + r
#pragma unroll
    for (int fm = 0; fm < FM; ++fm)
#pragma unroll
        for (int fn = 0; fn < FN; ++fn)
#pragma unroll
            for (int r = 0; r < 4; ++r) {
                const int gm = m0 + rm + fm * 16 + (l >> 4) * 4 + r;
                const int gn = n0 + cn + fn * 16 + lr;
                float v = acc[fm][fn][r];
                if constexpr (EPI == E_F32) {
                    v *= alpha;
                    if (bias) v += bias[gn];
                    size_t idx = (size_t)gm * ldc + gn;
                    Cf[idx] = v;
                    if (Cb) Cb[idx] = f2b(v);
                } else if constexpr (EPI == E_GELU) {
                    v += bias[gn];
                    float g = gelu_f(v);
                    size_t idx = (size_t)gm * ldc + gn;
                    if (Cf) Cf[idx] = g;
                    Cb[idx] = f2b(g);
                } else if constexpr (EPI == E_TD) {
                    size_t idx = (size_t)gm * ldc + gn;
                    float dlt = GAMMA_ * (v + cvec[gn]
                                - woutF[(size_t)gn * V_ + tcl[gm]]
                                - (subv ? subv[idx] : 0.f));
                    float o2 = base[idx] + dlt;
                    if (Cf) Cf[idx] = o2;
                    Cb[idx] = f2b(o2);
                    if (ebF) ebF[idx] = dlt;
                    if (ebB) ebB[idx] = f2b(dlt);
                } else if constexpr (EPI == E_X15B) {
                    size_t idx = (size_t)gm * ldc + gn;
                    Cb[idx] = f2b(base[idx] + GAMMA_ * v);
                } else if constexpr (EPI == E_EC) {
                    size_t idx = (size_t)gm * ldc + gn;
                    Cf[idx] = base[idx] - (v + bias[gn]);
                } else if constexpr (EPI == E_QKV3) {
                    v += bias[gn];
                    int b = gm >> 9, s = gm & (S_ - 1);
                    int sel = gn >> 9, d9 = gn & 511, h = d9 >> 6, d = d9 & 63;
                    u16 bvv = f2b(v);
                    if (sel == 0)
                        Cb[(((size_t)(b * H_ + h) * S_ + s) << 6) + d] = bvv;
                    else if (sel == 1)
                        Cb2[(((size_t)(b * H_ + h) * S_ + s) << 6) + d] = bvv;
                    else
                        Cb3[((((size_t)(b * H_ + h)) << 6) + d) * S_ + s] = bvv;
                }
            }
}

// ================= fused causal flash attention =================
// grid: (S/64, B*H); 4 waves, wave w owns q-rows [qt*64+w*16, +16)
// q,k: (B,H,S,64) bf16; vT: (B,H,64,S) bf16; ctx out: (B,S,512) bf16
__global__ __launch_bounds__(256)
void flash_attn(const u16* __restrict__ q, const u16* __restrict__ k,
                const u16* __restrict__ vT, u16* __restrict__ ctx)
{
    __shared__ __align__(16) u16 Ks[64 * 64];     // [kv][d]
    __shared__ __align__(16) u16 Vs[64 * 64];     // [d][kv]
    __shared__ __align__(16) u16 Ps[4][16 * 64];  // per-wave probs [qr][kv]
    const int t = threadIdx.x, l = t & 63, w = t >> 6;
    const int qt = blockIdx.x, z = blockIdx.y;
    const int bb = z >> 3, hh = z & 7;
    const int lr = l & 15, hi = l >> 4;
    const u16* qp = q + (((size_t)z * S_ + qt * 64 + w * 16) << 6);
    const u16* kp = k + ((size_t)z * S_ << 6);
    const u16* vp = vT + (((size_t)z) << 6) * S_;

    const s16x8 aq0 = *(const s16x8*)&qp[lr * 64 + hi * 8];
    const s16x8 aq1 = *(const s16x8*)&qp[lr * 64 + 32 + hi * 8];

    f32x4 o[4] = {};
    float m[4], ls[4];
#pragma unroll
    for (int r = 0; r < 4; ++r) { m[r] = -3.0e38f; ls[r] = 0.f; }
    const int qrow = qt * 64 + w * 16 + hi * 4;   // + r

    for (int j = 0; j <= qt; ++j) {
        __syncthreads();   // all waves done with previous Ks/Vs
        {
            int row = t >> 3, c8 = (t & 7) * 8;
            gl_lds16(kp + ((size_t)(j * 64 + row) << 6) + c8, &Ks[(row << 6) + c8]);
            gl_lds16(vp + (size_t)row * S_ + j * 64 + c8, &Vs[(row << 6) + c8]);
            int t2 = t + 256; row = t2 >> 3; c8 = (t2 & 7) * 8;
            gl_lds16(kp + ((size_t)(j * 64 + row) << 6) + c8, &Ks[(row << 6) + c8]);
            gl_lds16(vp + (size_t)row * S_ + j * 64 + c8, &Vs[(row << 6) + c8]);
        }
        __syncthreads();   // staging complete (vmcnt drained by barrier)

        float pv[4][4];
#pragma unroll
        for (int fn = 0; fn < 4; ++fn) {
            f32x4 acc = {};
            acc = __builtin_amdgcn_mfma_f32_16x16x32_bf16(aq0,
                    *(const s16x8*)&Ks[((fn * 16 + lr) << 6) + hi * 8], acc, 0, 0, 0);
            acc = __builtin_amdgcn_mfma_f32_16x16x32_bf16(aq1,
                    *(const s16x8*)&Ks[((fn * 16 + lr) << 6) + 32 + hi * 8], acc, 0, 0, 0);
#pragma unroll
            for (int r = 0; r < 4; ++r) pv[fn][r] = acc[r] * 0.125f;
        }
        if (j == qt) {  // causal mask on diagonal tile
#pragma unroll
            for (int fn = 0; fn < 4; ++fn) {
                int col = j * 64 + fn * 16 + lr;
#pragma unroll
                for (int r = 0; r < 4; ++r)
                    if (col > qrow + r) pv[fn][r] = -3.0e38f;
            }
        }
        // online softmax (row = (hi,r); cols spread over the 16-lane lr group)
        float sc[4], rs[4];
#pragma unroll
        for (int r = 0; r < 4; ++r) {
            float x = fmaxf(fmaxf(pv[0][r], pv[1][r]), fmaxf(pv[2][r], pv[3][r]));
#pragma unroll
            for (int off = 1; off < 16; off <<= 1) x = fmaxf(x, __shfl_xor(x, off, 64));
            float nm = fmaxf(m[r], x);
            sc[r] = expf(m[r] - nm);
            m[r] = nm;
            rs[r] = 0.f;
        }
#pragma unroll
        for (int fn = 0; fn < 4; ++fn)
#pragma unroll
            for (int r = 0; r < 4; ++r) {
                float p = expf(pv[fn][r] - m[r]);
                pv[fn][r] = p;
                rs[r] += p;
            }
#pragma unroll
        for (int r = 0; r < 4; ++r) {
#pragma unroll
            for (int off = 1; off < 16; off <<= 1) rs[r] += __shfl_xor(rs[r], off, 64);
            ls[r] = ls[r] * sc[r] + rs[r];
        }
#pragma unroll
        for (int fn = 0; fn < 4; ++fn)
#pragma unroll
            for (int r = 0; r < 4; ++r) o[fn][r] *= sc[r];
        // bounce P through per-wave LDS to A-frag layout (wave-local RAW; compiler waits)
#pragma unroll
        for (int fn = 0; fn < 4; ++fn)
#pragma unroll
            for (int r = 0; r < 4; ++r)
                Ps[w][((hi * 4 + r) << 6) + fn * 16 + lr] = f2b(pv[fn][r]);
#pragma unroll
        for (int ks = 0; ks < 2; ++ks) {
            const s16x8 pa = *(const s16x8*)&Ps[w][(lr << 6) + ks * 32 + hi * 8];
#pragma unroll
            for (int fn = 0; fn < 4; ++fn)
                o[fn] = __builtin_amdgcn_mfma_f32_16x16x32_bf16(pa,
                        *(const s16x8*)&Vs[((fn * 16 + lr) << 6) + ks * 32 + hi * 8], o[fn], 0, 0, 0);
        }
    }
    u16* cp = ctx + ((size_t)(bb * S_ + qt * 64 + w * 16) * D_) + hh * 64;
#pragma unroll
    for (int r = 0; r < 4; ++r) {
        float inv = 1.f / ls[r];
#pragma unroll
        for (int fn = 0; fn < 4; ++fn)
            cp[(size_t)(hi * 4 + r) * D_ + fn * 16 + lr] = f2b(o[fn][r] * inv);
    }
}

// ============ converters / small kernels ============
// f32 (R x C, +z*R*C) -> bf16 transposed (C x R), out += z*ostride
__global__ __launch_bounds__(256)
void transpose_cvt(const float* __restrict__ in, u16* __restrict__ out, int R, int C, long ostride)
{
    __shared__ float tile[32][33];
    long z = blockIdx.z;
    in += z * (long)R * C; out += z * ostride;
    int c0 = blockIdx.x * 32, r0 = blockIdx.y * 32;
    int tr = threadIdx.x >> 3, tc4 = (threadIdx.x & 7) * 4;
    const float4 v = *(const float4*)&in[(size_t)(r0 + tr) * C + c0 + tc4];
    tile[tr][tc4 + 0] = v.x; tile[tr][tc4 + 1] = v.y;
    tile[tr][tc4 + 2] = v.z; tile[tr][tc4 + 3] = v.w;
    __syncthreads();
    u16x4 o;
    o.x = f2b(tile[tc4 + 0][tr]); o.y = f2b(tile[tc4 + 1][tr]);
    o.z = f2b(tile[tc4 + 2][tr]); o.w = f2b(tile[tc4 + 3][tr]);
    *(u16x4*)&out[(size_t)(c0 + tr) * R + r0 + tc4] = o;
}

__global__ void cvt_bf16(const float4* __restrict__ in, u16* __restrict__ out, int n4)
{
    for (int i = blockIdx.x * blockDim.x + threadIdx.x; i < n4; i += gridDim.x * blockDim.x) {
        float4 v = in[i];
        u16x4 o; o.x = f2b(v.x); o.y = f2b(v.y); o.z = f2b(v.z); o.w = f2b(v.w);
        *(u16x4*)&out[i * 4] = o;
    }
}

__global__ __launch_bounds__(256)
void cvec_kernel(const float* __restrict__ Wout, const float* __restrict__ bout,
                 float* __restrict__ c)
{
    __shared__ float sh[4];
    int d = blockIdx.x;
    const float* row = Wout + (size_t)d * V_;
    float s = 0.f;
    for (int v = threadIdx.x * 4; v < V_; v += 1024) {
        float4 a = *(const float4*)&row[v];
        float4 b = *(const float4*)&bout[v];
        s += a.x * b.x + a.y * b.y + a.z * b.z + a.w * b.w;
    }
    float r = blk_sum(s, sh);
    if (threadIdx.x == 0) c[d] = r;
}

__global__ void gred_kernel(const float* __restrict__ P, u16* __restrict__ G)
{
    int i = blockIdx.x * blockDim.x + threadIdx.x;
    if (i < D_ * D_) {
        float s = 0.f;
#pragma unroll
        for (int zz = 0; zz < 8; ++zz) s += P[(size_t)zz * D_ * D_ + i];
        G[i] = f2b(s);
    }
}

__global__ void tclip_k(const int* __restrict__ t, int* __restrict__ o)
{
    int i = blockIdx.x * blockDim.x + threadIdx.x;
    if (i < M_) { int v = t[i]; o[i] = v < 0 ? 0 : (v > V_ - 1 ? V_ - 1 : v); }
}

__global__ void qkvb_kernel(const float* __restrict__ bq, const float* __restrict__ bk,
                            const float* __restrict__ bv, float* __restrict__ o)
{
    int i = blockIdx.x * blockDim.x + threadIdx.x;   // 4*1536
    if (i < 4 * 1536) {
        int b = i / 1536, j = i - b * 1536;
        float v = (j < 512) ? bq[b * 512 + j]
                : (j < 1024) ? bk[b * 512 + j - 512] : bv[b * 512 + j - 1024];
        o[i] = v;
    }
}

__global__ void embed_kernel(const float4* __restrict__ we, const float4* __restrict__ pe,
                             const int* __restrict__ ids, float4* __restrict__ o)
{
    int t = blockIdx.x * blockDim.x + threadIdx.x;  // M*128
    int d4 = t & 127, row = t >> 7;
    int ss = row & (S_ - 1);
    int id = ids[row];
    id = id < 0 ? 0 : (id > V_ - 1 ? V_ - 1 : id);
    float4 a = we[(size_t)id * 128 + d4];
    float4 b = pe[(size_t)ss * 128 + d4];
    o[(size_t)row * 128 + d4] = make_float4(a.x + b.x, a.y + b.y, a.z + b.z, a.w + b.w);
}

__global__ __launch_bounds__(256)
void ln_fwd_kernel(const float* __restrict__ x, const float* __restrict__ s,
                   const float* __restrict__ bb, u16* __restrict__ h)
{
    __shared__ float sh[4];
    int row = blockIdx.x, t = threadIdx.x;
    const float* xr = x + (size_t)row * D_;
    float x0 = xr[t], x1 = xr[t + 256];
    float mu = blk_sum(x0 + x1, sh) * (1.f / D_);
    float d0 = x0 - mu, d1 = x1 - mu;
    float var = blk_sum(d0 * d0 + d1 * d1, sh) * (1.f / D_);
    float r = rsqrtf(var + 1e-5f);
    u16* hr = h + (size_t)row * D_;
    hr[t]       = f2b(d0 * r * s[t]       + bb[t]);
    hr[t + 256] = f2b(d1 * r * s[t + 256] + bb[t + 256]);
}

// ================= host =================
extern "C" void kernel_launch(void* const* d_in, const int* in_sizes, int n_in,
                              void* d_out, int out_size, void* d_ws, size_t ws_size,
                              hipStream_t stream)
{
    (void)in_sizes; (void)n_in; (void)out_size;
    const float* Wq  = (const float*)d_in[2];
    const float* Wk  = (const float*)d_in[3];
    const float* Wv  = (const float*)d_in[4];
    const float* bq  = (const float*)d_in[5];
    const float* bk  = (const float*)d_in[6];
    const float* bv  = (const float*)d_in[7];
    const float* Wo  = (const float*)d_in[8];
    const float* bo  = (const float*)d_in[9];
    const float* ln1_s = (const float*)d_in[10];
    const float* ln1_b = (const float*)d_in[11];
    const float* ln2_s = (const float*)d_in[12];
    const float* ln2_b = (const float*)d_in[13];
    const float* W1  = (const float*)d_in[14];
    const float* b1  = (const float*)d_in[15];
    const float* W2  = (const float*)d_in[16];
    const float* b2  = (const float*)d_in[17];
    const float* Wout = (const float*)d_in[18];
    const float* bout = (const float*)d_in[19];
    const int* input_ids  = (const int*)d_in[20];
    const int* target_ids = (const int*)d_in[21];
    float* out = (float*)d_out;

    // ---- workspace carve ----
    char* wsb = (char*)d_ws;
    size_t off = 0;
    auto alloc = [&](size_t bytes) -> void* {
        off = (off + 255) & ~(size_t)255;
        void* p = wsb + off; off += bytes; return p;
    };
    u16* wqkvT = (u16*)alloc((size_t)4 * 1536 * D_ * 2);   // per-layer [Q^T;K^T;V^T] (1536,512)
    u16* woT   = (u16*)alloc((size_t)4 * D_ * D_ * 2);
    u16* w1T   = (u16*)alloc((size_t)4 * D_ * F_ * 2);
    u16* w2T   = (u16*)alloc((size_t)4 * D_ * F_ * 2);
    u16* w2d   = (u16*)alloc((size_t)F_ * D_ * 2);
    u16* woutT = (u16*)alloc((size_t)V_ * D_ * 2);
    u16* G_b   = (u16*)alloc((size_t)D_ * D_ * 2);
    float* qkvb = (float*)alloc((size_t)4 * 1536 * 4);
    float* bufA = (float*)alloc((size_t)MF_ * 4);
    float* bufB = (float*)alloc((size_t)MD_ * 4);
    u16* h_b    = (u16*)alloc((size_t)MD_ * 2);
    u16* gelu_b = (u16*)alloc((size_t)MF_ * 2);
    u16* x16_b  = (u16*)alloc((size_t)MD_ * 2);
    float* cvec = (float*)alloc(D_ * 4);
    int* tcl    = (int*)alloc(M_ * 4);
    size_t uStart = (off + 255) & ~(size_t)255;
    // phase G (precompute)
    off = uStart;
    u16* woutD   = (u16*)alloc((size_t)V_ * D_ * 2);
    float* Gpart = (float*)alloc((size_t)8 * D_ * D_ * 4);
    size_t endG = off;
    // phase attention
    off = uStart;
    u16* q_b   = (u16*)alloc((size_t)MD_ * 2);
    u16* k_b   = (u16*)alloc((size_t)MD_ * 2);
    u16* v_b   = (u16*)alloc((size_t)MD_ * 2);   // V^T (B,H,dh,S)
    u16* ctx_b = (u16*)alloc((size_t)MD_ * 2);
    size_t endA = off;
    // phase tail
    off = uStart;
    float* xA  = (float*)alloc((size_t)MD_ * 4);
    float* xB  = (float*)alloc((size_t)MD_ * 4);
    float* eb  = (float*)alloc((size_t)MD_ * 4);
    float* ec  = (float*)alloc((size_t)MD_ * 4);
    u16* xA_b  = (u16*)alloc((size_t)MD_ * 2);
    u16* xB_b  = (u16*)alloc((size_t)MD_ * 2);
    u16* xC_b  = (u16*)alloc((size_t)MD_ * 2);
    u16* eb_b  = (u16*)alloc((size_t)MD_ * 2);
    u16* x15b_b = (u16*)alloc((size_t)MF_ * 2);
    size_t endT = off;
    size_t need = endG > endA ? endG : endA;
    if (endT > need) need = endT;
    if (need > ws_size) return;

    dim3 blk(256);
    const long NL = 0;  // null long
    #define GZ nullptr, nullptr, nullptr, nullptr, nullptr, nullptr, nullptr  // base..ebB

    // ---- one-time precompute ----
    tclip_k<<<dim3(4), blk, 0, stream>>>(target_ids, tcl);
    cvec_kernel<<<dim3(D_), blk, 0, stream>>>(Wout, bout, cvec);
    qkvb_kernel<<<dim3(24), blk, 0, stream>>>(bq, bk, bv, qkvb);
    transpose_cvt<<<dim3(16, 16, 4), blk, 0, stream>>>(Wq, wqkvT, D_, D_, 1536L * 512);
    transpose_cvt<<<dim3(16, 16, 4), blk, 0, stream>>>(Wk, wqkvT + 512 * 512, D_, D_, 1536L * 512);
    transpose_cvt<<<dim3(16, 16, 4), blk, 0, stream>>>(Wv, wqkvT + 1024 * 512, D_, D_, 1536L * 512);
    transpose_cvt<<<dim3(16, 16, 4), blk, 0, stream>>>(Wo, woT, D_, D_, (long)D_ * D_);
    transpose_cvt<<<dim3(64, 16, 4), blk, 0, stream>>>(W1, w1T, D_, F_, (long)D_ * F_);
    transpose_cvt<<<dim3(16, 64, 4), blk, 0, stream>>>(W2, w2T, F_, D_, (long)F_ * D_);
    transpose_cvt<<<dim3(512, 16, 1), blk, 0, stream>>>(Wout, woutT, D_, V_, (long)V_ * D_);
    cvt_bf16<<<dim3(1024), blk, 0, stream>>>((const float4*)(W2 + (size_t)3 * F_ * D_), w2d, F_ * D_ / 4);
    cvt_bf16<<<dim3(2048), blk, 0, stream>>>((const float4*)Wout, woutD, V_ * D_ / 4);
    // G = Wout @ Wout^T, split-K 8x2048
    mfma_gemm<128, 128, 4, 4, E_F32><<<dim3(4, 4, 8), blk, 0, stream>>>(
        woutD, woutD, Gpart, nullptr, nullptr, nullptr, nullptr, 2048, V_, V_, D_,
        (long)D_ * D_, 2048, 1.f, GZ);
    gred_kernel<<<dim3(1024), blk, 0, stream>>>(Gpart, G_b);

    // ---- forward sweep ----
    embed_kernel<<<dim3(512), blk, 0, stream>>>((const float4*)d_in[0], (const float4*)d_in[1],
                                                input_ids, (float4*)bufB);
    for (int b = 0; b < 4; ++b) {
        const size_t wDD = (size_t)b * D_ * D_, wDF = (size_t)b * D_ * F_;
        ln_fwd_kernel<<<dim3(M_), blk, 0, stream>>>(bufB, ln1_s + b * D_, ln1_b + b * D_, h_b);
        // fused QKV projection + scatter
        mfma_gemm<128, 64, 4, 2, E_QKV3><<<dim3(24, 8, 1), blk, 0, stream>>>(
            h_b, wqkvT + (size_t)b * 1536 * 512, nullptr, q_b, k_b, v_b,
            qkvb + b * 1536, D_, D_, D_, 0, NL, NL, 1.f, GZ);
        flash_attn<<<dim3(8, 16), blk, 0, stream>>>(q_b, k_b, v_b, ctx_b);
        mfma_gemm<64, 64, 2, 2, E_F32><<<dim3(8, 16, 1), blk, 0, stream>>>(
            ctx_b, woT + wDD, bufB, nullptr, nullptr, nullptr, bo + b * D_,
            D_, D_, D_, D_, NL, NL, 1.f, GZ);
        ln_fwd_kernel<<<dim3(M_), blk, 0, stream>>>(bufB, ln2_s + b * D_, ln2_b + b * D_, h_b);
        mfma_gemm<128, 128, 4, 4, E_GELU><<<dim3(16, 8, 1), blk, 0, stream>>>(
            h_b, w1T + wDF, (b == 3) ? bufA : nullptr, gelu_b, nullptr, nullptr, b1 + b * F_,
            D_, D_, D_, F_, NL, NL, 1.f, GZ);
        mfma_gemm<64, 64, 2, 2, E_F32><<<dim3(8, 16, 1), blk, 0, stream>>>(
            gelu_b, w2T + wDF, bufB, (b == 3) ? x16_b : nullptr, nullptr, nullptr, b2 + b * D_,
            F_, F_, F_, D_, NL, NL, 1.f, GZ);
    }
    // x15 f32 = bufA, x16 f32 = bufB, x16 bf16 = x16_b

    // ---- PC tail ----
    // iter 1: xA = x16 + dlt; eb = dlt  (dlt = g*(x16@G + cvec - gather))
    mfma_gemm<64, 64, 2, 2, E_TD><<<dim3(8, 16, 1), blk, 0, stream>>>(
        x16_b, G_b, xA, xA_b, nullptr, nullptr, nullptr, D_, D_, D_, D_, NL, NL, 1.f,
        bufB, nullptr, cvec, Wout, tcl, eb, eb_b);
    // iter 2: xB = xA + g*(xA@G + cvec - gth - eb)
    mfma_gemm<64, 64, 2, 2, E_TD><<<dim3(8, 16, 1), blk, 0, stream>>>(
        xA_b, G_b, xB, xB_b, nullptr, nullptr, nullptr, D_, D_, D_, D_, NL, NL, 1.f,
        xA, eb, cvec, Wout, tcl, nullptr, nullptr);
    // x15b = x15 + g*(eb @ W2[3]^T)
    mfma_gemm<128, 128, 4, 4, E_X15B><<<dim3(16, 8, 1), blk, 0, stream>>>(
        eb_b, w2d, nullptr, x15b_b, nullptr, nullptr, nullptr, D_, D_, D_, F_, NL, NL, 1.f,
        bufA, nullptr, nullptr, nullptr, nullptr, nullptr, nullptr);
    // ec = xB - (x15b @ W2[3] + b2[3])
    mfma_gemm<64, 64, 2, 2, E_EC><<<dim3(8, 16, 1), blk, 0, stream>>>(
        x15b_b, w2T + (size_t)3 * D_ * F_, ec, nullptr, nullptr, nullptr, b2 + 3 * D_,
        F_, F_, F_, D_, NL, NL, 1.f,
        xB, nullptr, nullptr, nullptr, nullptr, nullptr, nullptr);
    // iter 3: xC = xB + g*(xB@G + cvec - gth - ec)
    mfma_gemm<64, 64, 2, 2, E_TD><<<dim3(8, 16, 1), blk, 0, stream>>>(
        xB_b, G_b, nullptr, xC_b, nullptr, nullptr, nullptr, D_, D_, D_, D_, NL, NL, 1.f,
        xB, ec, cvec, Wout, tcl, nullptr, nullptr);
    // final: out = xC @ Wout + bout
    mfma_gemm<128, 128, 4, 4, E_F32><<<dim3(128, 8, 1), blk, 0, stream>>>(
        xC_b, woutT, out, nullptr, nullptr, nullptr, bout, D_, D_, D_, V_, NL, NL, 1.f, GZ);
    #undef GZ
}

// Round 4
// 590.092 us; speedup vs baseline: 9.3494x; 1.1163x over previous
//
#include <hip/hip_runtime.h>
#include <hip/hip_bf16.h>
#include <math.h>

#define D_   512
#define F_   2048
#define V_   16384
#define H_   8
#define DH_  64
#define S_   512
#define B_   2
#define M_   1024
#define MD_  (M_ * D_)
#define MF_  (M_ * F_)
#define GAMMA_ 0.1f

typedef unsigned int u32;
typedef unsigned short u16;
typedef __attribute__((ext_vector_type(4))) float f32x4;
typedef __attribute__((ext_vector_type(8))) short s16x8;
typedef __attribute__((ext_vector_type(4))) u16 u16x4;

__device__ __forceinline__ u16 f2b(float f) {
    __hip_bfloat16 h = __float2bfloat16(f);   // RTNE
    return *reinterpret_cast<u16*>(&h);
}
__device__ __forceinline__ u16x4 pack4(f32x4 v) {
    u16x4 o; o.x = f2b(v[0]); o.y = f2b(v[1]); o.z = f2b(v[2]); o.w = f2b(v[3]);
    return o;
}

__device__ __forceinline__ void gl_lds16(const void* g, void* l) {
    __builtin_amdgcn_global_load_lds((const __attribute__((address_space(1))) u32*)g,
                                     (__attribute__((address_space(3))) u32*)l, 16, 0, 0);
}

__device__ __forceinline__ float gelu_f(float v) {
    float u = 0.7978845608028654f * (v + 0.044715f * v * v * v);
    return 0.5f * v * (1.f + tanhf(u));
}

// 4x4 transpose across lane quads (lanes differing in bits 0..1), 4 regs each.
// old: lane b holds Sub[r][b] in reg r  ->  new: lane b holds Sub[b][j] in reg j.
__device__ __forceinline__ f32x4 xpose4(f32x4 v, int b) {
#pragma unroll
    for (int s = 1; s < 4; s <<= 1) {
        f32x4 nv;
#pragma unroll
        for (int j = 0; j < 4; ++j) {
            float ex = __shfl_xor(v[j ^ s], s, 64);
            nv[j] = ((b ^ j) & s) ? ex : v[j];
        }
        v = nv;
    }
    return v;
}

// block reduction (blockDim.x == 256)
__device__ __forceinline__ float blk_sum(float v, float* sh) {
#pragma unroll
    for (int o = 32; o > 0; o >>= 1) v += __shfl_down(v, o, 64);
    int lane = threadIdx.x & 63, w = threadIdx.x >> 6;
    if (lane == 0) sh[w] = v;
    __syncthreads();
    float r = sh[0] + sh[1] + sh[2] + sh[3];
    __syncthreads();
    return r;
}

// ================= MFMA GEMM (NT: A MxK row-major, B NxK row-major, bf16) ===========
#define E_F32   0
#define E_GELU  1
#define E_TD    2
#define E_X15B  3
#define E_EC    4
#define E_QKV3  5

template<int BM, int BN, int FM, int FN, int EPI>
__global__ __launch_bounds__(256)
void mfma_gemm(const u16* __restrict__ A, const u16* __restrict__ B,
               float* __restrict__ Cf, u16* __restrict__ Cb,
               u16* __restrict__ Cb2, u16* __restrict__ Cb3,
               const float* __restrict__ bias,
               int K, int lda, int ldb, int ldc,
               long sC, long sKz, float alpha,
               const float* __restrict__ base, const float* __restrict__ subv,
               const float* __restrict__ cvec, const float* __restrict__ woutF,
               const int* __restrict__ tcl,
               float* __restrict__ ebF, u16* __restrict__ ebB)
{
    constexpr int WC = BN / (FN * 16);
    static_assert((BM / (FM * 16)) * WC == 4, "4 waves");
    __shared__ __align__(16) u16 Asl[BM * 32];
    __shared__ __align__(16) u16 Bsl[BN * 32];
    const int t = threadIdx.x, l = t & 63, wid = t >> 6;
    int bx = blockIdx.x, by = blockIdx.y;
    // XCD-aware bijective swizzle (z==1 grids only, nwg % 8 == 0)
    if (gridDim.z == 1) {
        int nwg = gridDim.x * gridDim.y;
        if ((nwg & 7) == 0) {
            int id = by * gridDim.x + bx;
            int wg = (id & 7) * (nwg >> 3) + (id >> 3);
            bx = wg % gridDim.x; by = wg / gridDim.x;
        }
    }
    const int m0 = by * BM, n0 = bx * BN;
    const long z = blockIdx.z;
    A += z * sKz;
    B += z * sKz;
    if (Cf) Cf += z * sC;

    f32x4 acc[FM][FN] = {};
    const int rm = (wid / WC) * (FM * 16), cn = (wid % WC) * (FN * 16);
    const int lr = l & 15, hi = l >> 4;
    const int srow = t >> 2;                          // staging row within 64-group
    const int scol = ((t & 3) ^ ((t >> 3) & 3)) * 8;  // pre-swizzled global k-chunk (u16)
    const int ksw = (hi ^ ((lr >> 1) & 3)) * 8;       // swizzled read chunk (u16)

    for (int k0 = 0; k0 < K; k0 += 32) {
#pragma unroll
        for (int i = 0; i < BM / 64; ++i)
            gl_lds16(A + (size_t)(m0 + i * 64 + srow) * lda + k0 + scol,
                     &Asl[i * 2048 + t * 8]);
#pragma unroll
        for (int i = 0; i < BN / 64; ++i)
            gl_lds16(B + (size_t)(n0 + i * 64 + srow) * ldb + k0 + scol,
                     &Bsl[i * 2048 + t * 8]);
        __syncthreads();
        s16x8 av[FM], bv[FN];
#pragma unroll
        for (int fm = 0; fm < FM; ++fm)
            av[fm] = *(const s16x8*)&Asl[(rm + fm * 16 + lr) * 32 + ksw];
#pragma unroll
        for (int fn = 0; fn < FN; ++fn)
            bv[fn] = *(const s16x8*)&Bsl[(cn + fn * 16 + lr) * 32 + ksw];
#pragma unroll
        for (int fm = 0; fm < FM; ++fm)
#pragma unroll
            for (int fn = 0; fn < FN; ++fn)
                acc[fm][fn] = __builtin_amdgcn_mfma_f32_16x16x32_bf16(av[fm], bv[fn], acc[fm][fn], 0, 0, 0);
        __syncthreads();
    }

    // epilogue: per-fragment 4x4 transpose -> lane holds row (hi*4+qb), 4 consecutive cols
    const int qb = lr & 3, qi = lr >> 2;
#pragma unroll
    for (int fm = 0; fm < FM; ++fm)
#pragma unroll
        for (int fn = 0; fn < FN; ++fn) {
            f32x4 v = xpose4(acc[fm][fn], qb);
            const int gm = m0 + rm + fm * 16 + hi * 4 + qb;
            const int gn0 = n0 + cn + fn * 16 + qi * 4;
            const size_t idx0 = (size_t)gm * ldc + gn0;
            if constexpr (EPI == E_F32) {
#pragma unroll
                for (int j = 0; j < 4; ++j) v[j] *= alpha;
                if (bias) {
                    f32x4 bv4 = *(const f32x4*)&bias[gn0];
#pragma unroll
                    for (int j = 0; j < 4; ++j) v[j] += bv4[j];
                }
                *(f32x4*)&Cf[idx0] = v;
                if (Cb) *(u16x4*)&Cb[idx0] = pack4(v);
            } else if constexpr (EPI == E_GELU) {
                f32x4 bv4 = *(const f32x4*)&bias[gn0];
#pragma unroll
                for (int j = 0; j < 4; ++j) v[j] = gelu_f(v[j] + bv4[j]);
                if (Cf) *(f32x4*)&Cf[idx0] = v;
                *(u16x4*)&Cb[idx0] = pack4(v);
            } else if constexpr (EPI == E_TD) {
                const int tc = tcl[gm];
                f32x4 cv4 = *(const f32x4*)&cvec[gn0];
                f32x4 ba4 = *(const f32x4*)&base[idx0];
                f32x4 dlt, o2;
#pragma unroll
                for (int j = 0; j < 4; ++j) {
                    float d = v[j] + cv4[j] - woutF[(size_t)(gn0 + j) * V_ + tc];
                    dlt[j] = GAMMA_ * d;
                }
                if (subv) {
                    f32x4 sv4 = *(const f32x4*)&subv[idx0];
#pragma unroll
                    for (int j = 0; j < 4; ++j) dlt[j] -= GAMMA_ * sv4[j];
                }
#pragma unroll
                for (int j = 0; j < 4; ++j) o2[j] = ba4[j] + dlt[j];
                if (Cf) *(f32x4*)&Cf[idx0] = o2;
                *(u16x4*)&Cb[idx0] = pack4(o2);
                if (ebF) *(f32x4*)&ebF[idx0] = dlt;
                if (ebB) *(u16x4*)&ebB[idx0] = pack4(dlt);
            } else if constexpr (EPI == E_X15B) {
                f32x4 ba4 = *(const f32x4*)&base[idx0];
#pragma unroll
                for (int j = 0; j < 4; ++j) v[j] = ba4[j] + GAMMA_ * v[j];
                *(u16x4*)&Cb[idx0] = pack4(v);
            } else if constexpr (EPI == E_EC) {
                f32x4 ba4 = *(const f32x4*)&base[idx0];
                f32x4 bv4 = *(const f32x4*)&bias[gn0];
#pragma unroll
                for (int j = 0; j < 4; ++j) v[j] = ba4[j] - (v[j] + bv4[j]);
                *(f32x4*)&Cf[idx0] = v;
            } else if constexpr (EPI == E_QKV3) {
                f32x4 bv4 = *(const f32x4*)&bias[gn0];
#pragma unroll
                for (int j = 0; j < 4; ++j) v[j] += bv4[j];
                int b = gm >> 9, s = gm & (S_ - 1);
                int sel = gn0 >> 9, d9 = gn0 & 511, h = d9 >> 6, d = d9 & 63;
                if (sel == 0)
                    *(u16x4*)&Cb[(((size_t)(b * H_ + h) * S_ + s) << 6) + d] = pack4(v);
                else if (sel == 1)
                    *(u16x4*)&Cb2[(((size_t)(b * H_ + h) * S_ + s) << 6) + d] = pack4(v);
                else {
                    u16x4 p = pack4(v);
#pragma unroll
                    for (int j = 0; j < 4; ++j)
                        Cb3[((((size_t)(b * H_ + h)) << 6) + d + j) * S_ + s] = p[j];
                }
            }
        }
}

// ================= fused causal flash attention =================
// grid: (S/64, B*H); 4 waves, wave w owns q-rows [qt*64+w*16, +16)
__global__ __launch_bounds__(256)
void flash_attn(const u16* __restrict__ q, const u16* __restrict__ k,
                const u16* __restrict__ vT, u16* __restrict__ ctx)
{
    __shared__ __align__(16) u16 Ks[64 * 64];
    __shared__ __align__(16) u16 Vs[64 * 64];
    __shared__ __align__(16) u16 Ps[4][16 * 64];
    const int t = threadIdx.x, l = t & 63, w = t >> 6;
    const int qt = blockIdx.x, z = blockIdx.y;
    const int bb = z >> 3, hh = z & 7;
    const int lr = l & 15, hi = l >> 4;
    const u16* qp = q + (((size_t)z * S_ + qt * 64 + w * 16) << 6);
    const u16* kp = k + ((size_t)z * S_ << 6);
    const u16* vp = vT + (((size_t)z) << 6) * S_;

    const s16x8 aq0 = *(const s16x8*)&qp[lr * 64 + hi * 8];
    const s16x8 aq1 = *(const s16x8*)&qp[lr * 64 + 32 + hi * 8];

    f32x4 o[4] = {};
    float m[4], ls[4];
#pragma unroll
    for (int r = 0; r < 4; ++r) { m[r] = -3.0e38f; ls[r] = 0.f; }
    const int qrow = qt * 64 + w * 16 + hi * 4;
    // staging coords (pre-swizzled global source, linear LDS dest)
    const int srow = t >> 3, scl = t & 7;
    const int cg1 = (scl ^ (srow & 7)) * 8;
    const int srow2 = srow + 32;
    const int cg2 = (scl ^ (srow2 & 7)) * 8;
    const int sw7 = (lr & 7);   // read-side row swizzle bits

    for (int j = 0; j <= qt; ++j) {
        __syncthreads();
        gl_lds16(kp + ((size_t)(j * 64 + srow) << 6) + cg1, &Ks[t * 8]);
        gl_lds16(vp + (size_t)srow * S_ + j * 64 + cg1, &Vs[t * 8]);
        gl_lds16(kp + ((size_t)(j * 64 + srow2) << 6) + cg2, &Ks[(t + 256) * 8]);
        gl_lds16(vp + (size_t)srow2 * S_ + j * 64 + cg2, &Vs[(t + 256) * 8]);
        __syncthreads();

        float pv[4][4];
#pragma unroll
        for (int fn = 0; fn < 4; ++fn) {
            f32x4 acc = {};
            acc = __builtin_amdgcn_mfma_f32_16x16x32_bf16(aq0,
                    *(const s16x8*)&Ks[((fn * 16 + lr) << 6) + ((hi ^ sw7) * 8)], acc, 0, 0, 0);
            acc = __builtin_amdgcn_mfma_f32_16x16x32_bf16(aq1,
                    *(const s16x8*)&Ks[((fn * 16 + lr) << 6) + (((hi + 4) ^ sw7) * 8)], acc, 0, 0, 0);
#pragma unroll
            for (int r = 0; r < 4; ++r) pv[fn][r] = acc[r] * 0.125f;
        }
        if (j == qt) {
#pragma unroll
            for (int fn = 0; fn < 4; ++fn) {
                int col = j * 64 + fn * 16 + lr;
#pragma unroll
                for (int r = 0; r < 4; ++r)
                    if (col > qrow + r) pv[fn][r] = -3.0e38f;
            }
        }
        float sc[4], rs[4];
#pragma unroll
        for (int r = 0; r < 4; ++r) {
            float x = fmaxf(fmaxf(pv[0][r], pv[1][r]), fmaxf(pv[2][r], pv[3][r]));
#pragma unroll
            for (int off = 1; off < 16; off <<= 1) x = fmaxf(x, __shfl_xor(x, off, 64));
            float nm = fmaxf(m[r], x);
            sc[r] = expf(m[r] - nm);
            m[r] = nm;
            rs[r] = 0.f;
        }
#pragma unroll
        for (int fn = 0; fn < 4; ++fn)
#pragma unroll
            for (int r = 0; r < 4; ++r) {
                float p = expf(pv[fn][r] - m[r]);
                pv[fn][r] = p;
                rs[r] += p;
            }
#pragma unroll
        for (int r = 0; r < 4; ++r) {
#pragma unroll
            for (int off = 1; off < 16; off <<= 1) rs[r] += __shfl_xor(rs[r], off, 64);
            ls[r] = ls[r] * sc[r] + rs[r];
        }
#pragma unroll
        for (int fn = 0; fn < 4; ++fn)
#pragma unroll
            for (int r = 0; r < 4; ++r) o[fn][r] *= sc[r];
        // P bounce via per-wave LDS (swizzled both sides)
#pragma unroll
        for (int fn = 0; fn < 4; ++fn)
#pragma unroll
            for (int r = 0; r < 4; ++r) {
                int qr = hi * 4 + r;
                int ci = (2 * fn + (lr >> 3)) ^ (qr & 7);
                Ps[w][qr * 64 + ci * 8 + (lr & 7)] = f2b(pv[fn][r]);
            }
#pragma unroll
        for (int ks = 0; ks < 2; ++ks) {
            const s16x8 pa = *(const s16x8*)&Ps[w][lr * 64 + (((4 * ks + hi) ^ sw7) * 8)];
#pragma unroll
            for (int fn = 0; fn < 4; ++fn)
                o[fn] = __builtin_amdgcn_mfma_f32_16x16x32_bf16(pa,
                        *(const s16x8*)&Vs[((fn * 16 + lr) << 6) + (((hi + 4 * ks) ^ sw7) * 8)], o[fn], 0, 0, 0);
        }
    }
    // epilogue: scale rows, transpose, vectorized store
    float inv[4];
#pragma unroll
    for (int r = 0; r < 4; ++r) inv[r] = 1.f / ls[r];
    u16* cp = ctx + ((size_t)(bb * S_ + qt * 64 + w * 16) * D_) + hh * 64;
    const int qb = lr & 3, qi = lr >> 2;
#pragma unroll
    for (int fn = 0; fn < 4; ++fn) {
        f32x4 v = o[fn];
#pragma unroll
        for (int r = 0; r < 4; ++r) v[r] *= inv[r];
        v = xpose4(v, qb);
        *(u16x4*)&cp[(size_t)(hi * 4 + qb) * D_ + fn * 16 + qi * 4] = pack4(v);
    }
}

// ============ mega precompute: all transposes/casts + misc in one dispatch ============
__device__ __forceinline__ void tr_tile(const float* __restrict__ in, u16* __restrict__ out,
                                        int R, int C, int tx, int ty, float (*tile)[33])
{
    int c0 = tx * 32, r0 = ty * 32;
    int tr = threadIdx.x >> 3, tc4 = (threadIdx.x & 7) * 4;
    const float4 v = *(const float4*)&in[(size_t)(r0 + tr) * C + c0 + tc4];
    tile[tr][tc4 + 0] = v.x; tile[tr][tc4 + 1] = v.y;
    tile[tr][tc4 + 2] = v.z; tile[tr][tc4 + 3] = v.w;
    __syncthreads();
    u16x4 o;
    o.x = f2b(tile[tc4 + 0][tr]); o.y = f2b(tile[tc4 + 1][tr]);
    o.z = f2b(tile[tc4 + 2][tr]); o.w = f2b(tile[tc4 + 3][tr]);
    *(u16x4*)&out[(size_t)(c0 + tr) * R + r0 + tc4] = o;
}

__device__ __forceinline__ void cvt_blk(const float* __restrict__ in, u16* __restrict__ out,
                                        int blk)
{
    int i0 = blk * 1024 + threadIdx.x * 4;
    float4 v = *(const float4*)&in[i0];
    u16x4 o; o.x = f2b(v.x); o.y = f2b(v.y); o.z = f2b(v.z); o.w = f2b(v.w);
    *(u16x4*)&out[i0] = o;
}

__global__ __launch_bounds__(256)
void mega_prep(const float* __restrict__ Wq, const float* __restrict__ Wk,
               const float* __restrict__ Wv, const float* __restrict__ Wo,
               const float* __restrict__ W1, const float* __restrict__ W2,
               const float* __restrict__ Wout,
               const float* __restrict__ bq, const float* __restrict__ bk,
               const float* __restrict__ bv, const int* __restrict__ target_ids,
               u16* __restrict__ wqkvT, u16* __restrict__ woT, u16* __restrict__ w1T,
               u16* __restrict__ w2T, u16* __restrict__ w2d, u16* __restrict__ woutT,
               u16* __restrict__ woutD, float* __restrict__ qkvb, int* __restrict__ tcl)
{
    __shared__ float tile[32][33];
    const int g = blockIdx.x, t = threadIdx.x;
    if (g < 3072) {               // Wq/Wk/Wv -> wqkvT (per layer: [Q^T;K^T;V^T] 1536x512)
        int sel = g >> 10, rem = g & 1023, z = rem >> 8, tl = rem & 255;
        const float* src = (sel == 0 ? Wq : sel == 1 ? Wk : Wv) + (size_t)z * 262144;
        u16* dst = wqkvT + (size_t)z * 786432 + sel * 262144;
        tr_tile(src, dst, 512, 512, tl & 15, tl >> 4, tile);
    } else if (g < 4096) {        // Wo -> woT
        int rem = g - 3072, z = rem >> 8, tl = rem & 255;
        tr_tile(Wo + (size_t)z * 262144, woT + (size_t)z * 262144, 512, 512, tl & 15, tl >> 4, tile);
    } else if (g < 8192) {        // W1 (512x2048) -> w1T (2048x512)
        int rem = g - 4096, z = rem >> 10, tl = rem & 1023;
        tr_tile(W1 + (size_t)z * 1048576, w1T + (size_t)z * 1048576, 512, 2048, tl & 63, tl >> 6, tile);
    } else if (g < 12288) {       // W2 (2048x512) -> w2T (512x2048)
        int rem = g - 8192, z = rem >> 10, tl = rem & 1023;
        tr_tile(W2 + (size_t)z * 1048576, w2T + (size_t)z * 1048576, 2048, 512, tl & 15, tl >> 4, tile);
    } else if (g < 20480) {       // Wout (512x16384) -> woutT (16384x512)
        int tl = g - 12288;
        tr_tile(Wout, woutT, 512, 16384, tl & 511, tl >> 9, tile);
    } else if (g < 21504) {       // W2[3] cast -> w2d (row-major bf16)
        cvt_blk(W2 + (size_t)3 * F_ * D_, w2d, g - 20480);
    } else if (g < 29696) {       // Wout cast -> woutD (row-major bf16)
        cvt_blk(Wout, woutD, g - 21504);
    } else {                      // misc: tclip + qkvb
        for (int i = t; i < M_; i += 256) {
            int v = target_ids[i];
            tcl[i] = v < 0 ? 0 : (v > V_ - 1 ? V_ - 1 : v);
        }
        for (int i = t; i < 4 * 1536; i += 256) {
            int b = i / 1536, j = i - b * 1536;
            qkvb[i] = (j < 512) ? bq[b * 512 + j]
                    : (j < 1024) ? bk[b * 512 + j - 512] : bv[b * 512 + j - 1024];
        }
    }
}

__global__ __launch_bounds__(256)
void cvec_kernel(const float* __restrict__ Wout, const float* __restrict__ bout,
                 float* __restrict__ c)
{
    __shared__ float sh[4];
    int d = blockIdx.x;
    const float* row = Wout + (size_t)d * V_;
    float s = 0.f;
    for (int v = threadIdx.x * 4; v < V_; v += 1024) {
        float4 a = *(const float4*)&row[v];
        float4 b = *(const float4*)&bout[v];
        s += a.x * b.x + a.y * b.y + a.z * b.z + a.w * b.w;
    }
    float r = blk_sum(s, sh);
    if (threadIdx.x == 0) c[d] = r;
}

__global__ void gred_kernel(const float* __restrict__ P, u16* __restrict__ G)
{
    int i = blockIdx.x * blockDim.x + threadIdx.x;
    if (i < D_ * D_) {
        float s = 0.f;
#pragma unroll
        for (int zz = 0; zz < 16; ++zz) s += P[(size_t)zz * D_ * D_ + i];
        G[i] = f2b(s);
    }
}

__global__ void embed_kernel(const float4* __restrict__ we, const float4* __restrict__ pe,
                             const int* __restrict__ ids, float4* __restrict__ o)
{
    int t = blockIdx.x * blockDim.x + threadIdx.x;  // M*128
    int d4 = t & 127, row = t >> 7;
    int ss = row & (S_ - 1);
    int id = ids[row];
    id = id < 0 ? 0 : (id > V_ - 1 ? V_ - 1 : id);
    float4 a = we[(size_t)id * 128 + d4];
    float4 b = pe[(size_t)ss * 128 + d4];
    o[(size_t)row * 128 + d4] = make_float4(a.x + b.x, a.y + b.y, a.z + b.z, a.w + b.w);
}

__global__ __launch_bounds__(256)
void ln_fwd_kernel(const float* __restrict__ x, const float* __restrict__ s,
                   const float* __restrict__ bb, u16* __restrict__ h)
{
    __shared__ float sh[4];
    int row = blockIdx.x, t = threadIdx.x;
    const float* xr = x + (size_t)row * D_;
    float x0 = xr[t], x1 = xr[t + 256];
    float mu = blk_sum(x0 + x1, sh) * (1.f / D_);
    float d0 = x0 - mu, d1 = x1 - mu;
    float var = blk_sum(d0 * d0 + d1 * d1, sh) * (1.f / D_);
    float r = rsqrtf(var + 1e-5f);
    u16* hr = h + (size_t)row * D_;
    hr[t]       = f2b(d0 * r * s[t]       + bb[t]);
    hr[t + 256] = f2b(d1 * r * s[t + 256] + bb[t + 256]);
}

// ================= host =================
extern "C" void kernel_launch(void* const* d_in, const int* in_sizes, int n_in,
                              void* d_out, int out_size, void* d_ws, size_t ws_size,
                              hipStream_t stream)
{
    (void)in_sizes; (void)n_in; (void)out_size;
    const float* Wq  = (const float*)d_in[2];
    const float* Wk  = (const float*)d_in[3];
    const float* Wv  = (const float*)d_in[4];
    const float* bq  = (const float*)d_in[5];
    const float* bk  = (const float*)d_in[6];
    const float* bv  = (const float*)d_in[7];
    const float* Wo  = (const float*)d_in[8];
    const float* bo  = (const float*)d_in[9];
    const float* ln1_s = (const float*)d_in[10];
    const float* ln1_b = (const float*)d_in[11];
    const float* ln2_s = (const float*)d_in[12];
    const float* ln2_b = (const float*)d_in[13];
    const float* W1  = (const float*)d_in[14];
    const float* b1  = (const float*)d_in[15];
    const float* W2  = (const float*)d_in[16];
    const float* b2  = (const float*)d_in[17];
    const float* Wout = (const float*)d_in[18];
    const float* bout = (const float*)d_in[19];
    const int* input_ids  = (const int*)d_in[20];
    const int* target_ids = (const int*)d_in[21];
    float* out = (float*)d_out;

    // ---- workspace carve ----
    char* wsb = (char*)d_ws;
    size_t off = 0;
    auto alloc = [&](size_t bytes) -> void* {
        off = (off + 255) & ~(size_t)255;
        void* p = wsb + off; off += bytes; return p;
    };
    u16* wqkvT = (u16*)alloc((size_t)4 * 1536 * D_ * 2);
    u16* woT   = (u16*)alloc((size_t)4 * D_ * D_ * 2);
    u16* w1T   = (u16*)alloc((size_t)4 * D_ * F_ * 2);
    u16* w2T   = (u16*)alloc((size_t)4 * D_ * F_ * 2);
    u16* w2d   = (u16*)alloc((size_t)F_ * D_ * 2);
    u16* woutT = (u16*)alloc((size_t)V_ * D_ * 2);
    u16* G_b   = (u16*)alloc((size_t)D_ * D_ * 2);
    float* qkvb = (float*)alloc((size_t)4 * 1536 * 4);
    float* bufA = (float*)alloc((size_t)MF_ * 4);
    float* bufB = (float*)alloc((size_t)MD_ * 4);
    u16* h_b    = (u16*)alloc((size_t)MD_ * 2);
    u16* gelu_b = (u16*)alloc((size_t)MF_ * 2);
    u16* x16_b  = (u16*)alloc((size_t)MD_ * 2);
    float* cvec = (float*)alloc(D_ * 4);
    int* tcl    = (int*)alloc(M_ * 4);
    size_t uStart = (off + 255) & ~(size_t)255;
    // phase G (precompute)
    off = uStart;
    u16* woutD   = (u16*)alloc((size_t)V_ * D_ * 2);
    float* Gpart = (float*)alloc((size_t)16 * D_ * D_ * 4);
    size_t endG = off;
    // phase attention
    off = uStart;
    u16* q_b   = (u16*)alloc((size_t)MD_ * 2);
    u16* k_b   = (u16*)alloc((size_t)MD_ * 2);
    u16* v_b   = (u16*)alloc((size_t)MD_ * 2);
    u16* ctx_b = (u16*)alloc((size_t)MD_ * 2);
    size_t endA = off;
    // phase tail
    off = uStart;
    float* xA  = (float*)alloc((size_t)MD_ * 4);
    float* xB  = (float*)alloc((size_t)MD_ * 4);
    float* eb  = (float*)alloc((size_t)MD_ * 4);
    float* ec  = (float*)alloc((size_t)MD_ * 4);
    u16* xA_b  = (u16*)alloc((size_t)MD_ * 2);
    u16* xB_b  = (u16*)alloc((size_t)MD_ * 2);
    u16* xC_b  = (u16*)alloc((size_t)MD_ * 2);
    u16* eb_b  = (u16*)alloc((size_t)MD_ * 2);
    u16* x15b_b = (u16*)alloc((size_t)MF_ * 2);
    size_t endT = off;
    size_t need = endG > endA ? endG : endA;
    if (endT > need) need = endT;
    if (need > ws_size) return;

    dim3 blk(256);
    const long NL = 0;
    #define GZ nullptr, nullptr, nullptr, nullptr, nullptr, nullptr, nullptr

    // ---- precompute: 3 dispatches ----
    mega_prep<<<dim3(29697), blk, 0, stream>>>(Wq, Wk, Wv, Wo, W1, W2, Wout,
        bq, bk, bv, target_ids, wqkvT, woT, w1T, w2T, w2d, woutT, woutD, qkvb, tcl);
    cvec_kernel<<<dim3(D_), blk, 0, stream>>>(Wout, bout, cvec);
    // G = Wout @ Wout^T, split-K 16 x 1024
    mfma_gemm<128, 128, 4, 4, E_F32><<<dim3(4, 4, 16), blk, 0, stream>>>(
        woutD, woutD, Gpart, nullptr, nullptr, nullptr, nullptr, 1024, V_, V_, D_,
        (long)D_ * D_, 1024, 1.f, GZ);
    gred_kernel<<<dim3(1024), blk, 0, stream>>>(Gpart, G_b);

    // ---- forward sweep ----
    embed_kernel<<<dim3(512), blk, 0, stream>>>((const float4*)d_in[0], (const float4*)d_in[1],
                                                input_ids, (float4*)bufB);
    for (int b = 0; b < 4; ++b) {
        const size_t wDD = (size_t)b * D_ * D_, wDF = (size_t)b * D_ * F_;
        ln_fwd_kernel<<<dim3(M_), blk, 0, stream>>>(bufB, ln1_s + b * D_, ln1_b + b * D_, h_b);
        mfma_gemm<128, 64, 4, 2, E_QKV3><<<dim3(24, 8, 1), blk, 0, stream>>>(
            h_b, wqkvT + (size_t)b * 1536 * 512, nullptr, q_b, k_b, v_b,
            qkvb + b * 1536, D_, D_, D_, 0, NL, NL, 1.f, GZ);
        flash_attn<<<dim3(8, 16), blk, 0, stream>>>(q_b, k_b, v_b, ctx_b);
        mfma_gemm<64, 64, 2, 2, E_F32><<<dim3(8, 16, 1), blk, 0, stream>>>(
            ctx_b, woT + wDD, bufB, nullptr, nullptr, nullptr, bo + b * D_,
            D_, D_, D_, D_, NL, NL, 1.f, GZ);
        ln_fwd_kernel<<<dim3(M_), blk, 0, stream>>>(bufB, ln2_s + b * D_, ln2_b + b * D_, h_b);
        mfma_gemm<128, 128, 4, 4, E_GELU><<<dim3(16, 8, 1), blk, 0, stream>>>(
            h_b, w1T + wDF, (b == 3) ? bufA : nullptr, gelu_b, nullptr, nullptr, b1 + b * F_,
            D_, D_, D_, F_, NL, NL, 1.f, GZ);
        mfma_gemm<64, 64, 2, 2, E_F32><<<dim3(8, 16, 1), blk, 0, stream>>>(
            gelu_b, w2T + wDF, bufB, (b == 3) ? x16_b : nullptr, nullptr, nullptr, b2 + b * D_,
            F_, F_, F_, D_, NL, NL, 1.f, GZ);
    }
    // x15 f32 = bufA, x16 f32 = bufB, x16 bf16 = x16_b

    // ---- PC tail ----
    mfma_gemm<64, 64, 2, 2, E_TD><<<dim3(8, 16, 1), blk, 0, stream>>>(
        x16_b, G_b, xA, xA_b, nullptr, nullptr, nullptr, D_, D_, D_, D_, NL, NL, 1.f,
        bufB, nullptr, cvec, Wout, tcl, eb, eb_b);
    mfma_gemm<64, 64, 2, 2, E_TD><<<dim3(8, 16, 1), blk, 0, stream>>>(
        xA_b, G_b, xB, xB_b, nullptr, nullptr, nullptr, D_, D_, D_, D_, NL, NL, 1.f,
        xA, eb, cvec, Wout, tcl, nullptr, nullptr);
    mfma_gemm<128, 128, 4, 4, E_X15B><<<dim3(16, 8, 1), blk, 0, stream>>>(
        eb_b, w2d, nullptr, x15b_b, nullptr, nullptr, nullptr, D_, D_, D_, F_, NL, NL, 1.f,
        bufA, nullptr, nullptr, nullptr, nullptr, nullptr, nullptr);
    mfma_gemm<64, 64, 2, 2, E_EC><<<dim3(8, 16, 1), blk, 0, stream>>>(
        x15b_b, w2T + (size_t)3 * D_ * F_, ec, nullptr, nullptr, nullptr, b2 + 3 * D_,
        F_, F_, F_, D_, NL, NL, 1.f,
        xB, nullptr, nullptr, nullptr, nullptr, nullptr, nullptr);
    mfma_gemm<64, 64, 2, 2, E_TD><<<dim3(8, 16, 1), blk, 0, stream>>>(
        xB_b, G_b, nullptr, xC_b, nullptr, nullptr, nullptr, D_, D_, D_, D_, NL, NL, 1.f,
        xB, ec, cvec, Wout, tcl, nullptr, nullptr);
    // final: out = xC @ Wout + bout
    mfma_gemm<128, 128, 4, 4, E_F32><<<dim3(128, 8, 1), blk, 0, stream>>>(
        xC_b, woutT, out, nullptr, nullptr, nullptr, bout, D_, D_, D_, V_, NL, NL, 1.f, GZ);
    #undef GZ
}

// Round 5
// 566.915 us; speedup vs baseline: 9.7316x; 1.0409x over previous
//
#include <hip/hip_runtime.h>
#include <hip/hip_bf16.h>
#include <math.h>

#define D_   512
#define F_   2048
#define V_   16384
#define H_   8
#define DH_  64
#define S_   512
#define B_   2
#define M_   1024
#define MD_  (M_ * D_)
#define MF_  (M_ * F_)
#define GAMMA_ 0.1f

typedef unsigned int u32;
typedef unsigned short u16;
typedef __attribute__((ext_vector_type(4))) float f32x4;
typedef __attribute__((ext_vector_type(8))) short s16x8;
typedef __attribute__((ext_vector_type(4))) u16 u16x4;

__device__ __forceinline__ u16 f2b(float f) {
    __hip_bfloat16 h = __float2bfloat16(f);   // RTNE
    return *reinterpret_cast<u16*>(&h);
}
__device__ __forceinline__ u16x4 pack4(f32x4 v) {
    u16x4 o; o.x = f2b(v[0]); o.y = f2b(v[1]); o.z = f2b(v[2]); o.w = f2b(v[3]);
    return o;
}

__device__ __forceinline__ void gl_lds16(const void* g, void* l) {
    __builtin_amdgcn_global_load_lds((const __attribute__((address_space(1))) u32*)g,
                                     (__attribute__((address_space(3))) u32*)l, 16, 0, 0);
}

__device__ __forceinline__ float gelu_f(float v) {
    float u = 0.7978845608028654f * (v + 0.044715f * v * v * v);
    return 0.5f * v * (1.f + tanhf(u));
}

// 4x4 transpose across lane quads; lane b: reg r holds Sub[r][b] -> reg j holds Sub[b][j]
__device__ __forceinline__ f32x4 xpose4(f32x4 v, int b) {
#pragma unroll
    for (int s = 1; s < 4; s <<= 1) {
        f32x4 nv;
#pragma unroll
        for (int j = 0; j < 4; ++j) {
            float ex = __shfl_xor(v[j ^ s], s, 64);
            nv[j] = ((b ^ j) & s) ? ex : v[j];
        }
        v = nv;
    }
    return v;
}

// block reduction (blockDim.x == 256)
__device__ __forceinline__ float blk_sum(float v, float* sh) {
#pragma unroll
    for (int o = 32; o > 0; o >>= 1) v += __shfl_down(v, o, 64);
    int lane = threadIdx.x & 63, w = threadIdx.x >> 6;
    if (lane == 0) sh[w] = v;
    __syncthreads();
    float r = sh[0] + sh[1] + sh[2] + sh[3];
    __syncthreads();
    return r;
}

// wave-wide sum (64 lanes)
__device__ __forceinline__ float wave_sum(float v) {
#pragma unroll
    for (int o = 32; o > 0; o >>= 1) v += __shfl_xor(v, o, 64);
    return v;
}

// ================= MFMA GEMM (NT: A MxK row-major, B NxK row-major, bf16) ===========
// 2-phase LDS double-buffered pipeline (T3 minimal recipe).
#define E_F32   0
#define E_GELU  1
#define E_TD    2
#define E_X15B  3
#define E_EC    4
#define E_QKV3  5
#define E_OUT   6   // f32 + bias, nontemporal store (final logits)

template<int BM, int BN, int FM, int FN, int EPI>
__global__ __launch_bounds__(256)
void mfma_gemm(const u16* __restrict__ A, const u16* __restrict__ B,
               float* __restrict__ Cf, u16* __restrict__ Cb,
               u16* __restrict__ Cb2, u16* __restrict__ Cb3,
               const float* __restrict__ bias,
               int K, int lda, int ldb, int ldc,
               long sC, long sKz, float alpha,
               const float* __restrict__ base, const float* __restrict__ subv,
               const float* __restrict__ cvec, const float* __restrict__ woutF,
               const int* __restrict__ tcl,
               float* __restrict__ ebF, u16* __restrict__ ebB)
{
    constexpr int WC = BN / (FN * 16);
    static_assert((BM / (FM * 16)) * WC == 4, "4 waves");
    __shared__ __align__(16) u16 Asl[2][BM * 32];
    __shared__ __align__(16) u16 Bsl[2][BN * 32];
    const int t = threadIdx.x, l = t & 63, wid = t >> 6;
    const int m0 = blockIdx.y * BM, n0 = blockIdx.x * BN;
    const long z = blockIdx.z;
    A += z * sKz;
    B += z * sKz;
    if (Cf) Cf += z * sC;

    f32x4 acc[FM][FN] = {};
    const int rm = (wid / WC) * (FM * 16), cn = (wid % WC) * (FN * 16);
    const int lr = l & 15, hi = l >> 4;
    const int srow = t >> 2;                          // staging row within 64-group
    const int scol = ((t & 3) ^ ((t >> 3) & 3)) * 8;  // pre-swizzled global k-chunk (u16)
    const int ksw = (hi ^ ((lr >> 1) & 3)) * 8;       // swizzled read chunk (u16)

    auto stage = [&](int k0, int pb) {
#pragma unroll
        for (int i = 0; i < BM / 64; ++i)
            gl_lds16(A + (size_t)(m0 + i * 64 + srow) * lda + k0 + scol,
                     &Asl[pb][i * 2048 + t * 8]);
#pragma unroll
        for (int i = 0; i < BN / 64; ++i)
            gl_lds16(B + (size_t)(n0 + i * 64 + srow) * ldb + k0 + scol,
                     &Bsl[pb][i * 2048 + t * 8]);
    };
    auto compute = [&](int pb) {
        s16x8 av[FM], bv[FN];
#pragma unroll
        for (int fm = 0; fm < FM; ++fm)
            av[fm] = *(const s16x8*)&Asl[pb][(rm + fm * 16 + lr) * 32 + ksw];
#pragma unroll
        for (int fn = 0; fn < FN; ++fn)
            bv[fn] = *(const s16x8*)&Bsl[pb][(cn + fn * 16 + lr) * 32 + ksw];
#pragma unroll
        for (int fm = 0; fm < FM; ++fm)
#pragma unroll
            for (int fn = 0; fn < FN; ++fn)
                acc[fm][fn] = __builtin_amdgcn_mfma_f32_16x16x32_bf16(av[fm], bv[fn], acc[fm][fn], 0, 0, 0);
    };

    stage(0, 0);
    __syncthreads();               // drains vmcnt: buf0 ready
    int cur = 0;
    for (int k0 = 32; k0 < K; k0 += 32) {
        stage(k0, cur ^ 1);        // overlap next-tile load with current compute
        compute(cur);
        __syncthreads();           // next buf staged + all waves done reading cur
        cur ^= 1;
    }
    compute(cur);

    // epilogue: per-fragment 4x4 transpose -> lane holds row (hi*4+qb), 4 consecutive cols
    const int qb = lr & 3, qi = lr >> 2;
#pragma unroll
    for (int fm = 0; fm < FM; ++fm)
#pragma unroll
        for (int fn = 0; fn < FN; ++fn) {
            const int gm = m0 + rm + fm * 16 + hi * 4 + qb;
            const int gn0 = n0 + cn + fn * 16 + qi * 4;
            const size_t idx0 = (size_t)gm * ldc + gn0;
            if constexpr (EPI == E_QKV3) {
                const int gnf = n0 + cn + fn * 16;   // fragment n-base (sel uniform)
                const int sel = gnf >> 9;
                if (sel < 2) {
                    f32x4 v = xpose4(acc[fm][fn], qb);
                    f32x4 bv4 = *(const f32x4*)&bias[gn0];
#pragma unroll
                    for (int j = 0; j < 4; ++j) v[j] += bv4[j];
                    int b = gm >> 9, s = gm & (S_ - 1);
                    int d9 = gn0 & 511, h = d9 >> 6, d = d9 & 63;
                    u16* dst = (sel == 0) ? Cb : Cb2;
                    *(u16x4*)&dst[(((size_t)(b * H_ + h) * S_ + s) << 6) + d] = pack4(v);
                } else {
                    // V: store pre-transpose fragment directly to V^T (B,H,dh,S)
                    const int gnl = gnf + lr;        // this lane's d-column
                    const int gm0 = m0 + rm + fm * 16 + hi * 4;
                    int b = gm0 >> 9, s0 = gm0 & (S_ - 1);
                    int d9 = gnl & 511, h = d9 >> 6, d = d9 & 63;
                    float bb = bias[gnl];
                    f32x4 v = acc[fm][fn];
#pragma unroll
                    for (int j = 0; j < 4; ++j) v[j] += bb;
                    *(u16x4*)&Cb3[((((size_t)(b * H_ + h)) << 6) + d) * S_ + s0] = pack4(v);
                }
            } else {
                f32x4 v = xpose4(acc[fm][fn], qb);
                if constexpr (EPI == E_F32) {
#pragma unroll
                    for (int j = 0; j < 4; ++j) v[j] *= alpha;
                    if (bias) {
                        f32x4 bv4 = *(const f32x4*)&bias[gn0];
#pragma unroll
                        for (int j = 0; j < 4; ++j) v[j] += bv4[j];
                    }
                    *(f32x4*)&Cf[idx0] = v;
                    if (Cb) *(u16x4*)&Cb[idx0] = pack4(v);
                } else if constexpr (EPI == E_OUT) {
                    f32x4 bv4 = *(const f32x4*)&bias[gn0];
#pragma unroll
                    for (int j = 0; j < 4; ++j) v[j] += bv4[j];
                    __builtin_nontemporal_store(v, (f32x4*)&Cf[idx0]);
                } else if constexpr (EPI == E_GELU) {
                    f32x4 bv4 = *(const f32x4*)&bias[gn0];
#pragma unroll
                    for (int j = 0; j < 4; ++j) v[j] = gelu_f(v[j] + bv4[j]);
                    if (Cf) *(f32x4*)&Cf[idx0] = v;
                    *(u16x4*)&Cb[idx0] = pack4(v);
                } else if constexpr (EPI == E_TD) {
                    const int tc = tcl[gm];
                    f32x4 cv4 = *(const f32x4*)&cvec[gn0];
                    f32x4 ba4 = *(const f32x4*)&base[idx0];
                    f32x4 dlt, o2;
#pragma unroll
                    for (int j = 0; j < 4; ++j) {
                        float d = v[j] + cv4[j] - woutF[(size_t)(gn0 + j) * V_ + tc];
                        dlt[j] = GAMMA_ * d;
                    }
                    if (subv) {
                        f32x4 sv4 = *(const f32x4*)&subv[idx0];
#pragma unroll
                        for (int j = 0; j < 4; ++j) dlt[j] -= GAMMA_ * sv4[j];
                    }
#pragma unroll
                    for (int j = 0; j < 4; ++j) o2[j] = ba4[j] + dlt[j];
                    if (Cf) *(f32x4*)&Cf[idx0] = o2;
                    *(u16x4*)&Cb[idx0] = pack4(o2);
                    if (ebF) *(f32x4*)&ebF[idx0] = dlt;
                    if (ebB) *(u16x4*)&ebB[idx0] = pack4(dlt);
                } else if constexpr (EPI == E_X15B) {
                    f32x4 ba4 = *(const f32x4*)&base[idx0];
#pragma unroll
                    for (int j = 0; j < 4; ++j) v[j] = ba4[j] + GAMMA_ * v[j];
                    *(u16x4*)&Cb[idx0] = pack4(v);
                } else if constexpr (EPI == E_EC) {
                    f32x4 ba4 = *(const f32x4*)&base[idx0];
                    f32x4 bv4 = *(const f32x4*)&bias[gn0];
#pragma unroll
                    for (int j = 0; j < 4; ++j) v[j] = ba4[j] - (v[j] + bv4[j]);
                    *(f32x4*)&Cf[idx0] = v;
                }
            }
        }
}

// ================= fused causal flash attention (2-phase K/V pipeline) =================
// grid: (S/64, B*H); 4 waves, wave w owns q-rows [qt*64+w*16, +16)
__global__ __launch_bounds__(256)
void flash_attn(const u16* __restrict__ q, const u16* __restrict__ k,
                const u16* __restrict__ vT, u16* __restrict__ ctx)
{
    __shared__ __align__(16) u16 Ks[2][64 * 64];
    __shared__ __align__(16) u16 Vs[2][64 * 64];
    __shared__ __align__(16) u16 Ps[4][16 * 64];
    const int t = threadIdx.x, l = t & 63, w = t >> 6;
    const int qt = blockIdx.x, z = blockIdx.y;
    const int bb = z >> 3, hh = z & 7;
    const int lr = l & 15, hi = l >> 4;
    const u16* qp = q + (((size_t)z * S_ + qt * 64 + w * 16) << 6);
    const u16* kp = k + ((size_t)z * S_ << 6);
    const u16* vp = vT + (((size_t)z) << 6) * S_;

    const s16x8 aq0 = *(const s16x8*)&qp[lr * 64 + hi * 8];
    const s16x8 aq1 = *(const s16x8*)&qp[lr * 64 + 32 + hi * 8];

    f32x4 o[4] = {};
    float m[4], ls[4];
#pragma unroll
    for (int r = 0; r < 4; ++r) { m[r] = -3.0e38f; ls[r] = 0.f; }
    const int qrow = qt * 64 + w * 16 + hi * 4;
    const int srow = t >> 3, scl = t & 7;
    const int cg1 = (scl ^ (srow & 7)) * 8;
    const int srow2 = srow + 32;
    const int cg2 = (scl ^ (srow2 & 7)) * 8;
    const int sw7 = (lr & 7);

    auto stage = [&](int j, int pb) {
        gl_lds16(kp + ((size_t)(j * 64 + srow) << 6) + cg1, &Ks[pb][t * 8]);
        gl_lds16(vp + (size_t)srow * S_ + j * 64 + cg1, &Vs[pb][t * 8]);
        gl_lds16(kp + ((size_t)(j * 64 + srow2) << 6) + cg2, &Ks[pb][(t + 256) * 8]);
        gl_lds16(vp + (size_t)srow2 * S_ + j * 64 + cg2, &Vs[pb][(t + 256) * 8]);
    };

    stage(0, 0);
    __syncthreads();
    int cur = 0;
    for (int j = 0; j <= qt; ++j) {
        if (j < qt) stage(j + 1, cur ^ 1);

        float pv[4][4];
#pragma unroll
        for (int fn = 0; fn < 4; ++fn) {
            f32x4 acc = {};
            acc = __builtin_amdgcn_mfma_f32_16x16x32_bf16(aq0,
                    *(const s16x8*)&Ks[cur][((fn * 16 + lr) << 6) + ((hi ^ sw7) * 8)], acc, 0, 0, 0);
            acc = __builtin_amdgcn_mfma_f32_16x16x32_bf16(aq1,
                    *(const s16x8*)&Ks[cur][((fn * 16 + lr) << 6) + (((hi + 4) ^ sw7) * 8)], acc, 0, 0, 0);
#pragma unroll
            for (int r = 0; r < 4; ++r) pv[fn][r] = acc[r] * 0.125f;
        }
        if (j == qt) {
#pragma unroll
            for (int fn = 0; fn < 4; ++fn) {
                int col = j * 64 + fn * 16 + lr;
#pragma unroll
                for (int r = 0; r < 4; ++r)
                    if (col > qrow + r) pv[fn][r] = -3.0e38f;
            }
        }
        float sc[4], rs[4];
#pragma unroll
        for (int r = 0; r < 4; ++r) {
            float x = fmaxf(fmaxf(pv[0][r], pv[1][r]), fmaxf(pv[2][r], pv[3][r]));
#pragma unroll
            for (int off = 1; off < 16; off <<= 1) x = fmaxf(x, __shfl_xor(x, off, 64));
            float nm = fmaxf(m[r], x);
            sc[r] = expf(m[r] - nm);
            m[r] = nm;
            rs[r] = 0.f;
        }
#pragma unroll
        for (int fn = 0; fn < 4; ++fn)
#pragma unroll
            for (int r = 0; r < 4; ++r) {
                float p = expf(pv[fn][r] - m[r]);
                pv[fn][r] = p;
                rs[r] += p;
            }
#pragma unroll
        for (int r = 0; r < 4; ++r) {
#pragma unroll
            for (int off = 1; off < 16; off <<= 1) rs[r] += __shfl_xor(rs[r], off, 64);
            ls[r] = ls[r] * sc[r] + rs[r];
        }
#pragma unroll
        for (int fn = 0; fn < 4; ++fn)
#pragma unroll
            for (int r = 0; r < 4; ++r) o[fn][r] *= sc[r];
        // P bounce via per-wave LDS (swizzled both sides, wave-local RAW)
#pragma unroll
        for (int fn = 0; fn < 4; ++fn)
#pragma unroll
            for (int r = 0; r < 4; ++r) {
                int qr = hi * 4 + r;
                int ci = (2 * fn + (lr >> 3)) ^ (qr & 7);
                Ps[w][qr * 64 + ci * 8 + (lr & 7)] = f2b(pv[fn][r]);
            }
#pragma unroll
        for (int ks = 0; ks < 2; ++ks) {
            const s16x8 pa = *(const s16x8*)&Ps[w][lr * 64 + (((4 * ks + hi) ^ sw7) * 8)];
#pragma unroll
            for (int fn = 0; fn < 4; ++fn)
                o[fn] = __builtin_amdgcn_mfma_f32_16x16x32_bf16(pa,
                        *(const s16x8*)&Vs[cur][((fn * 16 + lr) << 6) + (((hi + 4 * ks) ^ sw7) * 8)], o[fn], 0, 0, 0);
        }
        __syncthreads();
        cur ^= 1;
    }
    float inv[4];
#pragma unroll
    for (int r = 0; r < 4; ++r) inv[r] = 1.f / ls[r];
    u16* cp = ctx + ((size_t)(bb * S_ + qt * 64 + w * 16) * D_) + hh * 64;
    const int qb = lr & 3, qi = lr >> 2;
#pragma unroll
    for (int fn = 0; fn < 4; ++fn) {
        f32x4 v = o[fn];
#pragma unroll
        for (int r = 0; r < 4; ++r) v[r] *= inv[r];
        v = xpose4(v, qb);
        *(u16x4*)&cp[(size_t)(hi * 4 + qb) * D_ + fn * 16 + qi * 4] = pack4(v);
    }
}

// ============ mega precompute ============
__device__ __forceinline__ void tr_tile(const float* __restrict__ in, u16* __restrict__ out,
                                        int R, int C, int tx, int ty, float (*tile)[33])
{
    int c0 = tx * 32, r0 = ty * 32;
    int tr = threadIdx.x >> 3, tc4 = (threadIdx.x & 7) * 4;
    const float4 v = *(const float4*)&in[(size_t)(r0 + tr) * C + c0 + tc4];
    tile[tr][tc4 + 0] = v.x; tile[tr][tc4 + 1] = v.y;
    tile[tr][tc4 + 2] = v.z; tile[tr][tc4 + 3] = v.w;
    __syncthreads();
    u16x4 o;
    o.x = f2b(tile[tc4 + 0][tr]); o.y = f2b(tile[tc4 + 1][tr]);
    o.z = f2b(tile[tc4 + 2][tr]); o.w = f2b(tile[tc4 + 3][tr]);
    *(u16x4*)&out[(size_t)(c0 + tr) * R + r0 + tc4] = o;
}

__device__ __forceinline__ void cvt_blk(const float* __restrict__ in, u16* __restrict__ out,
                                        int blk)
{
    int i0 = blk * 1024 + threadIdx.x * 4;
    float4 v = *(const float4*)&in[i0];
    u16x4 o; o.x = f2b(v.x); o.y = f2b(v.y); o.z = f2b(v.z); o.w = f2b(v.w);
    *(u16x4*)&out[i0] = o;
}

__global__ __launch_bounds__(256)
void mega_prep(const float* __restrict__ Wq, const float* __restrict__ Wk,
               const float* __restrict__ Wv, const float* __restrict__ Wo,
               const float* __restrict__ W1, const float* __restrict__ W2,
               const float* __restrict__ Wout,
               const float* __restrict__ bq, const float* __restrict__ bk,
               const float* __restrict__ bv, const int* __restrict__ target_ids,
               u16* __restrict__ wqkvT, u16* __restrict__ woT, u16* __restrict__ w1T,
               u16* __restrict__ w2T, u16* __restrict__ w2d, u16* __restrict__ woutT,
               u16* __restrict__ woutD, float* __restrict__ qkvb, int* __restrict__ tcl)
{
    __shared__ float tile[32][33];
    const int g = blockIdx.x, t = threadIdx.x;
    if (g < 3072) {
        int sel = g >> 10, rem = g & 1023, z = rem >> 8, tl = rem & 255;
        const float* src = (sel == 0 ? Wq : sel == 1 ? Wk : Wv) + (size_t)z * 262144;
        u16* dst = wqkvT + (size_t)z * 786432 + sel * 262144;
        tr_tile(src, dst, 512, 512, tl & 15, tl >> 4, tile);
    } else if (g < 4096) {
        int rem = g - 3072, z = rem >> 8, tl = rem & 255;
        tr_tile(Wo + (size_t)z * 262144, woT + (size_t)z * 262144, 512, 512, tl & 15, tl >> 4, tile);
    } else if (g < 8192) {
        int rem = g - 4096, z = rem >> 10, tl = rem & 1023;
        tr_tile(W1 + (size_t)z * 1048576, w1T + (size_t)z * 1048576, 512, 2048, tl & 63, tl >> 6, tile);
    } else if (g < 12288) {
        int rem = g - 8192, z = rem >> 10, tl = rem & 1023;
        tr_tile(W2 + (size_t)z * 1048576, w2T + (size_t)z * 1048576, 2048, 512, tl & 15, tl >> 4, tile);
    } else if (g < 20480) {
        int tl = g - 12288;
        tr_tile(Wout, woutT, 512, 16384, tl & 511, tl >> 9, tile);
    } else if (g < 21504) {
        cvt_blk(W2 + (size_t)3 * F_ * D_, w2d, g - 20480);
    } else if (g < 29696) {
        cvt_blk(Wout, woutD, g - 21504);
    } else {
        for (int i = t; i < M_; i += 256) {
            int v = target_ids[i];
            tcl[i] = v < 0 ? 0 : (v > V_ - 1 ? V_ - 1 : v);
        }
        for (int i = t; i < 4 * 1536; i += 256) {
            int b = i / 1536, j = i - b * 1536;
            qkvb[i] = (j < 512) ? bq[b * 512 + j]
                    : (j < 1024) ? bk[b * 512 + j - 512] : bv[b * 512 + j - 1024];
        }
    }
}

__global__ __launch_bounds__(256)
void cvec_kernel(const float* __restrict__ Wout, const float* __restrict__ bout,
                 float* __restrict__ c)
{
    __shared__ float sh[4];
    int d = blockIdx.x;
    const float* row = Wout + (size_t)d * V_;
    float s = 0.f;
    for (int v = threadIdx.x * 4; v < V_; v += 1024) {
        float4 a = *(const float4*)&row[v];
        float4 b = *(const float4*)&bout[v];
        s += a.x * b.x + a.y * b.y + a.z * b.z + a.w * b.w;
    }
    float r = blk_sum(s, sh);
    if (threadIdx.x == 0) c[d] = r;
}

__global__ void gred_kernel(const float* __restrict__ P, u16* __restrict__ G)
{
    int i = blockIdx.x * blockDim.x + threadIdx.x;
    if (i < D_ * D_) {
        float s = 0.f;
#pragma unroll
        for (int zz = 0; zz < 16; ++zz) s += P[(size_t)zz * D_ * D_ + i];
        G[i] = f2b(s);
    }
}

__global__ void embed_kernel(const float4* __restrict__ we, const float4* __restrict__ pe,
                             const int* __restrict__ ids, float4* __restrict__ o)
{
    int t = blockIdx.x * blockDim.x + threadIdx.x;
    int d4 = t & 127, row = t >> 7;
    int ss = row & (S_ - 1);
    int id = ids[row];
    id = id < 0 ? 0 : (id > V_ - 1 ? V_ - 1 : id);
    float4 a = we[(size_t)id * 128 + d4];
    float4 b = pe[(size_t)ss * 128 + d4];
    o[(size_t)row * 128 + d4] = make_float4(a.x + b.x, a.y + b.y, a.z + b.z, a.w + b.w);
}

// LayerNorm: wave-per-row (no LDS, no barriers); grid = M/4, block = 256
__global__ __launch_bounds__(256)
void ln_fwd_kernel(const float* __restrict__ x, const float* __restrict__ s,
                   const float* __restrict__ bb, u16* __restrict__ h)
{
    const int l = threadIdx.x & 63, w = threadIdx.x >> 6;
    const int row = blockIdx.x * 4 + w;
    const float* xr = x + (size_t)row * D_;
    const int c0 = l * 8;
    float4 a = *(const float4*)&xr[c0];
    float4 b = *(const float4*)&xr[c0 + 4];
    float sum = a.x + a.y + a.z + a.w + b.x + b.y + b.z + b.w;
    float mu = wave_sum(sum) * (1.f / D_);
    float d0 = a.x - mu, d1 = a.y - mu, d2 = a.z - mu, d3 = a.w - mu;
    float d4 = b.x - mu, d5 = b.y - mu, d6 = b.z - mu, d7 = b.w - mu;
    float vs = d0*d0 + d1*d1 + d2*d2 + d3*d3 + d4*d4 + d5*d5 + d6*d6 + d7*d7;
    float var = wave_sum(vs) * (1.f / D_);
    float r = rsqrtf(var + 1e-5f);
    float4 s0 = *(const float4*)&s[c0], s1 = *(const float4*)&s[c0 + 4];
    float4 b0 = *(const float4*)&bb[c0], b1 = *(const float4*)&bb[c0 + 4];
    u16* hr = h + (size_t)row * D_;
    f32x4 o0, o1;
    o0[0] = d0 * r * s0.x + b0.x; o0[1] = d1 * r * s0.y + b0.y;
    o0[2] = d2 * r * s0.z + b0.z; o0[3] = d3 * r * s0.w + b0.w;
    o1[0] = d4 * r * s1.x + b1.x; o1[1] = d5 * r * s1.y + b1.y;
    o1[2] = d6 * r * s1.z + b1.z; o1[3] = d7 * r * s1.w + b1.w;
    *(u16x4*)&hr[c0] = pack4(o0);
    *(u16x4*)&hr[c0 + 4] = pack4(o1);
}

// ================= host =================
extern "C" void kernel_launch(void* const* d_in, const int* in_sizes, int n_in,
                              void* d_out, int out_size, void* d_ws, size_t ws_size,
                              hipStream_t stream)
{
    (void)in_sizes; (void)n_in; (void)out_size;
    const float* Wq  = (const float*)d_in[2];
    const float* Wk  = (const float*)d_in[3];
    const float* Wv  = (const float*)d_in[4];
    const float* bq  = (const float*)d_in[5];
    const float* bk  = (const float*)d_in[6];
    const float* bv  = (const float*)d_in[7];
    const float* Wo  = (const float*)d_in[8];
    const float* bo  = (const float*)d_in[9];
    const float* ln1_s = (const float*)d_in[10];
    const float* ln1_b = (const float*)d_in[11];
    const float* ln2_s = (const float*)d_in[12];
    const float* ln2_b = (const float*)d_in[13];
    const float* W1  = (const float*)d_in[14];
    const float* b1  = (const float*)d_in[15];
    const float* W2  = (const float*)d_in[16];
    const float* b2  = (const float*)d_in[17];
    const float* Wout = (const float*)d_in[18];
    const float* bout = (const float*)d_in[19];
    const int* input_ids  = (const int*)d_in[20];
    const int* target_ids = (const int*)d_in[21];
    float* out = (float*)d_out;

    // ---- workspace carve ----
    char* wsb = (char*)d_ws;
    size_t off = 0;
    auto alloc = [&](size_t bytes) -> void* {
        off = (off + 255) & ~(size_t)255;
        void* p = wsb + off; off += bytes; return p;
    };
    u16* wqkvT = (u16*)alloc((size_t)4 * 1536 * D_ * 2);
    u16* woT   = (u16*)alloc((size_t)4 * D_ * D_ * 2);
    u16* w1T   = (u16*)alloc((size_t)4 * D_ * F_ * 2);
    u16* w2T   = (u16*)alloc((size_t)4 * D_ * F_ * 2);
    u16* w2d   = (u16*)alloc((size_t)F_ * D_ * 2);
    u16* woutT = (u16*)alloc((size_t)V_ * D_ * 2);
    u16* G_b   = (u16*)alloc((size_t)D_ * D_ * 2);
    float* qkvb = (float*)alloc((size_t)4 * 1536 * 4);
    float* bufA = (float*)alloc((size_t)MF_ * 4);
    float* bufB = (float*)alloc((size_t)MD_ * 4);
    u16* h_b    = (u16*)alloc((size_t)MD_ * 2);
    u16* gelu_b = (u16*)alloc((size_t)MF_ * 2);
    u16* x16_b  = (u16*)alloc((size_t)MD_ * 2);
    float* cvec = (float*)alloc(D_ * 4);
    int* tcl    = (int*)alloc(M_ * 4);
    size_t uStart = (off + 255) & ~(size_t)255;
    // phase G
    off = uStart;
    u16* woutD   = (u16*)alloc((size_t)V_ * D_ * 2);
    float* Gpart = (float*)alloc((size_t)16 * D_ * D_ * 4);
    size_t endG = off;
    // phase attention
    off = uStart;
    u16* q_b   = (u16*)alloc((size_t)MD_ * 2);
    u16* k_b   = (u16*)alloc((size_t)MD_ * 2);
    u16* v_b   = (u16*)alloc((size_t)MD_ * 2);
    u16* ctx_b = (u16*)alloc((size_t)MD_ * 2);
    size_t endA = off;
    // phase tail
    off = uStart;
    float* xA  = (float*)alloc((size_t)MD_ * 4);
    float* xB  = (float*)alloc((size_t)MD_ * 4);
    float* eb  = (float*)alloc((size_t)MD_ * 4);
    float* ec  = (float*)alloc((size_t)MD_ * 4);
    u16* xA_b  = (u16*)alloc((size_t)MD_ * 2);
    u16* xB_b  = (u16*)alloc((size_t)MD_ * 2);
    u16* xC_b  = (u16*)alloc((size_t)MD_ * 2);
    u16* eb_b  = (u16*)alloc((size_t)MD_ * 2);
    u16* x15b_b = (u16*)alloc((size_t)MF_ * 2);
    size_t endT = off;
    size_t need = endG > endA ? endG : endA;
    if (endT > need) need = endT;
    if (need > ws_size) return;

    dim3 blk(256);
    const long NL = 0;
    #define GZ nullptr, nullptr, nullptr, nullptr, nullptr, nullptr, nullptr

    // ---- precompute ----
    mega_prep<<<dim3(29697), blk, 0, stream>>>(Wq, Wk, Wv, Wo, W1, W2, Wout,
        bq, bk, bv, target_ids, wqkvT, woT, w1T, w2T, w2d, woutT, woutD, qkvb, tcl);
    cvec_kernel<<<dim3(D_), blk, 0, stream>>>(Wout, bout, cvec);
    mfma_gemm<128, 128, 4, 4, E_F32><<<dim3(4, 4, 16), blk, 0, stream>>>(
        woutD, woutD, Gpart, nullptr, nullptr, nullptr, nullptr, 1024, V_, V_, D_,
        (long)D_ * D_, 1024, 1.f, GZ);
    gred_kernel<<<dim3(1024), blk, 0, stream>>>(Gpart, G_b);

    // ---- forward sweep ----
    embed_kernel<<<dim3(512), blk, 0, stream>>>((const float4*)d_in[0], (const float4*)d_in[1],
                                                input_ids, (float4*)bufB);
    for (int b = 0; b < 4; ++b) {
        const size_t wDD = (size_t)b * D_ * D_, wDF = (size_t)b * D_ * F_;
        ln_fwd_kernel<<<dim3(M_ / 4), blk, 0, stream>>>(bufB, ln1_s + b * D_, ln1_b + b * D_, h_b);
        mfma_gemm<128, 64, 4, 2, E_QKV3><<<dim3(24, 8, 1), blk, 0, stream>>>(
            h_b, wqkvT + (size_t)b * 1536 * 512, nullptr, q_b, k_b, v_b,
            qkvb + b * 1536, D_, D_, D_, 0, NL, NL, 1.f, GZ);
        flash_attn<<<dim3(8, 16), blk, 0, stream>>>(q_b, k_b, v_b, ctx_b);
        mfma_gemm<64, 64, 2, 2, E_F32><<<dim3(8, 16, 1), blk, 0, stream>>>(
            ctx_b, woT + wDD, bufB, nullptr, nullptr, nullptr, bo + b * D_,
            D_, D_, D_, D_, NL, NL, 1.f, GZ);
        ln_fwd_kernel<<<dim3(M_ / 4), blk, 0, stream>>>(bufB, ln2_s + b * D_, ln2_b + b * D_, h_b);
        mfma_gemm<128, 128, 4, 4, E_GELU><<<dim3(16, 8, 1), blk, 0, stream>>>(
            h_b, w1T + wDF, (b == 3) ? bufA : nullptr, gelu_b, nullptr, nullptr, b1 + b * F_,
            D_, D_, D_, F_, NL, NL, 1.f, GZ);
        mfma_gemm<64, 64, 2, 2, E_F32><<<dim3(8, 16, 1), blk, 0, stream>>>(
            gelu_b, w2T + wDF, bufB, (b == 3) ? x16_b : nullptr, nullptr, nullptr, b2 + b * D_,
            F_, F_, F_, D_, NL, NL, 1.f, GZ);
    }
    // x15 f32 = bufA, x16 f32 = bufB, x16 bf16 = x16_b

    // ---- PC tail ----
    mfma_gemm<64, 64, 2, 2, E_TD><<<dim3(8, 16, 1), blk, 0, stream>>>(
        x16_b, G_b, xA, xA_b, nullptr, nullptr, nullptr, D_, D_, D_, D_, NL, NL, 1.f,
        bufB, nullptr, cvec, Wout, tcl, eb, eb_b);
    mfma_gemm<64, 64, 2, 2, E_TD><<<dim3(8, 16, 1), blk, 0, stream>>>(
        xA_b, G_b, xB, xB_b, nullptr, nullptr, nullptr, D_, D_, D_, D_, NL, NL, 1.f,
        xA, eb, cvec, Wout, tcl, nullptr, nullptr);
    mfma_gemm<128, 128, 4, 4, E_X15B><<<dim3(16, 8, 1), blk, 0, stream>>>(
        eb_b, w2d, nullptr, x15b_b, nullptr, nullptr, nullptr, D_, D_, D_, F_, NL, NL, 1.f,
        bufA, nullptr, nullptr, nullptr, nullptr, nullptr, nullptr);
    mfma_gemm<64, 64, 2, 2, E_EC><<<dim3(8, 16, 1), blk, 0, stream>>>(
        x15b_b, w2T + (size_t)3 * D_ * F_, ec, nullptr, nullptr, nullptr, b2 + 3 * D_,
        F_, F_, F_, D_, NL, NL, 1.f,
        xB, nullptr, nullptr, nullptr, nullptr, nullptr, nullptr);
    mfma_gemm<64, 64, 2, 2, E_TD><<<dim3(8, 16, 1), blk, 0, stream>>>(
        xB_b, G_b, nullptr, xC_b, nullptr, nullptr, nullptr, D_, D_, D_, D_, NL, NL, 1.f,
        xB, ec, cvec, Wout, tcl, nullptr, nullptr);
    // final: out = xC @ Wout + bout (nontemporal f32 stores)
    mfma_gemm<128, 128, 4, 4, E_OUT><<<dim3(128, 8, 1), blk, 0, stream>>>(
        xC_b, woutT, out, nullptr, nullptr, nullptr, bout, D_, D_, D_, V_, NL, NL, 1.f, GZ);
    #undef GZ
}

// Round 6
// 449.972 us; speedup vs baseline: 12.2608x; 1.2599x over previous
//
#include <hip/hip_runtime.h>
#include <hip/hip_bf16.h>
#include <math.h>

#define D_   512
#define F_   2048
#define V_   16384
#define H_   8
#define DH_  64
#define S_   512
#define B_   2
#define M_   1024
#define MD_  (M_ * D_)
#define MF_  (M_ * F_)
#define GAMMA_ 0.1f

typedef unsigned int u32;
typedef unsigned short u16;
typedef __attribute__((ext_vector_type(4))) float f32x4;
typedef __attribute__((ext_vector_type(8))) short s16x8;
typedef __attribute__((ext_vector_type(4))) u16 u16x4;
typedef __attribute__((ext_vector_type(8))) u16 u16x8;

__device__ __forceinline__ u16 f2b(float f) {
    __hip_bfloat16 h = __float2bfloat16(f);   // RTNE
    return *reinterpret_cast<u16*>(&h);
}
__device__ __forceinline__ u16x4 pack4(f32x4 v) {
    u16x4 o; o.x = f2b(v[0]); o.y = f2b(v[1]); o.z = f2b(v[2]); o.w = f2b(v[3]);
    return o;
}

__device__ __forceinline__ void gl_lds16(const void* g, void* l) {
    __builtin_amdgcn_global_load_lds((const __attribute__((address_space(1))) u32*)g,
                                     (__attribute__((address_space(3))) u32*)l, 16, 0, 0);
}

__device__ __forceinline__ float gelu_f(float v) {
    float u = 0.7978845608028654f * (v + 0.044715f * v * v * v);
    return 0.5f * v * (1.f + tanhf(u));
}

// 4x4 transpose across lane quads; lane b: reg r holds Sub[r][b] -> reg j holds Sub[b][j]
__device__ __forceinline__ f32x4 xpose4(f32x4 v, int b) {
#pragma unroll
    for (int s = 1; s < 4; s <<= 1) {
        f32x4 nv;
#pragma unroll
        for (int j = 0; j < 4; ++j) {
            float ex = __shfl_xor(v[j ^ s], s, 64);
            nv[j] = ((b ^ j) & s) ? ex : v[j];
        }
        v = nv;
    }
    return v;
}

__device__ __forceinline__ float blk_sum(float v, float* sh) {
#pragma unroll
    for (int o = 32; o > 0; o >>= 1) v += __shfl_down(v, o, 64);
    int lane = threadIdx.x & 63, w = threadIdx.x >> 6;
    if (lane == 0) sh[w] = v;
    __syncthreads();
    float r = sh[0] + sh[1] + sh[2] + sh[3];
    __syncthreads();
    return r;
}

__device__ __forceinline__ float wave_sum(float v) {
#pragma unroll
    for (int o = 32; o > 0; o >>= 1) v += __shfl_xor(v, o, 64);
    return v;
}

// ================= MFMA GEMM (NT: A MxK row-major, B NxK row-major, bf16) ===========
// 2-phase LDS double-buffered pipeline, parameterized BK.
#define E_F32   0
#define E_GELU  1
#define E_TD    2
#define E_X15B  3
#define E_EC    4
#define E_QKV3  5
#define E_OUT   6   // f32 + bias (final logits)

// per-BK bank-conflict-free chunk swizzle (chunk = 8 u16 = 16 B)
template<int BK>
__device__ __forceinline__ int swz(int c, int row) {
    if constexpr (BK == 32) return c ^ ((row >> 1) & 3);
    else                    return c ^ (row & 7);
}

template<int BM, int BN, int BK, int FM, int FN, int EPI>
__global__ __launch_bounds__(256)
void mfma_gemm(const u16* __restrict__ A, const u16* __restrict__ B,
               float* __restrict__ Cf, u16* __restrict__ Cb,
               u16* __restrict__ Cb2, u16* __restrict__ Cb3,
               const float* __restrict__ bias,
               int K, int lda, int ldb, int ldc,
               long sC, long sKz, float alpha,
               const float* __restrict__ base, const float* __restrict__ subv,
               const float* __restrict__ cvec, const float* __restrict__ woutF,
               const int* __restrict__ tcl,
               float* __restrict__ ebF, u16* __restrict__ ebB)
{
    constexpr int WC = BN / (FN * 16);
    static_assert((BM / (FM * 16)) * WC == 4, "4 waves");
    constexpr int LPR = BK / 8;      // lanes per staged row
    constexpr int RPI = 2048 / BK;   // rows per 4KB issue
    __shared__ __align__(16) u16 Asl[2][BM * BK];
    __shared__ __align__(16) u16 Bsl[2][BN * BK];
    const int t = threadIdx.x, l = t & 63, wid = t >> 6;
    const int m0 = blockIdx.y * BM, n0 = blockIdx.x * BN;
    const long z = blockIdx.z;
    A += z * sKz;
    B += z * sKz;
    if (Cf) Cf += z * sC;

    f32x4 acc[FM][FN] = {};
    const int rm = (wid / WC) * (FM * 16), cn = (wid % WC) * (FN * 16);
    const int lr = l & 15, hi = l >> 4;
    const int srl = t / LPR, sc = t % LPR;

    auto stage = [&](int k0, int pb) {
#pragma unroll
        for (int i = 0; i < BM / RPI; ++i) {
            int row = i * RPI + srl;
            gl_lds16(A + (size_t)(m0 + row) * lda + k0 + swz<BK>(sc, row) * 8,
                     &Asl[pb][i * 2048 + t * 8]);
        }
#pragma unroll
        for (int i = 0; i < BN / RPI; ++i) {
            int row = i * RPI + srl;
            gl_lds16(B + (size_t)(n0 + row) * ldb + k0 + swz<BK>(sc, row) * 8,
                     &Bsl[pb][i * 2048 + t * 8]);
        }
    };
    auto compute = [&](int pb) {
#pragma unroll
        for (int kk = 0; kk < BK / 32; ++kk) {
            s16x8 av[FM], bv[FN];
#pragma unroll
            for (int fm = 0; fm < FM; ++fm)
                av[fm] = *(const s16x8*)&Asl[pb][(rm + fm * 16 + lr) * BK + swz<BK>(kk * 4 + hi, lr) * 8];
#pragma unroll
            for (int fn = 0; fn < FN; ++fn)
                bv[fn] = *(const s16x8*)&Bsl[pb][(cn + fn * 16 + lr) * BK + swz<BK>(kk * 4 + hi, lr) * 8];
#pragma unroll
            for (int fm = 0; fm < FM; ++fm)
#pragma unroll
                for (int fn = 0; fn < FN; ++fn)
                    acc[fm][fn] = __builtin_amdgcn_mfma_f32_16x16x32_bf16(av[fm], bv[fn], acc[fm][fn], 0, 0, 0);
        }
    };

    stage(0, 0);
    __syncthreads();
    int cur = 0;
    for (int k0 = BK; k0 < K; k0 += BK) {
        stage(k0, cur ^ 1);
        compute(cur);
        __syncthreads();
        cur ^= 1;
    }
    compute(cur);

    // epilogue: per-fragment 4x4 transpose -> lane holds row (hi*4+qb), 4 consecutive cols
    const int qb = lr & 3, qi = lr >> 2;
#pragma unroll
    for (int fm = 0; fm < FM; ++fm)
#pragma unroll
        for (int fn = 0; fn < FN; ++fn) {
            const int gm = m0 + rm + fm * 16 + hi * 4 + qb;
            const int gn0 = n0 + cn + fn * 16 + qi * 4;
            const size_t idx0 = (size_t)gm * ldc + gn0;
            if constexpr (EPI == E_QKV3) {
                const int gnf = n0 + cn + fn * 16;
                const int sel = gnf >> 9;
                if (sel < 2) {
                    f32x4 v = xpose4(acc[fm][fn], qb);
                    f32x4 bv4 = *(const f32x4*)&bias[gn0];
#pragma unroll
                    for (int j = 0; j < 4; ++j) v[j] += bv4[j];
                    int b = gm >> 9, s = gm & (S_ - 1);
                    int d9 = gn0 & 511, h = d9 >> 6, d = d9 & 63;
                    u16* dst = (sel == 0) ? Cb : Cb2;
                    *(u16x4*)&dst[(((size_t)(b * H_ + h) * S_ + s) << 6) + d] = pack4(v);
                } else {
                    const int gnl = gnf + lr;
                    const int gm0 = m0 + rm + fm * 16 + hi * 4;
                    int b = gm0 >> 9, s0 = gm0 & (S_ - 1);
                    int d9 = gnl & 511, h = d9 >> 6, d = d9 & 63;
                    float bb = bias[gnl];
                    f32x4 v = acc[fm][fn];
#pragma unroll
                    for (int j = 0; j < 4; ++j) v[j] += bb;
                    *(u16x4*)&Cb3[((((size_t)(b * H_ + h)) << 6) + d) * S_ + s0] = pack4(v);
                }
            } else {
                f32x4 v = xpose4(acc[fm][fn], qb);
                if constexpr (EPI == E_F32) {
#pragma unroll
                    for (int j = 0; j < 4; ++j) v[j] *= alpha;
                    if (bias) {
                        f32x4 bv4 = *(const f32x4*)&bias[gn0];
#pragma unroll
                        for (int j = 0; j < 4; ++j) v[j] += bv4[j];
                    }
                    *(f32x4*)&Cf[idx0] = v;
                    if (Cb) *(u16x4*)&Cb[idx0] = pack4(v);
                } else if constexpr (EPI == E_OUT) {
                    f32x4 bv4 = *(const f32x4*)&bias[gn0];
#pragma unroll
                    for (int j = 0; j < 4; ++j) v[j] += bv4[j];
                    *(f32x4*)&Cf[idx0] = v;
                } else if constexpr (EPI == E_GELU) {
                    f32x4 bv4 = *(const f32x4*)&bias[gn0];
#pragma unroll
                    for (int j = 0; j < 4; ++j) v[j] = gelu_f(v[j] + bv4[j]);
                    if (Cf) *(f32x4*)&Cf[idx0] = v;
                    *(u16x4*)&Cb[idx0] = pack4(v);
                } else if constexpr (EPI == E_TD) {
                    const int tc = tcl[gm];
                    f32x4 cv4 = *(const f32x4*)&cvec[gn0];
                    f32x4 ba4 = *(const f32x4*)&base[idx0];
                    f32x4 dlt, o2;
#pragma unroll
                    for (int j = 0; j < 4; ++j) {
                        float d = v[j] + cv4[j] - woutF[(size_t)(gn0 + j) * V_ + tc];
                        dlt[j] = GAMMA_ * d;
                    }
                    if (subv) {
                        f32x4 sv4 = *(const f32x4*)&subv[idx0];
#pragma unroll
                        for (int j = 0; j < 4; ++j) dlt[j] -= GAMMA_ * sv4[j];
                    }
#pragma unroll
                    for (int j = 0; j < 4; ++j) o2[j] = ba4[j] + dlt[j];
                    if (Cf) *(f32x4*)&Cf[idx0] = o2;
                    *(u16x4*)&Cb[idx0] = pack4(o2);
                    if (ebF) *(f32x4*)&ebF[idx0] = dlt;
                    if (ebB) *(u16x4*)&ebB[idx0] = pack4(dlt);
                } else if constexpr (EPI == E_X15B) {
                    f32x4 ba4 = *(const f32x4*)&base[idx0];
#pragma unroll
                    for (int j = 0; j < 4; ++j) v[j] = ba4[j] + GAMMA_ * v[j];
                    *(u16x4*)&Cb[idx0] = pack4(v);
                } else if constexpr (EPI == E_EC) {
                    f32x4 ba4 = *(const f32x4*)&base[idx0];
                    f32x4 bv4 = *(const f32x4*)&bias[gn0];
#pragma unroll
                    for (int j = 0; j < 4; ++j) v[j] = ba4[j] - (v[j] + bv4[j]);
                    *(f32x4*)&Cf[idx0] = v;
                }
            }
        }
}

// ================= fused causal flash attention (2-phase K/V pipeline) =================
__global__ __launch_bounds__(256)
void flash_attn(const u16* __restrict__ q, const u16* __restrict__ k,
                const u16* __restrict__ vT, u16* __restrict__ ctx)
{
    __shared__ __align__(16) u16 Ks[2][64 * 64];
    __shared__ __align__(16) u16 Vs[2][64 * 64];
    __shared__ __align__(16) u16 Ps[4][16 * 64];
    const int t = threadIdx.x, l = t & 63, w = t >> 6;
    const int qt = blockIdx.x, z = blockIdx.y;
    const int bb = z >> 3, hh = z & 7;
    const int lr = l & 15, hi = l >> 4;
    const u16* qp = q + (((size_t)z * S_ + qt * 64 + w * 16) << 6);
    const u16* kp = k + ((size_t)z * S_ << 6);
    const u16* vp = vT + (((size_t)z) << 6) * S_;

    const s16x8 aq0 = *(const s16x8*)&qp[lr * 64 + hi * 8];
    const s16x8 aq1 = *(const s16x8*)&qp[lr * 64 + 32 + hi * 8];

    f32x4 o[4] = {};
    float m[4], ls[4];
#pragma unroll
    for (int r = 0; r < 4; ++r) { m[r] = -3.0e38f; ls[r] = 0.f; }
    const int qrow = qt * 64 + w * 16 + hi * 4;
    const int srow = t >> 3, scl = t & 7;
    const int cg1 = (scl ^ (srow & 7)) * 8;
    const int srow2 = srow + 32;
    const int cg2 = (scl ^ (srow2 & 7)) * 8;
    const int sw7 = (lr & 7);

    auto stage = [&](int j, int pb) {
        gl_lds16(kp + ((size_t)(j * 64 + srow) << 6) + cg1, &Ks[pb][t * 8]);
        gl_lds16(vp + (size_t)srow * S_ + j * 64 + cg1, &Vs[pb][t * 8]);
        gl_lds16(kp + ((size_t)(j * 64 + srow2) << 6) + cg2, &Ks[pb][(t + 256) * 8]);
        gl_lds16(vp + (size_t)srow2 * S_ + j * 64 + cg2, &Vs[pb][(t + 256) * 8]);
    };

    stage(0, 0);
    __syncthreads();
    int cur = 0;
    for (int j = 0; j <= qt; ++j) {
        if (j < qt) stage(j + 1, cur ^ 1);

        float pv[4][4];
#pragma unroll
        for (int fn = 0; fn < 4; ++fn) {
            f32x4 acc = {};
            acc = __builtin_amdgcn_mfma_f32_16x16x32_bf16(aq0,
                    *(const s16x8*)&Ks[cur][((fn * 16 + lr) << 6) + ((hi ^ sw7) * 8)], acc, 0, 0, 0);
            acc = __builtin_amdgcn_mfma_f32_16x16x32_bf16(aq1,
                    *(const s16x8*)&Ks[cur][((fn * 16 + lr) << 6) + (((hi + 4) ^ sw7) * 8)], acc, 0, 0, 0);
#pragma unroll
            for (int r = 0; r < 4; ++r) pv[fn][r] = acc[r] * 0.125f;
        }
        if (j == qt) {
#pragma unroll
            for (int fn = 0; fn < 4; ++fn) {
                int col = j * 64 + fn * 16 + lr;
#pragma unroll
                for (int r = 0; r < 4; ++r)
                    if (col > qrow + r) pv[fn][r] = -3.0e38f;
            }
        }
        float sc[4], rs[4];
#pragma unroll
        for (int r = 0; r < 4; ++r) {
            float x = fmaxf(fmaxf(pv[0][r], pv[1][r]), fmaxf(pv[2][r], pv[3][r]));
#pragma unroll
            for (int off = 1; off < 16; off <<= 1) x = fmaxf(x, __shfl_xor(x, off, 64));
            float nm = fmaxf(m[r], x);
            sc[r] = expf(m[r] - nm);
            m[r] = nm;
            rs[r] = 0.f;
        }
#pragma unroll
        for (int fn = 0; fn < 4; ++fn)
#pragma unroll
            for (int r = 0; r < 4; ++r) {
                float p = expf(pv[fn][r] - m[r]);
                pv[fn][r] = p;
                rs[r] += p;
            }
#pragma unroll
        for (int r = 0; r < 4; ++r) {
#pragma unroll
            for (int off = 1; off < 16; off <<= 1) rs[r] += __shfl_xor(rs[r], off, 64);
            ls[r] = ls[r] * sc[r] + rs[r];
        }
#pragma unroll
        for (int fn = 0; fn < 4; ++fn)
#pragma unroll
            for (int r = 0; r < 4; ++r) o[fn][r] *= sc[r];
#pragma unroll
        for (int fn = 0; fn < 4; ++fn)
#pragma unroll
            for (int r = 0; r < 4; ++r) {
                int qr = hi * 4 + r;
                int ci = (2 * fn + (lr >> 3)) ^ (qr & 7);
                Ps[w][qr * 64 + ci * 8 + (lr & 7)] = f2b(pv[fn][r]);
            }
#pragma unroll
        for (int ks = 0; ks < 2; ++ks) {
            const s16x8 pa = *(const s16x8*)&Ps[w][lr * 64 + (((4 * ks + hi) ^ sw7) * 8)];
#pragma unroll
            for (int fn = 0; fn < 4; ++fn)
                o[fn] = __builtin_amdgcn_mfma_f32_16x16x32_bf16(pa,
                        *(const s16x8*)&Vs[cur][((fn * 16 + lr) << 6) + (((hi + 4 * ks) ^ sw7) * 8)], o[fn], 0, 0, 0);
        }
        __syncthreads();
        cur ^= 1;
    }
    float inv[4];
#pragma unroll
    for (int r = 0; r < 4; ++r) inv[r] = 1.f / ls[r];
    u16* cp = ctx + ((size_t)(bb * S_ + qt * 64 + w * 16) * D_) + hh * 64;
    const int qb = lr & 3, qi = lr >> 2;
#pragma unroll
    for (int fn = 0; fn < 4; ++fn) {
        f32x4 v = o[fn];
#pragma unroll
        for (int r = 0; r < 4; ++r) v[r] *= inv[r];
        v = xpose4(v, qb);
        *(u16x4*)&cp[(size_t)(hi * 4 + qb) * D_ + fn * 16 + qi * 4] = pack4(v);
    }
}

// ============ mega precompute: 64x64 tiles, u16x8 stores, fused casts ============
__global__ __launch_bounds__(256)
void mega_prep(const float* __restrict__ Wq, const float* __restrict__ Wk,
               const float* __restrict__ Wv, const float* __restrict__ Wo,
               const float* __restrict__ W1, const float* __restrict__ W2,
               const float* __restrict__ Wout,
               const float* __restrict__ bq, const float* __restrict__ bk,
               const float* __restrict__ bv, const int* __restrict__ target_ids,
               u16* __restrict__ wqkvT, u16* __restrict__ woT, u16* __restrict__ w1T,
               u16* __restrict__ w2T, u16* __restrict__ w2d, u16* __restrict__ woutT,
               u16* __restrict__ woutD, float* __restrict__ qkvb, int* __restrict__ tcl)
{
    __shared__ float tile[64][65];
    const int g = blockIdx.x, t = threadIdx.x;

    const float* in = nullptr;
    u16 *outT = nullptr, *outC = nullptr;
    int R = 512, C = 512, tx = 0, ty = 0;

    if (g < 768) {                      // Wq/Wk/Wv -> wqkvT
        int sel = g / 256, rem = g % 256, zz = rem >> 6, tl = rem & 63;
        in = (sel == 0 ? Wq : sel == 1 ? Wk : Wv) + (size_t)zz * 262144;
        outT = wqkvT + (size_t)zz * 786432 + sel * 262144;
        tx = tl & 7; ty = tl >> 3;
    } else if (g < 1024) {              // Wo
        int rem = g - 768, zz = rem >> 6, tl = rem & 63;
        in = Wo + (size_t)zz * 262144; outT = woT + (size_t)zz * 262144;
        tx = tl & 7; ty = tl >> 3;
    } else if (g < 2048) {              // W1 (512x2048)
        int rem = g - 1024, zz = rem >> 8, tl = rem & 255;
        in = W1 + (size_t)zz * 1048576; outT = w1T + (size_t)zz * 1048576;
        C = 2048; tx = tl & 31; ty = tl >> 5;
    } else if (g < 3072) {              // W2 (2048x512); z==3 also casts to w2d
        int rem = g - 2048, zz = rem >> 8, tl = rem & 255;
        in = W2 + (size_t)zz * 1048576; outT = w2T + (size_t)zz * 1048576;
        if (zz == 3) outC = w2d;
        R = 2048; tx = tl & 7; ty = tl >> 3;
    } else if (g < 5120) {              // Wout (512x16384) -> woutT + woutD
        int tl = g - 3072;
        in = Wout; outT = woutT; outC = woutD;
        C = 16384; tx = tl & 255; ty = tl >> 8;
    } else {                            // misc
        for (int i = t; i < M_; i += 256) {
            int v = target_ids[i];
            tcl[i] = v < 0 ? 0 : (v > V_ - 1 ? V_ - 1 : v);
        }
        for (int i = t; i < 4 * 1536; i += 256) {
            int b = i / 1536, j = i - b * 1536;
            qkvb[i] = (j < 512) ? bq[b * 512 + j]
                    : (j < 1024) ? bk[b * 512 + j - 512] : bv[b * 512 + j - 1024];
        }
        return;
    }

    const int r0 = ty * 64, c0 = tx * 64;
#pragma unroll
    for (int p = 0; p < 4; ++p) {
        int row = p * 16 + (t >> 4), col = (t & 15) * 4;
        float4 v = *(const float4*)&in[(size_t)(r0 + row) * C + c0 + col];
        tile[row][col] = v.x; tile[row][col + 1] = v.y;
        tile[row][col + 2] = v.z; tile[row][col + 3] = v.w;
        if (outC) {
            f32x4 fv; fv[0] = v.x; fv[1] = v.y; fv[2] = v.z; fv[3] = v.w;
            *(u16x4*)&outC[(size_t)(r0 + row) * C + c0 + col] = pack4(fv);
        }
    }
    __syncthreads();
#pragma unroll
    for (int p = 0; p < 2; ++p) {
        int orow = p * 32 + (t >> 3), oc = (t & 7) * 8;
        u16x8 o;
#pragma unroll
        for (int j = 0; j < 8; ++j) o[j] = f2b(tile[oc + j][orow]);
        *(u16x8*)&outT[(size_t)(c0 + orow) * R + r0 + oc] = o;
    }
}

__global__ __launch_bounds__(256)
void cvec_kernel(const float* __restrict__ Wout, const float* __restrict__ bout,
                 float* __restrict__ c)
{
    __shared__ float sh[4];
    int d = blockIdx.x;
    const float* row = Wout + (size_t)d * V_;
    float s = 0.f;
    for (int v = threadIdx.x * 4; v < V_; v += 1024) {
        float4 a = *(const float4*)&row[v];
        float4 b = *(const float4*)&bout[v];
        s += a.x * b.x + a.y * b.y + a.z * b.z + a.w * b.w;
    }
    float r = blk_sum(s, sh);
    if (threadIdx.x == 0) c[d] = r;
}

__global__ void gred_kernel(const float* __restrict__ P, u16* __restrict__ G)
{
    int i = blockIdx.x * blockDim.x + threadIdx.x;
    if (i < D_ * D_) {
        float s = 0.f;
#pragma unroll
        for (int zz = 0; zz < 16; ++zz) s += P[(size_t)zz * D_ * D_ + i];
        G[i] = f2b(s);
    }
}

__global__ void embed_kernel(const float4* __restrict__ we, const float4* __restrict__ pe,
                             const int* __restrict__ ids, float4* __restrict__ o)
{
    int t = blockIdx.x * blockDim.x + threadIdx.x;
    int d4 = t & 127, row = t >> 7;
    int ss = row & (S_ - 1);
    int id = ids[row];
    id = id < 0 ? 0 : (id > V_ - 1 ? V_ - 1 : id);
    float4 a = we[(size_t)id * 128 + d4];
    float4 b = pe[(size_t)ss * 128 + d4];
    o[(size_t)row * 128 + d4] = make_float4(a.x + b.x, a.y + b.y, a.z + b.z, a.w + b.w);
}

// LayerNorm: wave-per-row; grid = M/4, block = 256
__global__ __launch_bounds__(256)
void ln_fwd_kernel(const float* __restrict__ x, const float* __restrict__ s,
                   const float* __restrict__ bb, u16* __restrict__ h)
{
    const int l = threadIdx.x & 63, w = threadIdx.x >> 6;
    const int row = blockIdx.x * 4 + w;
    const float* xr = x + (size_t)row * D_;
    const int c0 = l * 8;
    float4 a = *(const float4*)&xr[c0];
    float4 b = *(const float4*)&xr[c0 + 4];
    float sum = a.x + a.y + a.z + a.w + b.x + b.y + b.z + b.w;
    float mu = wave_sum(sum) * (1.f / D_);
    float d0 = a.x - mu, d1 = a.y - mu, d2 = a.z - mu, d3 = a.w - mu;
    float d4 = b.x - mu, d5 = b.y - mu, d6 = b.z - mu, d7 = b.w - mu;
    float vs = d0*d0 + d1*d1 + d2*d2 + d3*d3 + d4*d4 + d5*d5 + d6*d6 + d7*d7;
    float var = wave_sum(vs) * (1.f / D_);
    float r = rsqrtf(var + 1e-5f);
    float4 s0 = *(const float4*)&s[c0], s1 = *(const float4*)&s[c0 + 4];
    float4 b0 = *(const float4*)&bb[c0], b1 = *(const float4*)&bb[c0 + 4];
    u16* hr = h + (size_t)row * D_;
    f32x4 o0, o1;
    o0[0] = d0 * r * s0.x + b0.x; o0[1] = d1 * r * s0.y + b0.y;
    o0[2] = d2 * r * s0.z + b0.z; o0[3] = d3 * r * s0.w + b0.w;
    o1[0] = d4 * r * s1.x + b1.x; o1[1] = d5 * r * s1.y + b1.y;
    o1[2] = d6 * r * s1.z + b1.z; o1[3] = d7 * r * s1.w + b1.w;
    *(u16x4*)&hr[c0] = pack4(o0);
    *(u16x4*)&hr[c0 + 4] = pack4(o1);
}

// ================= host =================
extern "C" void kernel_launch(void* const* d_in, const int* in_sizes, int n_in,
                              void* d_out, int out_size, void* d_ws, size_t ws_size,
                              hipStream_t stream)
{
    (void)in_sizes; (void)n_in; (void)out_size;
    const float* Wq  = (const float*)d_in[2];
    const float* Wk  = (const float*)d_in[3];
    const float* Wv  = (const float*)d_in[4];
    const float* bq  = (const float*)d_in[5];
    const float* bk  = (const float*)d_in[6];
    const float* bv  = (const float*)d_in[7];
    const float* Wo  = (const float*)d_in[8];
    const float* bo  = (const float*)d_in[9];
    const float* ln1_s = (const float*)d_in[10];
    const float* ln1_b = (const float*)d_in[11];
    const float* ln2_s = (const float*)d_in[12];
    const float* ln2_b = (const float*)d_in[13];
    const float* W1  = (const float*)d_in[14];
    const float* b1  = (const float*)d_in[15];
    const float* W2  = (const float*)d_in[16];
    const float* b2  = (const float*)d_in[17];
    const float* Wout = (const float*)d_in[18];
    const float* bout = (const float*)d_in[19];
    const int* input_ids  = (const int*)d_in[20];
    const int* target_ids = (const int*)d_in[21];
    float* out = (float*)d_out;

    // ---- workspace carve ----
    char* wsb = (char*)d_ws;
    size_t off = 0;
    auto alloc = [&](size_t bytes) -> void* {
        off = (off + 255) & ~(size_t)255;
        void* p = wsb + off; off += bytes; return p;
    };
    u16* wqkvT = (u16*)alloc((size_t)4 * 1536 * D_ * 2);
    u16* woT   = (u16*)alloc((size_t)4 * D_ * D_ * 2);
    u16* w1T   = (u16*)alloc((size_t)4 * D_ * F_ * 2);
    u16* w2T   = (u16*)alloc((size_t)4 * D_ * F_ * 2);
    u16* w2d   = (u16*)alloc((size_t)F_ * D_ * 2);
    u16* woutT = (u16*)alloc((size_t)V_ * D_ * 2);
    u16* G_b   = (u16*)alloc((size_t)D_ * D_ * 2);
    float* qkvb = (float*)alloc((size_t)4 * 1536 * 4);
    float* bufA = (float*)alloc((size_t)MF_ * 4);
    float* bufB = (float*)alloc((size_t)MD_ * 4);
    u16* h_b    = (u16*)alloc((size_t)MD_ * 2);
    u16* gelu_b = (u16*)alloc((size_t)MF_ * 2);
    u16* x16_b  = (u16*)alloc((size_t)MD_ * 2);
    float* cvec = (float*)alloc(D_ * 4);
    int* tcl    = (int*)alloc(M_ * 4);
    size_t uStart = (off + 255) & ~(size_t)255;
    // phase G
    off = uStart;
    u16* woutD   = (u16*)alloc((size_t)V_ * D_ * 2);
    float* Gpart = (float*)alloc((size_t)16 * D_ * D_ * 4);
    size_t endG = off;
    // phase attention
    off = uStart;
    u16* q_b   = (u16*)alloc((size_t)MD_ * 2);
    u16* k_b   = (u16*)alloc((size_t)MD_ * 2);
    u16* v_b   = (u16*)alloc((size_t)MD_ * 2);
    u16* ctx_b = (u16*)alloc((size_t)MD_ * 2);
    size_t endA = off;
    // phase tail
    off = uStart;
    float* xA  = (float*)alloc((size_t)MD_ * 4);
    float* xB  = (float*)alloc((size_t)MD_ * 4);
    float* eb  = (float*)alloc((size_t)MD_ * 4);
    float* ec  = (float*)alloc((size_t)MD_ * 4);
    u16* xA_b  = (u16*)alloc((size_t)MD_ * 2);
    u16* xB_b  = (u16*)alloc((size_t)MD_ * 2);
    u16* xC_b  = (u16*)alloc((size_t)MD_ * 2);
    u16* eb_b  = (u16*)alloc((size_t)MD_ * 2);
    u16* x15b_b = (u16*)alloc((size_t)MF_ * 2);
    size_t endT = off;
    size_t need = endG > endA ? endG : endA;
    if (endT > need) need = endT;
    if (need > ws_size) return;

    dim3 blk(256);
    const long NL = 0;
    #define GZ nullptr, nullptr, nullptr, nullptr, nullptr, nullptr, nullptr

    // ---- precompute ----
    mega_prep<<<dim3(5121), blk, 0, stream>>>(Wq, Wk, Wv, Wo, W1, W2, Wout,
        bq, bk, bv, target_ids, wqkvT, woT, w1T, w2T, w2d, woutT, woutD, qkvb, tcl);
    cvec_kernel<<<dim3(D_), blk, 0, stream>>>(Wout, bout, cvec);
    mfma_gemm<128, 128, 64, 4, 4, E_F32><<<dim3(4, 4, 16), blk, 0, stream>>>(
        woutD, woutD, Gpart, nullptr, nullptr, nullptr, nullptr, 1024, V_, V_, D_,
        (long)D_ * D_, 1024, 1.f, GZ);
    gred_kernel<<<dim3(1024), blk, 0, stream>>>(Gpart, G_b);

    // ---- forward sweep ----
    embed_kernel<<<dim3(512), blk, 0, stream>>>((const float4*)d_in[0], (const float4*)d_in[1],
                                                input_ids, (float4*)bufB);
    for (int b = 0; b < 4; ++b) {
        const size_t wDD = (size_t)b * D_ * D_, wDF = (size_t)b * D_ * F_;
        ln_fwd_kernel<<<dim3(M_ / 4), blk, 0, stream>>>(bufB, ln1_s + b * D_, ln1_b + b * D_, h_b);
        mfma_gemm<128, 64, 64, 4, 2, E_QKV3><<<dim3(24, 8, 1), blk, 0, stream>>>(
            h_b, wqkvT + (size_t)b * 1536 * 512, nullptr, q_b, k_b, v_b,
            qkvb + b * 1536, D_, D_, D_, 0, NL, NL, 1.f, GZ);
        flash_attn<<<dim3(8, 16), blk, 0, stream>>>(q_b, k_b, v_b, ctx_b);
        mfma_gemm<64, 64, 128, 2, 2, E_F32><<<dim3(8, 16, 1), blk, 0, stream>>>(
            ctx_b, woT + wDD, bufB, nullptr, nullptr, nullptr, bo + b * D_,
            D_, D_, D_, D_, NL, NL, 1.f, GZ);
        ln_fwd_kernel<<<dim3(M_ / 4), blk, 0, stream>>>(bufB, ln2_s + b * D_, ln2_b + b * D_, h_b);
        mfma_gemm<64, 64, 128, 2, 2, E_GELU><<<dim3(32, 16, 1), blk, 0, stream>>>(
            h_b, w1T + wDF, (b == 3) ? bufA : nullptr, gelu_b, nullptr, nullptr, b1 + b * F_,
            D_, D_, D_, F_, NL, NL, 1.f, GZ);
        mfma_gemm<64, 64, 128, 2, 2, E_F32><<<dim3(8, 16, 1), blk, 0, stream>>>(
            gelu_b, w2T + wDF, bufB, (b == 3) ? x16_b : nullptr, nullptr, nullptr, b2 + b * D_,
            F_, F_, F_, D_, NL, NL, 1.f, GZ);
    }
    // x15 f32 = bufA, x16 f32 = bufB, x16 bf16 = x16_b

    // ---- PC tail ----
    mfma_gemm<64, 64, 128, 2, 2, E_TD><<<dim3(8, 16, 1), blk, 0, stream>>>(
        x16_b, G_b, xA, xA_b, nullptr, nullptr, nullptr, D_, D_, D_, D_, NL, NL, 1.f,
        bufB, nullptr, cvec, Wout, tcl, eb, eb_b);
    mfma_gemm<64, 64, 128, 2, 2, E_TD><<<dim3(8, 16, 1), blk, 0, stream>>>(
        xA_b, G_b, xB, xB_b, nullptr, nullptr, nullptr, D_, D_, D_, D_, NL, NL, 1.f,
        xA, eb, cvec, Wout, tcl, nullptr, nullptr);
    mfma_gemm<64, 64, 128, 2, 2, E_X15B><<<dim3(32, 16, 1), blk, 0, stream>>>(
        eb_b, w2d, nullptr, x15b_b, nullptr, nullptr, nullptr, D_, D_, D_, F_, NL, NL, 1.f,
        bufA, nullptr, nullptr, nullptr, nullptr, nullptr, nullptr);
    mfma_gemm<64, 64, 128, 2, 2, E_EC><<<dim3(8, 16, 1), blk, 0, stream>>>(
        x15b_b, w2T + (size_t)3 * D_ * F_, ec, nullptr, nullptr, nullptr, b2 + 3 * D_,
        F_, F_, F_, D_, NL, NL, 1.f,
        xB, nullptr, nullptr, nullptr, nullptr, nullptr, nullptr);
    mfma_gemm<64, 64, 128, 2, 2, E_TD><<<dim3(8, 16, 1), blk, 0, stream>>>(
        xB_b, G_b, nullptr, xC_b, nullptr, nullptr, nullptr, D_, D_, D_, D_, NL, NL, 1.f,
        xB, ec, cvec, Wout, tcl, nullptr, nullptr);
    // final: out = xC @ Wout + bout (128x256 tile)
    mfma_gemm<128, 256, 32, 4, 8, E_OUT><<<dim3(64, 8, 1), blk, 0, stream>>>(
        xC_b, woutT, out, nullptr, nullptr, nullptr, bout, D_, D_, D_, V_, NL, NL, 1.f, GZ);
    #undef GZ
}

// Round 7
// 435.083 us; speedup vs baseline: 12.6803x; 1.0342x over previous
//
#include <hip/hip_runtime.h>
#include <hip/hip_bf16.h>
#include <math.h>

#define D_   512
#define F_   2048
#define V_   16384
#define H_   8
#define DH_  64
#define S_   512
#define B_   2
#define M_   1024
#define MD_  (M_ * D_)
#define MF_  (M_ * F_)
#define GAMMA_ 0.1f

typedef unsigned int u32;
typedef unsigned short u16;
typedef __attribute__((ext_vector_type(4))) float f32x4;
typedef __attribute__((ext_vector_type(8))) short s16x8;
typedef __attribute__((ext_vector_type(4))) u16 u16x4;
typedef __attribute__((ext_vector_type(8))) u16 u16x8;

__device__ __forceinline__ u16 f2b(float f) {
    __hip_bfloat16 h = __float2bfloat16(f);   // RTNE
    return *reinterpret_cast<u16*>(&h);
}
__device__ __forceinline__ float b2f(u16 v) {
    u32 u = ((u32)v) << 16;
    float f; __builtin_memcpy(&f, &u, 4); return f;
}
__device__ __forceinline__ u16x4 pack4(f32x4 v) {
    u16x4 o; o.x = f2b(v[0]); o.y = f2b(v[1]); o.z = f2b(v[2]); o.w = f2b(v[3]);
    return o;
}

__device__ __forceinline__ void gl_lds16(const void* g, void* l) {
    __builtin_amdgcn_global_load_lds((const __attribute__((address_space(1))) u32*)g,
                                     (__attribute__((address_space(3))) u32*)l, 16, 0, 0);
}

__device__ __forceinline__ float gelu_f(float v) {
    float u = 0.7978845608028654f * (v + 0.044715f * v * v * v);
    return 0.5f * v * (1.f + tanhf(u));
}

// 4x4 transpose across lane quads; lane b: reg r holds Sub[r][b] -> reg j holds Sub[b][j]
__device__ __forceinline__ f32x4 xpose4(f32x4 v, int b) {
#pragma unroll
    for (int s = 1; s < 4; s <<= 1) {
        f32x4 nv;
#pragma unroll
        for (int j = 0; j < 4; ++j) {
            float ex = __shfl_xor(v[j ^ s], s, 64);
            nv[j] = ((b ^ j) & s) ? ex : v[j];
        }
        v = nv;
    }
    return v;
}

__device__ __forceinline__ float wave_sum(float v) {
#pragma unroll
    for (int o = 32; o > 0; o >>= 1) v += __shfl_xor(v, o, 64);
    return v;
}

// ================= MFMA GEMM (NT: A MxK row-major, B NxK row-major, bf16) ===========
#define E_F32   0
#define E_GELU  1
#define E_TD    2   // dlt=g*(acc+cvec[n]-woutT[tcl[m]*D+n]-subv); o=base+dlt
#define E_EC2   3   // Cf = base - subv - g*acc
#define E_QKV3  4
#define E_OUT   5   // f32 + bias (final logits)
#define E_BF16  6   // Cb = bf16(acc)

// per-BK bank-conflict-free chunk swizzle (chunk = 8 u16 = 16 B)
template<int BK>
__device__ __forceinline__ int swz(int c, int row) {
    if constexpr (BK == 32) return c ^ ((row >> 1) & 3);
    else                    return c ^ (row & 7);
}

template<int BM, int BN, int BK, int FM, int FN, int EPI>
__global__ __launch_bounds__(256)
void mfma_gemm(const u16* __restrict__ A, const u16* __restrict__ B,
               float* __restrict__ Cf, u16* __restrict__ Cb,
               u16* __restrict__ Cb2, u16* __restrict__ Cb3,
               const float* __restrict__ bias,
               int K, int lda, int ldb, int ldc,
               long sC, long sKz, float alpha,
               const float* __restrict__ base, const float* __restrict__ subv,
               const float* __restrict__ cvec, const u16* __restrict__ woutTb,
               const int* __restrict__ tcl,
               float* __restrict__ ebF, u16* __restrict__ ebB)
{
    constexpr int WC = BN / (FN * 16);
    static_assert((BM / (FM * 16)) * WC == 4, "4 waves");
    constexpr int LPR = BK / 8;      // lanes per staged row
    constexpr int RPI = 2048 / BK;   // rows per 4KB issue
    __shared__ __align__(16) u16 Asl[2][BM * BK];
    __shared__ __align__(16) u16 Bsl[2][BN * BK];
    const int t = threadIdx.x, l = t & 63, wid = t >> 6;
    const int m0 = blockIdx.y * BM, n0 = blockIdx.x * BN;
    const long z = blockIdx.z;
    A += z * sKz;
    B += z * sKz;
    if (Cf) Cf += z * sC;

    f32x4 acc[FM][FN] = {};
    const int rm = (wid / WC) * (FM * 16), cn = (wid % WC) * (FN * 16);
    const int lr = l & 15, hi = l >> 4;
    const int srl = t / LPR, sc = t % LPR;

    auto stage = [&](int k0, int pb) {
#pragma unroll
        for (int i = 0; i < BM / RPI; ++i) {
            int row = i * RPI + srl;
            gl_lds16(A + (size_t)(m0 + row) * lda + k0 + swz<BK>(sc, row) * 8,
                     &Asl[pb][i * 2048 + t * 8]);
        }
#pragma unroll
        for (int i = 0; i < BN / RPI; ++i) {
            int row = i * RPI + srl;
            gl_lds16(B + (size_t)(n0 + row) * ldb + k0 + swz<BK>(sc, row) * 8,
                     &Bsl[pb][i * 2048 + t * 8]);
        }
    };
    auto compute = [&](int pb) {
#pragma unroll
        for (int kk = 0; kk < BK / 32; ++kk) {
            s16x8 av[FM], bv[FN];
#pragma unroll
            for (int fm = 0; fm < FM; ++fm)
                av[fm] = *(const s16x8*)&Asl[pb][(rm + fm * 16 + lr) * BK + swz<BK>(kk * 4 + hi, lr) * 8];
#pragma unroll
            for (int fn = 0; fn < FN; ++fn)
                bv[fn] = *(const s16x8*)&Bsl[pb][(cn + fn * 16 + lr) * BK + swz<BK>(kk * 4 + hi, lr) * 8];
#pragma unroll
            for (int fm = 0; fm < FM; ++fm)
#pragma unroll
                for (int fn = 0; fn < FN; ++fn)
                    acc[fm][fn] = __builtin_amdgcn_mfma_f32_16x16x32_bf16(av[fm], bv[fn], acc[fm][fn], 0, 0, 0);
        }
    };

    stage(0, 0);
    __syncthreads();
    int cur = 0;
    for (int k0 = BK; k0 < K; k0 += BK) {
        stage(k0, cur ^ 1);
        compute(cur);
        __syncthreads();
        cur ^= 1;
    }
    compute(cur);

    // epilogue: per-fragment 4x4 transpose -> lane holds row (hi*4+qb), 4 consecutive cols
    const int qb = lr & 3, qi = lr >> 2;
#pragma unroll
    for (int fm = 0; fm < FM; ++fm)
#pragma unroll
        for (int fn = 0; fn < FN; ++fn) {
            const int gm = m0 + rm + fm * 16 + hi * 4 + qb;
            const int gn0 = n0 + cn + fn * 16 + qi * 4;
            const size_t idx0 = (size_t)gm * ldc + gn0;
            if constexpr (EPI == E_QKV3) {
                const int gnf = n0 + cn + fn * 16;
                const int sel = gnf >> 9;
                if (sel < 2) {
                    f32x4 v = xpose4(acc[fm][fn], qb);
                    f32x4 bv4 = *(const f32x4*)&bias[gn0];
#pragma unroll
                    for (int j = 0; j < 4; ++j) v[j] += bv4[j];
                    int b = gm >> 9, s = gm & (S_ - 1);
                    int d9 = gn0 & 511, h = d9 >> 6, d = d9 & 63;
                    u16* dst = (sel == 0) ? Cb : Cb2;
                    *(u16x4*)&dst[(((size_t)(b * H_ + h) * S_ + s) << 6) + d] = pack4(v);
                } else {
                    const int gnl = gnf + lr;
                    const int gm0 = m0 + rm + fm * 16 + hi * 4;
                    int b = gm0 >> 9, s0 = gm0 & (S_ - 1);
                    int d9 = gnl & 511, h = d9 >> 6, d = d9 & 63;
                    float bb = bias[gnl];
                    f32x4 v = acc[fm][fn];
#pragma unroll
                    for (int j = 0; j < 4; ++j) v[j] += bb;
                    *(u16x4*)&Cb3[((((size_t)(b * H_ + h)) << 6) + d) * S_ + s0] = pack4(v);
                }
            } else {
                f32x4 v = xpose4(acc[fm][fn], qb);
                if constexpr (EPI == E_F32) {
#pragma unroll
                    for (int j = 0; j < 4; ++j) v[j] *= alpha;
                    if (bias) {
                        f32x4 bv4 = *(const f32x4*)&bias[gn0];
#pragma unroll
                        for (int j = 0; j < 4; ++j) v[j] += bv4[j];
                    }
                    *(f32x4*)&Cf[idx0] = v;
                    if (Cb) *(u16x4*)&Cb[idx0] = pack4(v);
                } else if constexpr (EPI == E_OUT) {
                    f32x4 bv4 = *(const f32x4*)&bias[gn0];
#pragma unroll
                    for (int j = 0; j < 4; ++j) v[j] += bv4[j];
                    *(f32x4*)&Cf[idx0] = v;
                } else if constexpr (EPI == E_GELU) {
                    f32x4 bv4 = *(const f32x4*)&bias[gn0];
#pragma unroll
                    for (int j = 0; j < 4; ++j) v[j] = gelu_f(v[j] + bv4[j]);
                    *(u16x4*)&Cb[idx0] = pack4(v);
                } else if constexpr (EPI == E_TD) {
                    const int tc = tcl[gm];
                    f32x4 cv4 = *(const f32x4*)&cvec[gn0];
                    f32x4 ba4 = *(const f32x4*)&base[idx0];
                    u16x4 gv = *(const u16x4*)&woutTb[(size_t)tc * D_ + gn0];
                    f32x4 dlt, o2;
#pragma unroll
                    for (int j = 0; j < 4; ++j)
                        dlt[j] = GAMMA_ * (v[j] + cv4[j] - b2f(gv[j]));
                    if (subv) {
                        f32x4 sv4 = *(const f32x4*)&subv[idx0];
#pragma unroll
                        for (int j = 0; j < 4; ++j) dlt[j] -= GAMMA_ * sv4[j];
                    }
#pragma unroll
                    for (int j = 0; j < 4; ++j) o2[j] = ba4[j] + dlt[j];
                    if (Cf) *(f32x4*)&Cf[idx0] = o2;
                    *(u16x4*)&Cb[idx0] = pack4(o2);
                    if (ebF) *(f32x4*)&ebF[idx0] = dlt;
                    if (ebB) *(u16x4*)&ebB[idx0] = pack4(dlt);
                } else if constexpr (EPI == E_EC2) {
                    f32x4 ba4 = *(const f32x4*)&base[idx0];
                    f32x4 sv4 = *(const f32x4*)&subv[idx0];
#pragma unroll
                    for (int j = 0; j < 4; ++j) v[j] = ba4[j] - sv4[j] - GAMMA_ * v[j];
                    *(f32x4*)&Cf[idx0] = v;
                } else if constexpr (EPI == E_BF16) {
                    *(u16x4*)&Cb[idx0] = pack4(v);
                }
            }
        }
}

// ================= fused causal flash attention (2-phase K/V pipeline) =================
__global__ __launch_bounds__(256)
void flash_attn(const u16* __restrict__ q, const u16* __restrict__ k,
                const u16* __restrict__ vT, u16* __restrict__ ctx)
{
    __shared__ __align__(16) u16 Ks[2][64 * 64];
    __shared__ __align__(16) u16 Vs[2][64 * 64];
    __shared__ __align__(16) u16 Ps[4][16 * 64];
    const int t = threadIdx.x, l = t & 63, w = t >> 6;
    const int qt = blockIdx.x, z = blockIdx.y;
    const int bb = z >> 3, hh = z & 7;
    const int lr = l & 15, hi = l >> 4;
    const u16* qp = q + (((size_t)z * S_ + qt * 64 + w * 16) << 6);
    const u16* kp = k + ((size_t)z * S_ << 6);
    const u16* vp = vT + (((size_t)z) << 6) * S_;

    const s16x8 aq0 = *(const s16x8*)&qp[lr * 64 + hi * 8];
    const s16x8 aq1 = *(const s16x8*)&qp[lr * 64 + 32 + hi * 8];

    f32x4 o[4] = {};
    float m[4], ls[4];
#pragma unroll
    for (int r = 0; r < 4; ++r) { m[r] = -3.0e38f; ls[r] = 0.f; }
    const int qrow = qt * 64 + w * 16 + hi * 4;
    const int srow = t >> 3, scl = t & 7;
    const int cg1 = (scl ^ (srow & 7)) * 8;
    const int srow2 = srow + 32;
    const int cg2 = (scl ^ (srow2 & 7)) * 8;
    const int sw7 = (lr & 7);

    auto stage = [&](int j, int pb) {
        gl_lds16(kp + ((size_t)(j * 64 + srow) << 6) + cg1, &Ks[pb][t * 8]);
        gl_lds16(vp + (size_t)srow * S_ + j * 64 + cg1, &Vs[pb][t * 8]);
        gl_lds16(kp + ((size_t)(j * 64 + srow2) << 6) + cg2, &Ks[pb][(t + 256) * 8]);
        gl_lds16(vp + (size_t)srow2 * S_ + j * 64 + cg2, &Vs[pb][(t + 256) * 8]);
    };

    stage(0, 0);
    __syncthreads();
    int cur = 0;
    for (int j = 0; j <= qt; ++j) {
        if (j < qt) stage(j + 1, cur ^ 1);

        float pv[4][4];
#pragma unroll
        for (int fn = 0; fn < 4; ++fn) {
            f32x4 acc = {};
            acc = __builtin_amdgcn_mfma_f32_16x16x32_bf16(aq0,
                    *(const s16x8*)&Ks[cur][((fn * 16 + lr) << 6) + ((hi ^ sw7) * 8)], acc, 0, 0, 0);
            acc = __builtin_amdgcn_mfma_f32_16x16x32_bf16(aq1,
                    *(const s16x8*)&Ks[cur][((fn * 16 + lr) << 6) + (((hi + 4) ^ sw7) * 8)], acc, 0, 0, 0);
#pragma unroll
            for (int r = 0; r < 4; ++r) pv[fn][r] = acc[r] * 0.125f;
        }
        if (j == qt) {
#pragma unroll
            for (int fn = 0; fn < 4; ++fn) {
                int col = j * 64 + fn * 16 + lr;
#pragma unroll
                for (int r = 0; r < 4; ++r)
                    if (col > qrow + r) pv[fn][r] = -3.0e38f;
            }
        }
        float sc[4], rs[4];
#pragma unroll
        for (int r = 0; r < 4; ++r) {
            float x = fmaxf(fmaxf(pv[0][r], pv[1][r]), fmaxf(pv[2][r], pv[3][r]));
#pragma unroll
            for (int off = 1; off < 16; off <<= 1) x = fmaxf(x, __shfl_xor(x, off, 64));
            float nm = fmaxf(m[r], x);
            sc[r] = expf(m[r] - nm);
            m[r] = nm;
            rs[r] = 0.f;
        }
#pragma unroll
        for (int fn = 0; fn < 4; ++fn)
#pragma unroll
            for (int r = 0; r < 4; ++r) {
                float p = expf(pv[fn][r] - m[r]);
                pv[fn][r] = p;
                rs[r] += p;
            }
#pragma unroll
        for (int r = 0; r < 4; ++r) {
#pragma unroll
            for (int off = 1; off < 16; off <<= 1) rs[r] += __shfl_xor(rs[r], off, 64);
            ls[r] = ls[r] * sc[r] + rs[r];
        }
#pragma unroll
        for (int fn = 0; fn < 4; ++fn)
#pragma unroll
            for (int r = 0; r < 4; ++r) o[fn][r] *= sc[r];
#pragma unroll
        for (int fn = 0; fn < 4; ++fn)
#pragma unroll
            for (int r = 0; r < 4; ++r) {
                int qr = hi * 4 + r;
                int ci = (2 * fn + (lr >> 3)) ^ (qr & 7);
                Ps[w][qr * 64 + ci * 8 + (lr & 7)] = f2b(pv[fn][r]);
            }
#pragma unroll
        for (int ks = 0; ks < 2; ++ks) {
            const s16x8 pa = *(const s16x8*)&Ps[w][lr * 64 + (((4 * ks + hi) ^ sw7) * 8)];
#pragma unroll
            for (int fn = 0; fn < 4; ++fn)
                o[fn] = __builtin_amdgcn_mfma_f32_16x16x32_bf16(pa,
                        *(const s16x8*)&Vs[cur][((fn * 16 + lr) << 6) + (((hi + 4 * ks) ^ sw7) * 8)], o[fn], 0, 0, 0);
        }
        __syncthreads();
        cur ^= 1;
    }
    float inv[4];
#pragma unroll
    for (int r = 0; r < 4; ++r) inv[r] = 1.f / ls[r];
    u16* cp = ctx + ((size_t)(bb * S_ + qt * 64 + w * 16) * D_) + hh * 64;
    const int qb = lr & 3, qi = lr >> 2;
#pragma unroll
    for (int fn = 0; fn < 4; ++fn) {
        f32x4 v = o[fn];
#pragma unroll
        for (int r = 0; r < 4; ++r) v[r] *= inv[r];
        v = xpose4(v, qb);
        *(u16x4*)&cp[(size_t)(hi * 4 + qb) * D_ + fn * 16 + qi * 4] = pack4(v);
    }
}

// ============ prep0: zero cvec, clip targets, pack qkv bias ============
__global__ __launch_bounds__(256)
void prep0(const float* __restrict__ bq, const float* __restrict__ bk,
           const float* __restrict__ bv, const int* __restrict__ target_ids,
           float* __restrict__ qkvb, int* __restrict__ tcl, float* __restrict__ cvec)
{
    int i = blockIdx.x * 256 + threadIdx.x;   // grid 32 -> 8192
    if (i < 512) cvec[i] = 0.f;
    else if (i < 1536) {
        int mm = i - 512;
        int v = target_ids[mm];
        tcl[mm] = v < 0 ? 0 : (v > V_ - 1 ? V_ - 1 : v);
    } else if (i < 1536 + 6144) {
        int j = i - 1536;
        int b = j / 1536, r = j - b * 1536;
        qkvb[j] = (r < 512) ? bq[b * 512 + r]
                : (r < 1024) ? bk[b * 512 + r - 512] : bv[b * 512 + r - 1024];
    }
}

// ============ mega precompute: 64x64 tiles, u16x8 stores, fused casts + cvec ============
__global__ __launch_bounds__(256)
void mega_prep(const float* __restrict__ Wq, const float* __restrict__ Wk,
               const float* __restrict__ Wv, const float* __restrict__ Wo,
               const float* __restrict__ W1, const float* __restrict__ W2,
               const float* __restrict__ Wout, const float* __restrict__ bout,
               u16* __restrict__ wqkvT, u16* __restrict__ woT, u16* __restrict__ w1T,
               u16* __restrict__ w2T, u16* __restrict__ woutT,
               u16* __restrict__ woutD, float* __restrict__ cvec)
{
    __shared__ float tile[64][65];
    const int g = blockIdx.x, t = threadIdx.x;

    const float* in = nullptr;
    u16 *outT = nullptr, *outC = nullptr;
    int R = 512, C = 512, tx = 0, ty = 0;
    bool doCvec = false;

    if (g < 768) {                      // Wq/Wk/Wv -> wqkvT
        int sel = g / 256, rem = g % 256, zz = rem >> 6, tl = rem & 63;
        in = (sel == 0 ? Wq : sel == 1 ? Wk : Wv) + (size_t)zz * 262144;
        outT = wqkvT + (size_t)zz * 786432 + sel * 262144;
        tx = tl & 7; ty = tl >> 3;
    } else if (g < 1024) {              // Wo
        int rem = g - 768, zz = rem >> 6, tl = rem & 63;
        in = Wo + (size_t)zz * 262144; outT = woT + (size_t)zz * 262144;
        tx = tl & 7; ty = tl >> 3;
    } else if (g < 2048) {              // W1 (512x2048)
        int rem = g - 1024, zz = rem >> 8, tl = rem & 255;
        in = W1 + (size_t)zz * 1048576; outT = w1T + (size_t)zz * 1048576;
        C = 2048; tx = tl & 31; ty = tl >> 5;
    } else if (g < 3072) {              // W2 (2048x512)
        int rem = g - 2048, zz = rem >> 8, tl = rem & 255;
        in = W2 + (size_t)zz * 1048576; outT = w2T + (size_t)zz * 1048576;
        R = 2048; tx = tl & 7; ty = tl >> 3;
    } else {                            // Wout (512x16384) -> woutT + woutD + cvec
        int tl = g - 3072;
        in = Wout; outT = woutT; outC = woutD; doCvec = true;
        C = 16384; tx = tl & 255; ty = tl >> 8;
    }

    const int r0 = ty * 64, c0 = tx * 64;
#pragma unroll
    for (int p = 0; p < 4; ++p) {
        int row = p * 16 + (t >> 4), col = (t & 15) * 4;
        float4 v = *(const float4*)&in[(size_t)(r0 + row) * C + c0 + col];
        tile[row][col] = v.x; tile[row][col + 1] = v.y;
        tile[row][col + 2] = v.z; tile[row][col + 3] = v.w;
        if (outC) {
            f32x4 fv; fv[0] = v.x; fv[1] = v.y; fv[2] = v.z; fv[3] = v.w;
            *(u16x4*)&outC[(size_t)(r0 + row) * C + c0 + col] = pack4(fv);
        }
    }
    __syncthreads();
#pragma unroll
    for (int p = 0; p < 2; ++p) {
        int orow = p * 32 + (t >> 3), oc = (t & 7) * 8;
        u16x8 o;
#pragma unroll
        for (int j = 0; j < 8; ++j) o[j] = f2b(tile[oc + j][orow]);
        *(u16x8*)&outT[(size_t)(c0 + orow) * R + r0 + oc] = o;
    }
    if (doCvec) {
        // cvec[r0+r] += dot(tile[r][:], bout[c0:c0+64])
        int r = t >> 2, q = t & 3;
        float s = 0.f;
#pragma unroll
        for (int i = 0; i < 16; ++i)
            s += tile[r][q * 16 + i] * bout[c0 + q * 16 + i];
        s += __shfl_xor(s, 1, 64);
        s += __shfl_xor(s, 2, 64);
        if (q == 0) atomicAdd(&cvec[r0 + r], s);
    }
}

__global__ void gred_kernel(const float* __restrict__ P, u16* __restrict__ G)
{
    int i = blockIdx.x * blockDim.x + threadIdx.x;
    if (i < D_ * D_) {
        float s = 0.f;
#pragma unroll
        for (int zz = 0; zz < 16; ++zz) s += P[(size_t)zz * D_ * D_ + i];
        G[i] = f2b(s);
    }
}

__global__ void embed_kernel(const float4* __restrict__ we, const float4* __restrict__ pe,
                             const int* __restrict__ ids, float4* __restrict__ o)
{
    int t = blockIdx.x * blockDim.x + threadIdx.x;
    int d4 = t & 127, row = t >> 7;
    int ss = row & (S_ - 1);
    int id = ids[row];
    id = id < 0 ? 0 : (id > V_ - 1 ? V_ - 1 : id);
    float4 a = we[(size_t)id * 128 + d4];
    float4 b = pe[(size_t)ss * 128 + d4];
    o[(size_t)row * 128 + d4] = make_float4(a.x + b.x, a.y + b.y, a.z + b.z, a.w + b.w);
}

// LayerNorm: wave-per-row; grid = M/4, block = 256
__global__ __launch_bounds__(256)
void ln_fwd_kernel(const float* __restrict__ x, const float* __restrict__ s,
                   const float* __restrict__ bb, u16* __restrict__ h)
{
    const int l = threadIdx.x & 63, w = threadIdx.x >> 6;
    const int row = blockIdx.x * 4 + w;
    const float* xr = x + (size_t)row * D_;
    const int c0 = l * 8;
    float4 a = *(const float4*)&xr[c0];
    float4 b = *(const float4*)&xr[c0 + 4];
    float sum = a.x + a.y + a.z + a.w + b.x + b.y + b.z + b.w;
    float mu = wave_sum(sum) * (1.f / D_);
    float d0 = a.x - mu, d1 = a.y - mu, d2 = a.z - mu, d3 = a.w - mu;
    float d4 = b.x - mu, d5 = b.y - mu, d6 = b.z - mu, d7 = b.w - mu;
    float vs = d0*d0 + d1*d1 + d2*d2 + d3*d3 + d4*d4 + d5*d5 + d6*d6 + d7*d7;
    float var = wave_sum(vs) * (1.f / D_);
    float r = rsqrtf(var + 1e-5f);
    float4 s0 = *(const float4*)&s[c0], s1 = *(const float4*)&s[c0 + 4];
    float4 b0 = *(const float4*)&bb[c0], b1 = *(const float4*)&bb[c0 + 4];
    u16* hr = h + (size_t)row * D_;
    f32x4 o0, o1;
    o0[0] = d0 * r * s0.x + b0.x; o0[1] = d1 * r * s0.y + b0.y;
    o0[2] = d2 * r * s0.z + b0.z; o0[3] = d3 * r * s0.w + b0.w;
    o1[0] = d4 * r * s1.x + b1.x; o1[1] = d5 * r * s1.y + b1.y;
    o1[2] = d6 * r * s1.z + b1.z; o1[3] = d7 * r * s1.w + b1.w;
    *(u16x4*)&hr[c0] = pack4(o0);
    *(u16x4*)&hr[c0 + 4] = pack4(o1);
}

// ================= host =================
extern "C" void kernel_launch(void* const* d_in, const int* in_sizes, int n_in,
                              void* d_out, int out_size, void* d_ws, size_t ws_size,
                              hipStream_t stream)
{
    (void)in_sizes; (void)n_in; (void)out_size;
    const float* Wq  = (const float*)d_in[2];
    const float* Wk  = (const float*)d_in[3];
    const float* Wv  = (const float*)d_in[4];
    const float* bq  = (const float*)d_in[5];
    const float* bk  = (const float*)d_in[6];
    const float* bv  = (const float*)d_in[7];
    const float* Wo  = (const float*)d_in[8];
    const float* bo  = (const float*)d_in[9];
    const float* ln1_s = (const float*)d_in[10];
    const float* ln1_b = (const float*)d_in[11];
    const float* ln2_s = (const float*)d_in[12];
    const float* ln2_b = (const float*)d_in[13];
    const float* W1  = (const float*)d_in[14];
    const float* b1  = (const float*)d_in[15];
    const float* W2  = (const float*)d_in[16];
    const float* b2  = (const float*)d_in[17];
    const float* Wout = (const float*)d_in[18];
    const float* bout = (const float*)d_in[19];
    const int* input_ids  = (const int*)d_in[20];
    const int* target_ids = (const int*)d_in[21];
    float* out = (float*)d_out;

    // ---- workspace carve ----
    char* wsb = (char*)d_ws;
    size_t off = 0;
    auto alloc = [&](size_t bytes) -> void* {
        off = (off + 255) & ~(size_t)255;
        void* p = wsb + off; off += bytes; return p;
    };
    u16* wqkvT = (u16*)alloc((size_t)4 * 1536 * D_ * 2);
    u16* woT   = (u16*)alloc((size_t)4 * D_ * D_ * 2);
    u16* w1T   = (u16*)alloc((size_t)4 * D_ * F_ * 2);
    u16* w2T   = (u16*)alloc((size_t)4 * D_ * F_ * 2);
    u16* woutT = (u16*)alloc((size_t)V_ * D_ * 2);
    u16* G_b   = (u16*)alloc((size_t)D_ * D_ * 2);
    u16* H2_b  = (u16*)alloc((size_t)D_ * D_ * 2);
    float* qkvb = (float*)alloc((size_t)4 * 1536 * 4);
    float* bufB = (float*)alloc((size_t)MD_ * 4);
    u16* h_b    = (u16*)alloc((size_t)MD_ * 2);
    u16* gelu_b = (u16*)alloc((size_t)MF_ * 2);
    u16* x16_b  = (u16*)alloc((size_t)MD_ * 2);
    float* cvec = (float*)alloc(D_ * 4);
    int* tcl    = (int*)alloc(M_ * 4);
    size_t uStart = (off + 255) & ~(size_t)255;
    // phase G (precompute)
    off = uStart;
    u16* woutD   = (u16*)alloc((size_t)V_ * D_ * 2);
    float* Gpart = (float*)alloc((size_t)16 * D_ * D_ * 4);
    size_t endG = off;
    // phase attention
    off = uStart;
    u16* q_b   = (u16*)alloc((size_t)MD_ * 2);
    u16* k_b   = (u16*)alloc((size_t)MD_ * 2);
    u16* v_b   = (u16*)alloc((size_t)MD_ * 2);
    u16* ctx_b = (u16*)alloc((size_t)MD_ * 2);
    size_t endA = off;
    // phase tail
    off = uStart;
    float* xA  = (float*)alloc((size_t)MD_ * 4);
    float* xB  = (float*)alloc((size_t)MD_ * 4);
    float* eb  = (float*)alloc((size_t)MD_ * 4);
    float* ec  = (float*)alloc((size_t)MD_ * 4);
    u16* xA_b  = (u16*)alloc((size_t)MD_ * 2);
    u16* xB_b  = (u16*)alloc((size_t)MD_ * 2);
    u16* xC_b  = (u16*)alloc((size_t)MD_ * 2);
    u16* eb_b  = (u16*)alloc((size_t)MD_ * 2);
    size_t endT = off;
    size_t need = endG > endA ? endG : endA;
    if (endT > need) need = endT;
    if (need > ws_size) return;

    dim3 blk(256);
    const long NL = 0;
    #define GZ nullptr, nullptr, nullptr, nullptr, nullptr, nullptr, nullptr

    // ---- precompute ----
    prep0<<<dim3(32), blk, 0, stream>>>(bq, bk, bv, target_ids, qkvb, tcl, cvec);
    mega_prep<<<dim3(5120), blk, 0, stream>>>(Wq, Wk, Wv, Wo, W1, W2, Wout, bout,
        wqkvT, woT, w1T, w2T, woutT, woutD, cvec);
    // G = Wout @ Wout^T, split-K 16 x 1024
    mfma_gemm<128, 128, 64, 4, 4, E_F32><<<dim3(4, 4, 16), blk, 0, stream>>>(
        woutD, woutD, Gpart, nullptr, nullptr, nullptr, nullptr, 1024, V_, V_, D_,
        (long)D_ * D_, 1024, 1.f, GZ);
    gred_kernel<<<dim3(1024), blk, 0, stream>>>(Gpart, G_b);
    // H2 = W2[3]^T @ W2[3]  (from w2T, NT form)
    mfma_gemm<64, 64, 128, 2, 2, E_BF16><<<dim3(8, 8, 1), blk, 0, stream>>>(
        w2T + (size_t)3 * D_ * F_, w2T + (size_t)3 * D_ * F_, nullptr, H2_b,
        nullptr, nullptr, nullptr, F_, F_, F_, D_, NL, NL, 1.f, GZ);

    // ---- forward sweep ----
    embed_kernel<<<dim3(512), blk, 0, stream>>>((const float4*)d_in[0], (const float4*)d_in[1],
                                                input_ids, (float4*)bufB);
    for (int b = 0; b < 4; ++b) {
        const size_t wDD = (size_t)b * D_ * D_, wDF = (size_t)b * D_ * F_;
        ln_fwd_kernel<<<dim3(M_ / 4), blk, 0, stream>>>(bufB, ln1_s + b * D_, ln1_b + b * D_, h_b);
        mfma_gemm<128, 64, 128, 4, 2, E_QKV3><<<dim3(24, 8, 1), blk, 0, stream>>>(
            h_b, wqkvT + (size_t)b * 1536 * 512, nullptr, q_b, k_b, v_b,
            qkvb + b * 1536, D_, D_, D_, 0, NL, NL, 1.f, GZ);
        flash_attn<<<dim3(8, 16), blk, 0, stream>>>(q_b, k_b, v_b, ctx_b);
        mfma_gemm<64, 64, 128, 2, 2, E_F32><<<dim3(8, 16, 1), blk, 0, stream>>>(
            ctx_b, woT + wDD, bufB, nullptr, nullptr, nullptr, bo + b * D_,
            D_, D_, D_, D_, NL, NL, 1.f, GZ);
        ln_fwd_kernel<<<dim3(M_ / 4), blk, 0, stream>>>(bufB, ln2_s + b * D_, ln2_b + b * D_, h_b);
        mfma_gemm<64, 64, 128, 2, 2, E_GELU><<<dim3(32, 16, 1), blk, 0, stream>>>(
            h_b, w1T + wDF, nullptr, gelu_b, nullptr, nullptr, b1 + b * F_,
            D_, D_, D_, F_, NL, NL, 1.f, GZ);
        mfma_gemm<64, 64, 128, 2, 2, E_F32><<<dim3(8, 16, 1), blk, 0, stream>>>(
            gelu_b, w2T + wDF, bufB, (b == 3) ? x16_b : nullptr, nullptr, nullptr, b2 + b * D_,
            F_, F_, F_, D_, NL, NL, 1.f, GZ);
    }
    // x16 f32 = bufB, x16 bf16 = x16_b

    // ---- PC tail ----
    // iter 1: xA = x16 + dlt; eb = dlt
    mfma_gemm<64, 64, 128, 2, 2, E_TD><<<dim3(8, 16, 1), blk, 0, stream>>>(
        x16_b, G_b, xA, xA_b, nullptr, nullptr, nullptr, D_, D_, D_, D_, NL, NL, 1.f,
        bufB, nullptr, cvec, woutT, tcl, eb, eb_b);
    // iter 2: xB = xA + g*(xA@G + cvec - gth - eb)
    mfma_gemm<64, 64, 128, 2, 2, E_TD><<<dim3(8, 16, 1), blk, 0, stream>>>(
        xA_b, G_b, xB, xB_b, nullptr, nullptr, nullptr, D_, D_, D_, D_, NL, NL, 1.f,
        xA, eb, cvec, woutT, tcl, nullptr, nullptr);
    // ec = xB - x16 - g*(eb @ H2)     [H2 = W2^T W2 folds x15b@W2+b2]
    mfma_gemm<64, 64, 128, 2, 2, E_EC2><<<dim3(8, 16, 1), blk, 0, stream>>>(
        eb_b, H2_b, ec, nullptr, nullptr, nullptr, nullptr, D_, D_, D_, D_, NL, NL, 1.f,
        xB, bufB, nullptr, nullptr, nullptr, nullptr, nullptr);
    // iter 3: xC = xB + g*(xB@G + cvec - gth - ec)
    mfma_gemm<64, 64, 128, 2, 2, E_TD><<<dim3(8, 16, 1), blk, 0, stream>>>(
        xB_b, G_b, nullptr, xC_b, nullptr, nullptr, nullptr, D_, D_, D_, D_, NL, NL, 1.f,
        xB, ec, cvec, woutT, tcl, nullptr, nullptr);
    // final: out = xC @ Wout + bout (128x256 tile, BK=64)
    mfma_gemm<128, 256, 64, 4, 8, E_OUT><<<dim3(64, 8, 1), blk, 0, stream>>>(
        xC_b, woutT, out, nullptr, nullptr, nullptr, bout, D_, D_, D_, V_, NL, NL, 1.f, GZ);
    #undef GZ
}

// Round 8
// 423.849 us; speedup vs baseline: 13.0164x; 1.0265x over previous
//
#include <hip/hip_runtime.h>
#include <hip/hip_bf16.h>
#include <math.h>

#define D_   512
#define F_   2048
#define V_   16384
#define H_   8
#define DH_  64
#define S_   512
#define B_   2
#define M_   1024
#define MD_  (M_ * D_)
#define MF_  (M_ * F_)
#define GAMMA_ 0.1f

typedef unsigned int u32;
typedef unsigned short u16;
typedef __attribute__((ext_vector_type(4))) float f32x4;
typedef __attribute__((ext_vector_type(8))) short s16x8;
typedef __attribute__((ext_vector_type(4))) u16 u16x4;
typedef __attribute__((ext_vector_type(8))) u16 u16x8;

__device__ __forceinline__ u16 f2b(float f) {
    __hip_bfloat16 h = __float2bfloat16(f);   // RTNE
    return *reinterpret_cast<u16*>(&h);
}
__device__ __forceinline__ float b2f(u16 v) {
    u32 u = ((u32)v) << 16;
    float f; __builtin_memcpy(&f, &u, 4); return f;
}
__device__ __forceinline__ u16x4 pack4(f32x4 v) {
    u16x4 o; o.x = f2b(v[0]); o.y = f2b(v[1]); o.z = f2b(v[2]); o.w = f2b(v[3]);
    return o;
}

__device__ __forceinline__ void gl_lds16(const void* g, void* l) {
    __builtin_amdgcn_global_load_lds((const __attribute__((address_space(1))) u32*)g,
                                     (__attribute__((address_space(3))) u32*)l, 16, 0, 0);
}

__device__ __forceinline__ float gelu_f(float v) {
    float u = 0.7978845608028654f * (v + 0.044715f * v * v * v);
    return 0.5f * v * (1.f + tanhf(u));
}

// 4x4 transpose across lane quads; lane b: reg r holds Sub[r][b] -> reg j holds Sub[b][j]
__device__ __forceinline__ f32x4 xpose4(f32x4 v, int b) {
#pragma unroll
    for (int s = 1; s < 4; s <<= 1) {
        f32x4 nv;
#pragma unroll
        for (int j = 0; j < 4; ++j) {
            float ex = __shfl_xor(v[j ^ s], s, 64);
            nv[j] = ((b ^ j) & s) ? ex : v[j];
        }
        v = nv;
    }
    return v;
}

__device__ __forceinline__ float wave_sum(float v) {
#pragma unroll
    for (int o = 32; o > 0; o >>= 1) v += __shfl_xor(v, o, 64);
    return v;
}

// ================= MFMA GEMM (NT: A MxK row-major, B NxK row-major, bf16) ===========
// 3-buffer counted-vmcnt pipeline (T3+T4): stage issued 2 iters ahead, vmcnt(NISS)
// mid-loop (never 0), raw s_barrier + sched_barrier(0). Per-wave vmcnt before the
// barrier => whole buffer ready after barrier. Write target = buffer last read 3
// barriers ago => overwrite-safe.
#define E_F32   0
#define E_GELU  1
#define E_TD    2   // dlt=g*(acc+cvec[n]-woutT[tcl[m]*D+n]-subv); o=base+dlt
#define E_EC2   3   // Cf = base - subv - g*acc
#define E_QKV3  4
#define E_OUT   5   // f32 + bias (final logits)
#define E_BF16  6   // Cb = bf16(acc)

// per-BK bank-conflict-free chunk swizzle (chunk = 8 u16 = 16 B)
template<int BK>
__device__ __forceinline__ int swz(int c, int row) {
    if constexpr (BK == 32) return c ^ ((row >> 1) & 3);
    else                    return c ^ (row & 7);
}

template<int BM, int BN, int BK, int FM, int FN, int EPI>
__global__ __launch_bounds__(256)
void mfma_gemm(const u16* __restrict__ A, const u16* __restrict__ B,
               float* __restrict__ Cf, u16* __restrict__ Cb,
               u16* __restrict__ Cb2, u16* __restrict__ Cb3,
               const float* __restrict__ bias,
               int K, int lda, int ldb, int ldc,
               long sC, long sKz, float alpha,
               const float* __restrict__ base, const float* __restrict__ subv,
               const float* __restrict__ cvec, const u16* __restrict__ woutTb,
               const int* __restrict__ tcl,
               float* __restrict__ ebF, u16* __restrict__ ebB)
{
    constexpr int WC = BN / (FN * 16);
    static_assert((BM / (FM * 16)) * WC == 4, "4 waves");
    constexpr int LPR = BK / 8;      // lanes per staged row
    constexpr int RPI = 2048 / BK;   // rows per 4KB issue
    constexpr int NISS = BM / RPI + BN / RPI;   // vmem issues per stage per thread
    __shared__ __align__(16) u16 Asl[3][BM * BK];
    __shared__ __align__(16) u16 Bsl[3][BN * BK];
    const int t = threadIdx.x, l = t & 63, wid = t >> 6;
    const int m0 = blockIdx.y * BM, n0 = blockIdx.x * BN;
    const long z = blockIdx.z;
    A += z * sKz;
    B += z * sKz;
    if (Cf) Cf += z * sC;

    f32x4 acc[FM][FN] = {};
    const int rm = (wid / WC) * (FM * 16), cn = (wid % WC) * (FN * 16);
    const int lr = l & 15, hi = l >> 4;
    const int srl = t / LPR, sc = t % LPR;

    auto stage = [&](int k0, int pb) {
#pragma unroll
        for (int i = 0; i < BM / RPI; ++i) {
            int row = i * RPI + srl;
            gl_lds16(A + (size_t)(m0 + row) * lda + k0 + swz<BK>(sc, row) * 8,
                     &Asl[pb][i * 2048 + t * 8]);
        }
#pragma unroll
        for (int i = 0; i < BN / RPI; ++i) {
            int row = i * RPI + srl;
            gl_lds16(B + (size_t)(n0 + row) * ldb + k0 + swz<BK>(sc, row) * 8,
                     &Bsl[pb][i * 2048 + t * 8]);
        }
    };
    auto compute = [&](int pb) {
#pragma unroll
        for (int kk = 0; kk < BK / 32; ++kk) {
            s16x8 av[FM], bv[FN];
#pragma unroll
            for (int fm = 0; fm < FM; ++fm)
                av[fm] = *(const s16x8*)&Asl[pb][(rm + fm * 16 + lr) * BK + swz<BK>(kk * 4 + hi, lr) * 8];
#pragma unroll
            for (int fn = 0; fn < FN; ++fn)
                bv[fn] = *(const s16x8*)&Bsl[pb][(cn + fn * 16 + lr) * BK + swz<BK>(kk * 4 + hi, lr) * 8];
#pragma unroll
            for (int fm = 0; fm < FM; ++fm)
#pragma unroll
                for (int fn = 0; fn < FN; ++fn)
                    acc[fm][fn] = __builtin_amdgcn_mfma_f32_16x16x32_bf16(av[fm], bv[fn], acc[fm][fn], 0, 0, 0);
        }
    };

    const int nst = K / BK;
    stage(0, 0);
    if (nst > 1) stage(BK, 1);
    int rd = 0, wr = 2;
    for (int s = 0; s < nst; ++s) {
        if (s < nst - 1)
            asm volatile("s_waitcnt vmcnt(%0)" :: "i"(NISS) : "memory");
        else
            asm volatile("s_waitcnt vmcnt(0)" ::: "memory");
        __builtin_amdgcn_s_barrier();
        __builtin_amdgcn_sched_barrier(0);
        compute(rd);
        if (s + 2 < nst) stage((s + 2) * BK, wr);
        rd = (rd + 1 == 3) ? 0 : rd + 1;
        wr = (wr + 1 == 3) ? 0 : wr + 1;
    }

    // epilogue: per-fragment 4x4 transpose -> lane holds row (hi*4+qb), 4 consecutive cols
    const int qb = lr & 3, qi = lr >> 2;
#pragma unroll
    for (int fm = 0; fm < FM; ++fm)
#pragma unroll
        for (int fn = 0; fn < FN; ++fn) {
            const int gm = m0 + rm + fm * 16 + hi * 4 + qb;
            const int gn0 = n0 + cn + fn * 16 + qi * 4;
            const size_t idx0 = (size_t)gm * ldc + gn0;
            if constexpr (EPI == E_QKV3) {
                const int gnf = n0 + cn + fn * 16;
                const int sel = gnf >> 9;
                if (sel < 2) {
                    f32x4 v = xpose4(acc[fm][fn], qb);
                    f32x4 bv4 = *(const f32x4*)&bias[gn0];
#pragma unroll
                    for (int j = 0; j < 4; ++j) v[j] += bv4[j];
                    int b = gm >> 9, s = gm & (S_ - 1);
                    int d9 = gn0 & 511, h = d9 >> 6, d = d9 & 63;
                    u16* dst = (sel == 0) ? Cb : Cb2;
                    *(u16x4*)&dst[(((size_t)(b * H_ + h) * S_ + s) << 6) + d] = pack4(v);
                } else {
                    const int gnl = gnf + lr;
                    const int gm0 = m0 + rm + fm * 16 + hi * 4;
                    int b = gm0 >> 9, s0 = gm0 & (S_ - 1);
                    int d9 = gnl & 511, h = d9 >> 6, d = d9 & 63;
                    float bb = bias[gnl];
                    f32x4 v = acc[fm][fn];
#pragma unroll
                    for (int j = 0; j < 4; ++j) v[j] += bb;
                    *(u16x4*)&Cb3[((((size_t)(b * H_ + h)) << 6) + d) * S_ + s0] = pack4(v);
                }
            } else {
                f32x4 v = xpose4(acc[fm][fn], qb);
                if constexpr (EPI == E_F32) {
#pragma unroll
                    for (int j = 0; j < 4; ++j) v[j] *= alpha;
                    if (bias) {
                        f32x4 bv4 = *(const f32x4*)&bias[gn0];
#pragma unroll
                        for (int j = 0; j < 4; ++j) v[j] += bv4[j];
                    }
                    *(f32x4*)&Cf[idx0] = v;
                    if (Cb) *(u16x4*)&Cb[idx0] = pack4(v);
                } else if constexpr (EPI == E_OUT) {
                    f32x4 bv4 = *(const f32x4*)&bias[gn0];
#pragma unroll
                    for (int j = 0; j < 4; ++j) v[j] += bv4[j];
                    *(f32x4*)&Cf[idx0] = v;
                } else if constexpr (EPI == E_GELU) {
                    f32x4 bv4 = *(const f32x4*)&bias[gn0];
#pragma unroll
                    for (int j = 0; j < 4; ++j) v[j] = gelu_f(v[j] + bv4[j]);
                    *(u16x4*)&Cb[idx0] = pack4(v);
                } else if constexpr (EPI == E_TD) {
                    const int tc = tcl[gm];
                    f32x4 cv4 = *(const f32x4*)&cvec[gn0];
                    f32x4 ba4 = *(const f32x4*)&base[idx0];
                    u16x4 gv = *(const u16x4*)&woutTb[(size_t)tc * D_ + gn0];
                    f32x4 dlt, o2;
#pragma unroll
                    for (int j = 0; j < 4; ++j)
                        dlt[j] = GAMMA_ * (v[j] + cv4[j] - b2f(gv[j]));
                    if (subv) {
                        f32x4 sv4 = *(const f32x4*)&subv[idx0];
#pragma unroll
                        for (int j = 0; j < 4; ++j) dlt[j] -= GAMMA_ * sv4[j];
                    }
#pragma unroll
                    for (int j = 0; j < 4; ++j) o2[j] = ba4[j] + dlt[j];
                    if (Cf) *(f32x4*)&Cf[idx0] = o2;
                    *(u16x4*)&Cb[idx0] = pack4(o2);
                    if (ebF) *(f32x4*)&ebF[idx0] = dlt;
                    if (ebB) *(u16x4*)&ebB[idx0] = pack4(dlt);
                } else if constexpr (EPI == E_EC2) {
                    f32x4 ba4 = *(const f32x4*)&base[idx0];
                    f32x4 sv4 = *(const f32x4*)&subv[idx0];
#pragma unroll
                    for (int j = 0; j < 4; ++j) v[j] = ba4[j] - sv4[j] - GAMMA_ * v[j];
                    *(f32x4*)&Cf[idx0] = v;
                } else if constexpr (EPI == E_BF16) {
                    *(u16x4*)&Cb[idx0] = pack4(v);
                }
            }
        }
}

// ================= fused causal flash attention (3-buffer counted pipeline) =================
__global__ __launch_bounds__(256)
void flash_attn(const u16* __restrict__ q, const u16* __restrict__ k,
                const u16* __restrict__ vT, u16* __restrict__ ctx)
{
    __shared__ __align__(16) u16 Ks[3][64 * 64];
    __shared__ __align__(16) u16 Vs[3][64 * 64];
    __shared__ __align__(16) u16 Ps[4][16 * 64];
    const int t = threadIdx.x, l = t & 63, w = t >> 6;
    const int qt = blockIdx.x, z = blockIdx.y;
    const int bb = z >> 3, hh = z & 7;
    const int lr = l & 15, hi = l >> 4;
    const u16* qp = q + (((size_t)z * S_ + qt * 64 + w * 16) << 6);
    const u16* kp = k + ((size_t)z * S_ << 6);
    const u16* vp = vT + (((size_t)z) << 6) * S_;

    const s16x8 aq0 = *(const s16x8*)&qp[lr * 64 + hi * 8];
    const s16x8 aq1 = *(const s16x8*)&qp[lr * 64 + 32 + hi * 8];

    f32x4 o[4] = {};
    float m[4], ls[4];
#pragma unroll
    for (int r = 0; r < 4; ++r) { m[r] = -3.0e38f; ls[r] = 0.f; }
    const int qrow = qt * 64 + w * 16 + hi * 4;
    const int srow = t >> 3, scl = t & 7;
    const int cg1 = (scl ^ (srow & 7)) * 8;
    const int srow2 = srow + 32;
    const int cg2 = (scl ^ (srow2 & 7)) * 8;
    const int sw7 = (lr & 7);

    auto stage = [&](int j, int pb) {
        gl_lds16(kp + ((size_t)(j * 64 + srow) << 6) + cg1, &Ks[pb][t * 8]);
        gl_lds16(vp + (size_t)srow * S_ + j * 64 + cg1, &Vs[pb][t * 8]);
        gl_lds16(kp + ((size_t)(j * 64 + srow2) << 6) + cg2, &Ks[pb][(t + 256) * 8]);
        gl_lds16(vp + (size_t)srow2 * S_ + j * 64 + cg2, &Vs[pb][(t + 256) * 8]);
    };

    stage(0, 0);
    if (qt > 0) stage(1, 1);
    int rd = 0, wr = 2;
    for (int j = 0; j <= qt; ++j) {
        if (j < qt) asm volatile("s_waitcnt vmcnt(4)" ::: "memory");
        else        asm volatile("s_waitcnt vmcnt(0)" ::: "memory");
        __builtin_amdgcn_s_barrier();
        __builtin_amdgcn_sched_barrier(0);

        float pv[4][4];
#pragma unroll
        for (int fn = 0; fn < 4; ++fn) {
            f32x4 acc = {};
            acc = __builtin_amdgcn_mfma_f32_16x16x32_bf16(aq0,
                    *(const s16x8*)&Ks[rd][((fn * 16 + lr) << 6) + ((hi ^ sw7) * 8)], acc, 0, 0, 0);
            acc = __builtin_amdgcn_mfma_f32_16x16x32_bf16(aq1,
                    *(const s16x8*)&Ks[rd][((fn * 16 + lr) << 6) + (((hi + 4) ^ sw7) * 8)], acc, 0, 0, 0);
#pragma unroll
            for (int r = 0; r < 4; ++r) pv[fn][r] = acc[r] * 0.125f;
        }
        if (j == qt) {
#pragma unroll
            for (int fn = 0; fn < 4; ++fn) {
                int col = j * 64 + fn * 16 + lr;
#pragma unroll
                for (int r = 0; r < 4; ++r)
                    if (col > qrow + r) pv[fn][r] = -3.0e38f;
            }
        }
        float sc[4], rs[4];
#pragma unroll
        for (int r = 0; r < 4; ++r) {
            float x = fmaxf(fmaxf(pv[0][r], pv[1][r]), fmaxf(pv[2][r], pv[3][r]));
#pragma unroll
            for (int off = 1; off < 16; off <<= 1) x = fmaxf(x, __shfl_xor(x, off, 64));
            float nm = fmaxf(m[r], x);
            sc[r] = expf(m[r] - nm);
            m[r] = nm;
            rs[r] = 0.f;
        }
#pragma unroll
        for (int fn = 0; fn < 4; ++fn)
#pragma unroll
            for (int r = 0; r < 4; ++r) {
                float p = expf(pv[fn][r] - m[r]);
                pv[fn][r] = p;
                rs[r] += p;
            }
#pragma unroll
        for (int r = 0; r < 4; ++r) {
#pragma unroll
            for (int off = 1; off < 16; off <<= 1) rs[r] += __shfl_xor(rs[r], off, 64);
            ls[r] = ls[r] * sc[r] + rs[r];
        }
#pragma unroll
        for (int fn = 0; fn < 4; ++fn)
#pragma unroll
            for (int r = 0; r < 4; ++r) o[fn][r] *= sc[r];
        // P bounce via per-wave LDS (swizzled both sides, wave-local RAW)
#pragma unroll
        for (int fn = 0; fn < 4; ++fn)
#pragma unroll
            for (int r = 0; r < 4; ++r) {
                int qr = hi * 4 + r;
                int ci = (2 * fn + (lr >> 3)) ^ (qr & 7);
                Ps[w][qr * 64 + ci * 8 + (lr & 7)] = f2b(pv[fn][r]);
            }
#pragma unroll
        for (int ks = 0; ks < 2; ++ks) {
            const s16x8 pa = *(const s16x8*)&Ps[w][lr * 64 + (((4 * ks + hi) ^ sw7) * 8)];
#pragma unroll
            for (int fn = 0; fn < 4; ++fn)
                o[fn] = __builtin_amdgcn_mfma_f32_16x16x32_bf16(pa,
                        *(const s16x8*)&Vs[rd][((fn * 16 + lr) << 6) + (((hi + 4 * ks) ^ sw7) * 8)], o[fn], 0, 0, 0);
        }
        if (j + 2 <= qt) stage(j + 2, wr);
        rd = (rd + 1 == 3) ? 0 : rd + 1;
        wr = (wr + 1 == 3) ? 0 : wr + 1;
    }
    float inv[4];
#pragma unroll
    for (int r = 0; r < 4; ++r) inv[r] = 1.f / ls[r];
    u16* cp = ctx + ((size_t)(bb * S_ + qt * 64 + w * 16) * D_) + hh * 64;
    const int qb = lr & 3, qi = lr >> 2;
#pragma unroll
    for (int fn = 0; fn < 4; ++fn) {
        f32x4 v = o[fn];
#pragma unroll
        for (int r = 0; r < 4; ++r) v[r] *= inv[r];
        v = xpose4(v, qb);
        *(u16x4*)&cp[(size_t)(hi * 4 + qb) * D_ + fn * 16 + qi * 4] = pack4(v);
    }
}

// ============ prep0: zero cvec, clip targets, pack qkv bias ============
__global__ __launch_bounds__(256)
void prep0(const float* __restrict__ bq, const float* __restrict__ bk,
           const float* __restrict__ bv, const int* __restrict__ target_ids,
           float* __restrict__ qkvb, int* __restrict__ tcl, float* __restrict__ cvec)
{
    int i = blockIdx.x * 256 + threadIdx.x;
    if (i < 512) cvec[i] = 0.f;
    else if (i < 1536) {
        int mm = i - 512;
        int v = target_ids[mm];
        tcl[mm] = v < 0 ? 0 : (v > V_ - 1 ? V_ - 1 : v);
    } else if (i < 1536 + 6144) {
        int j = i - 1536;
        int b = j / 1536, r = j - b * 1536;
        qkvb[j] = (r < 512) ? bq[b * 512 + r]
                : (r < 1024) ? bk[b * 512 + r - 512] : bv[b * 512 + r - 1024];
    }
}

// ============ mega precompute: 64x64 tiles, u16x8 stores, fused casts + cvec ============
__global__ __launch_bounds__(256)
void mega_prep(const float* __restrict__ Wq, const float* __restrict__ Wk,
               const float* __restrict__ Wv, const float* __restrict__ Wo,
               const float* __restrict__ W1, const float* __restrict__ W2,
               const float* __restrict__ Wout, const float* __restrict__ bout,
               u16* __restrict__ wqkvT, u16* __restrict__ woT, u16* __restrict__ w1T,
               u16* __restrict__ w2T, u16* __restrict__ woutT,
               u16* __restrict__ woutD, float* __restrict__ cvec)
{
    __shared__ float tile[64][65];
    const int g = blockIdx.x, t = threadIdx.x;

    const float* in = nullptr;
    u16 *outT = nullptr, *outC = nullptr;
    int R = 512, C = 512, tx = 0, ty = 0;
    bool doCvec = false;

    if (g < 768) {
        int sel = g / 256, rem = g % 256, zz = rem >> 6, tl = rem & 63;
        in = (sel == 0 ? Wq : sel == 1 ? Wk : Wv) + (size_t)zz * 262144;
        outT = wqkvT + (size_t)zz * 786432 + sel * 262144;
        tx = tl & 7; ty = tl >> 3;
    } else if (g < 1024) {
        int rem = g - 768, zz = rem >> 6, tl = rem & 63;
        in = Wo + (size_t)zz * 262144; outT = woT + (size_t)zz * 262144;
        tx = tl & 7; ty = tl >> 3;
    } else if (g < 2048) {
        int rem = g - 1024, zz = rem >> 8, tl = rem & 255;
        in = W1 + (size_t)zz * 1048576; outT = w1T + (size_t)zz * 1048576;
        C = 2048; tx = tl & 31; ty = tl >> 5;
    } else if (g < 3072) {
        int rem = g - 2048, zz = rem >> 8, tl = rem & 255;
        in = W2 + (size_t)zz * 1048576; outT = w2T + (size_t)zz * 1048576;
        R = 2048; tx = tl & 7; ty = tl >> 3;
    } else {
        int tl = g - 3072;
        in = Wout; outT = woutT; outC = woutD; doCvec = true;
        C = 16384; tx = tl & 255; ty = tl >> 8;
    }

    const int r0 = ty * 64, c0 = tx * 64;
#pragma unroll
    for (int p = 0; p < 4; ++p) {
        int row = p * 16 + (t >> 4), col = (t & 15) * 4;
        float4 v = *(const float4*)&in[(size_t)(r0 + row) * C + c0 + col];
        tile[row][col] = v.x; tile[row][col + 1] = v.y;
        tile[row][col + 2] = v.z; tile[row][col + 3] = v.w;
        if (outC) {
            f32x4 fv; fv[0] = v.x; fv[1] = v.y; fv[2] = v.z; fv[3] = v.w;
            *(u16x4*)&outC[(size_t)(r0 + row) * C + c0 + col] = pack4(fv);
        }
    }
    __syncthreads();
#pragma unroll
    for (int p = 0; p < 2; ++p) {
        int orow = p * 32 + (t >> 3), oc = (t & 7) * 8;
        u16x8 o;
#pragma unroll
        for (int j = 0; j < 8; ++j) o[j] = f2b(tile[oc + j][orow]);
        *(u16x8*)&outT[(size_t)(c0 + orow) * R + r0 + oc] = o;
    }
    if (doCvec) {
        int r = t >> 2, qq = t & 3;
        float s = 0.f;
#pragma unroll
        for (int i = 0; i < 16; ++i)
            s += tile[r][qq * 16 + i] * bout[c0 + qq * 16 + i];
        s += __shfl_xor(s, 1, 64);
        s += __shfl_xor(s, 2, 64);
        if (qq == 0) atomicAdd(&cvec[r0 + r], s);
    }
}

__global__ void gred_kernel(const float* __restrict__ P, u16* __restrict__ G)
{
    int i = blockIdx.x * blockDim.x + threadIdx.x;
    if (i < D_ * D_) {
        float s = 0.f;
#pragma unroll
        for (int zz = 0; zz < 16; ++zz) s += P[(size_t)zz * D_ * D_ + i];
        G[i] = f2b(s);
    }
}

__global__ void embed_kernel(const float4* __restrict__ we, const float4* __restrict__ pe,
                             const int* __restrict__ ids, float4* __restrict__ o)
{
    int t = blockIdx.x * blockDim.x + threadIdx.x;
    int d4 = t & 127, row = t >> 7;
    int ss = row & (S_ - 1);
    int id = ids[row];
    id = id < 0 ? 0 : (id > V_ - 1 ? V_ - 1 : id);
    float4 a = we[(size_t)id * 128 + d4];
    float4 b = pe[(size_t)ss * 128 + d4];
    o[(size_t)row * 128 + d4] = make_float4(a.x + b.x, a.y + b.y, a.z + b.z, a.w + b.w);
}

// LayerNorm: wave-per-row; grid = M/4, block = 256
__global__ __launch_bounds__(256)
void ln_fwd_kernel(const float* __restrict__ x, const float* __restrict__ s,
                   const float* __restrict__ bb, u16* __restrict__ h)
{
    const int l = threadIdx.x & 63, w = threadIdx.x >> 6;
    const int row = blockIdx.x * 4 + w;
    const float* xr = x + (size_t)row * D_;
    const int c0 = l * 8;
    float4 a = *(const float4*)&xr[c0];
    float4 b = *(const float4*)&xr[c0 + 4];
    float sum = a.x + a.y + a.z + a.w + b.x + b.y + b.z + b.w;
    float mu = wave_sum(sum) * (1.f / D_);
    float d0 = a.x - mu, d1 = a.y - mu, d2 = a.z - mu, d3 = a.w - mu;
    float d4 = b.x - mu, d5 = b.y - mu, d6 = b.z - mu, d7 = b.w - mu;
    float vs = d0*d0 + d1*d1 + d2*d2 + d3*d3 + d4*d4 + d5*d5 + d6*d6 + d7*d7;
    float var = wave_sum(vs) * (1.f / D_);
    float r = rsqrtf(var + 1e-5f);
    float4 s0 = *(const float4*)&s[c0], s1 = *(const float4*)&s[c0 + 4];
    float4 b0 = *(const float4*)&bb[c0], b1 = *(const float4*)&bb[c0 + 4];
    u16* hr = h + (size_t)row * D_;
    f32x4 o0, o1;
    o0[0] = d0 * r * s0.x + b0.x; o0[1] = d1 * r * s0.y + b0.y;
    o0[2] = d2 * r * s0.z + b0.z; o0[3] = d3 * r * s0.w + b0.w;
    o1[0] = d4 * r * s1.x + b1.x; o1[1] = d5 * r * s1.y + b1.y;
    o1[2] = d6 * r * s1.z + b1.z; o1[3] = d7 * r * s1.w + b1.w;
    *(u16x4*)&hr[c0] = pack4(o0);
    *(u16x4*)&hr[c0 + 4] = pack4(o1);
}

// ================= host =================
extern "C" void kernel_launch(void* const* d_in, const int* in_sizes, int n_in,
                              void* d_out, int out_size, void* d_ws, size_t ws_size,
                              hipStream_t stream)
{
    (void)in_sizes; (void)n_in; (void)out_size;
    const float* Wq  = (const float*)d_in[2];
    const float* Wk  = (const float*)d_in[3];
    const float* Wv  = (const float*)d_in[4];
    const float* bq  = (const float*)d_in[5];
    const float* bk  = (const float*)d_in[6];
    const float* bv  = (const float*)d_in[7];
    const float* Wo  = (const float*)d_in[8];
    const float* bo  = (const float*)d_in[9];
    const float* ln1_s = (const float*)d_in[10];
    const float* ln1_b = (const float*)d_in[11];
    const float* ln2_s = (const float*)d_in[12];
    const float* ln2_b = (const float*)d_in[13];
    const float* W1  = (const float*)d_in[14];
    const float* b1  = (const float*)d_in[15];
    const float* W2  = (const float*)d_in[16];
    const float* b2  = (const float*)d_in[17];
    const float* Wout = (const float*)d_in[18];
    const float* bout = (const float*)d_in[19];
    const int* input_ids  = (const int*)d_in[20];
    const int* target_ids = (const int*)d_in[21];
    float* out = (float*)d_out;

    // ---- workspace carve ----
    char* wsb = (char*)d_ws;
    size_t off = 0;
    auto alloc = [&](size_t bytes) -> void* {
        off = (off + 255) & ~(size_t)255;
        void* p = wsb + off; off += bytes; return p;
    };
    u16* wqkvT = (u16*)alloc((size_t)4 * 1536 * D_ * 2);
    u16* woT   = (u16*)alloc((size_t)4 * D_ * D_ * 2);
    u16* w1T   = (u16*)alloc((size_t)4 * D_ * F_ * 2);
    u16* w2T   = (u16*)alloc((size_t)4 * D_ * F_ * 2);
    u16* woutT = (u16*)alloc((size_t)V_ * D_ * 2);
    u16* G_b   = (u16*)alloc((size_t)D_ * D_ * 2);
    u16* H2_b  = (u16*)alloc((size_t)D_ * D_ * 2);
    float* qkvb = (float*)alloc((size_t)4 * 1536 * 4);
    float* bufB = (float*)alloc((size_t)MD_ * 4);
    u16* h_b    = (u16*)alloc((size_t)MD_ * 2);
    u16* gelu_b = (u16*)alloc((size_t)MF_ * 2);
    u16* x16_b  = (u16*)alloc((size_t)MD_ * 2);
    float* cvec = (float*)alloc(D_ * 4);
    int* tcl    = (int*)alloc(M_ * 4);
    size_t uStart = (off + 255) & ~(size_t)255;
    // phase G (precompute)
    off = uStart;
    u16* woutD   = (u16*)alloc((size_t)V_ * D_ * 2);
    float* Gpart = (float*)alloc((size_t)16 * D_ * D_ * 4);
    size_t endG = off;
    // phase attention
    off = uStart;
    u16* q_b   = (u16*)alloc((size_t)MD_ * 2);
    u16* k_b   = (u16*)alloc((size_t)MD_ * 2);
    u16* v_b   = (u16*)alloc((size_t)MD_ * 2);
    u16* ctx_b = (u16*)alloc((size_t)MD_ * 2);
    size_t endA = off;
    // phase tail
    off = uStart;
    float* xA  = (float*)alloc((size_t)MD_ * 4);
    float* xB  = (float*)alloc((size_t)MD_ * 4);
    float* eb  = (float*)alloc((size_t)MD_ * 4);
    float* ec  = (float*)alloc((size_t)MD_ * 4);
    u16* xA_b  = (u16*)alloc((size_t)MD_ * 2);
    u16* xB_b  = (u16*)alloc((size_t)MD_ * 2);
    u16* xC_b  = (u16*)alloc((size_t)MD_ * 2);
    u16* eb_b  = (u16*)alloc((size_t)MD_ * 2);
    size_t endT = off;
    size_t need = endG > endA ? endG : endA;
    if (endT > need) need = endT;
    if (need > ws_size) return;

    dim3 blk(256);
    const long NL = 0;
    #define GZ nullptr, nullptr, nullptr, nullptr, nullptr, nullptr, nullptr

    // ---- precompute ----
    prep0<<<dim3(32), blk, 0, stream>>>(bq, bk, bv, target_ids, qkvb, tcl, cvec);
    mega_prep<<<dim3(5120), blk, 0, stream>>>(Wq, Wk, Wv, Wo, W1, W2, Wout, bout,
        wqkvT, woT, w1T, w2T, woutT, woutD, cvec);
    // G = Wout @ Wout^T, split-K 16 x 1024
    mfma_gemm<128, 128, 64, 4, 4, E_F32><<<dim3(4, 4, 16), blk, 0, stream>>>(
        woutD, woutD, Gpart, nullptr, nullptr, nullptr, nullptr, 1024, V_, V_, D_,
        (long)D_ * D_, 1024, 1.f, GZ);
    gred_kernel<<<dim3(1024), blk, 0, stream>>>(Gpart, G_b);
    // H2 = W2[3]^T @ W2[3]  (from w2T, NT form)
    mfma_gemm<64, 64, 64, 2, 2, E_BF16><<<dim3(8, 8, 1), blk, 0, stream>>>(
        w2T + (size_t)3 * D_ * F_, w2T + (size_t)3 * D_ * F_, nullptr, H2_b,
        nullptr, nullptr, nullptr, F_, F_, F_, D_, NL, NL, 1.f, GZ);

    // ---- forward sweep ----
    embed_kernel<<<dim3(512), blk, 0, stream>>>((const float4*)d_in[0], (const float4*)d_in[1],
                                                input_ids, (float4*)bufB);
    for (int b = 0; b < 4; ++b) {
        const size_t wDD = (size_t)b * D_ * D_, wDF = (size_t)b * D_ * F_;
        ln_fwd_kernel<<<dim3(M_ / 4), blk, 0, stream>>>(bufB, ln1_s + b * D_, ln1_b + b * D_, h_b);
        mfma_gemm<128, 64, 64, 4, 2, E_QKV3><<<dim3(24, 8, 1), blk, 0, stream>>>(
            h_b, wqkvT + (size_t)b * 1536 * 512, nullptr, q_b, k_b, v_b,
            qkvb + b * 1536, D_, D_, D_, 0, NL, NL, 1.f, GZ);
        flash_attn<<<dim3(8, 16), blk, 0, stream>>>(q_b, k_b, v_b, ctx_b);
        mfma_gemm<64, 64, 64, 2, 2, E_F32><<<dim3(8, 16, 1), blk, 0, stream>>>(
            ctx_b, woT + wDD, bufB, nullptr, nullptr, nullptr, bo + b * D_,
            D_, D_, D_, D_, NL, NL, 1.f, GZ);
        ln_fwd_kernel<<<dim3(M_ / 4), blk, 0, stream>>>(bufB, ln2_s + b * D_, ln2_b + b * D_, h_b);
        mfma_gemm<64, 64, 64, 2, 2, E_GELU><<<dim3(32, 16, 1), blk, 0, stream>>>(
            h_b, w1T + wDF, nullptr, gelu_b, nullptr, nullptr, b1 + b * F_,
            D_, D_, D_, F_, NL, NL, 1.f, GZ);
        mfma_gemm<64, 64, 64, 2, 2, E_F32><<<dim3(8, 16, 1), blk, 0, stream>>>(
            gelu_b, w2T + wDF, bufB, (b == 3) ? x16_b : nullptr, nullptr, nullptr, b2 + b * D_,
            F_, F_, F_, D_, NL, NL, 1.f, GZ);
    }
    // x16 f32 = bufB, x16 bf16 = x16_b

    // ---- PC tail ----
    mfma_gemm<64, 64, 64, 2, 2, E_TD><<<dim3(8, 16, 1), blk, 0, stream>>>(
        x16_b, G_b, xA, xA_b, nullptr, nullptr, nullptr, D_, D_, D_, D_, NL, NL, 1.f,
        bufB, nullptr, cvec, woutT, tcl, eb, eb_b);
    mfma_gemm<64, 64, 64, 2, 2, E_TD><<<dim3(8, 16, 1), blk, 0, stream>>>(
        xA_b, G_b, xB, xB_b, nullptr, nullptr, nullptr, D_, D_, D_, D_, NL, NL, 1.f,
        xA, eb, cvec, woutT, tcl, nullptr, nullptr);
    mfma_gemm<64, 64, 64, 2, 2, E_EC2><<<dim3(8, 16, 1), blk, 0, stream>>>(
        eb_b, H2_b, ec, nullptr, nullptr, nullptr, nullptr, D_, D_, D_, D_, NL, NL, 1.f,
        xB, bufB, nullptr, nullptr, nullptr, nullptr, nullptr);
    mfma_gemm<64, 64, 64, 2, 2, E_TD><<<dim3(8, 16, 1), blk, 0, stream>>>(
        xB_b, G_b, nullptr, xC_b, nullptr, nullptr, nullptr, D_, D_, D_, D_, NL, NL, 1.f,
        xB, ec, cvec, woutT, tcl, nullptr, nullptr);
    // final: out = xC @ Wout + bout (128x256 tile, BK=32, 3-buf counted pipeline)
    mfma_gemm<128, 256, 32, 4, 8, E_OUT><<<dim3(64, 8, 1), blk, 0, stream>>>(
        xC_b, woutT, out, nullptr, nullptr, nullptr, bout, D_, D_, D_, V_, NL, NL, 1.f, GZ);
    #undef GZ
}

// Round 9
// 386.901 us; speedup vs baseline: 14.2594x; 1.0955x over previous
//
#include <hip/hip_runtime.h>
#include <hip/hip_bf16.h>
#include <math.h>

#define D_   512
#define F_   2048
#define V_   16384
#define H_   8
#define DH_  64
#define S_   512
#define B_   2
#define M_   1024
#define MD_  (M_ * D_)
#define MF_  (M_ * F_)
#define GAMMA_ 0.1f

typedef unsigned int u32;
typedef unsigned short u16;
typedef __attribute__((ext_vector_type(4))) float f32x4;
typedef __attribute__((ext_vector_type(8))) short s16x8;
typedef __attribute__((ext_vector_type(4))) u16 u16x4;
typedef __attribute__((ext_vector_type(8))) u16 u16x8;

__device__ __forceinline__ u16 f2b(float f) {
    __hip_bfloat16 h = __float2bfloat16(f);   // RTNE
    return *reinterpret_cast<u16*>(&h);
}
__device__ __forceinline__ float b2f(u16 v) {
    u32 u = ((u32)v) << 16;
    float f; __builtin_memcpy(&f, &u, 4); return f;
}
__device__ __forceinline__ u16x4 pack4(f32x4 v) {
    u16x4 o; o.x = f2b(v[0]); o.y = f2b(v[1]); o.z = f2b(v[2]); o.w = f2b(v[3]);
    return o;
}

__device__ __forceinline__ void gl_lds16(const void* g, void* l) {
    __builtin_amdgcn_global_load_lds((const __attribute__((address_space(1))) u32*)g,
                                     (__attribute__((address_space(3))) u32*)l, 16, 0, 0);
}

__device__ __forceinline__ float gelu_f(float v) {
    float u = 0.7978845608028654f * (v + 0.044715f * v * v * v);
    return 0.5f * v * (1.f + tanhf(u));
}

// 4x4 transpose across lane quads; lane b: reg r holds Sub[r][b] -> reg j holds Sub[b][j]
__device__ __forceinline__ f32x4 xpose4(f32x4 v, int b) {
#pragma unroll
    for (int s = 1; s < 4; s <<= 1) {
        f32x4 nv;
#pragma unroll
        for (int j = 0; j < 4; ++j) {
            float ex = __shfl_xor(v[j ^ s], s, 64);
            nv[j] = ((b ^ j) & s) ? ex : v[j];
        }
        v = nv;
    }
    return v;
}

__device__ __forceinline__ float wave_sum(float v) {
#pragma unroll
    for (int o = 32; o > 0; o >>= 1) v += __shfl_xor(v, o, 64);
    return v;
}

// ================= MFMA GEMM (NT: A MxK row-major, B NxK row-major, bf16) ===========
// 3-buffer counted-vmcnt pipeline (T3+T4).
#define E_F32   0
#define E_GELU  1
#define E_TD    2   // dlt=g*(acc+cvec[n]-woutT[tcl[m]*D+n]-subv); o=base+dlt
#define E_EC2   3   // Cf = base - subv - g*acc
#define E_QKV3  4
#define E_OUT   5   // f32 + bias (final logits)
#define E_BF16  6   // Cb = bf16(acc)

// per-BK bank-conflict-free chunk swizzle (chunk = 8 u16 = 16 B)
template<int BK>
__device__ __forceinline__ int swz(int c, int row) {
    if constexpr (BK == 32) return c ^ ((row >> 1) & 3);
    else                    return c ^ (row & 7);
}

template<int BM, int BN, int BK, int FM, int FN, int EPI>
__global__ __launch_bounds__(256)
void mfma_gemm(const u16* __restrict__ A, const u16* __restrict__ B,
               float* __restrict__ Cf, u16* __restrict__ Cb,
               u16* __restrict__ Cb2, u16* __restrict__ Cb3,
               const float* __restrict__ bias,
               int K, int lda, int ldb, int ldc,
               long sC, long sKz, float alpha,
               const float* __restrict__ base, const float* __restrict__ subv,
               const float* __restrict__ cvec, const u16* __restrict__ woutTb,
               const int* __restrict__ tcl,
               float* __restrict__ ebF, u16* __restrict__ ebB)
{
    constexpr int WC = BN / (FN * 16);
    static_assert((BM / (FM * 16)) * WC == 4, "4 waves");
    constexpr int LPR = BK / 8;      // lanes per staged row
    constexpr int RPI = 2048 / BK;   // rows per 4KB issue
    constexpr int NISS = BM / RPI + BN / RPI;   // vmem issues per stage per thread
    __shared__ __align__(16) u16 Asl[3][BM * BK];
    __shared__ __align__(16) u16 Bsl[3][BN * BK];
    const int t = threadIdx.x, l = t & 63, wid = t >> 6;
    const int m0 = blockIdx.y * BM, n0 = blockIdx.x * BN;
    const long z = blockIdx.z;
    A += z * sKz;
    B += z * sKz;
    if (Cf) Cf += z * sC;

    f32x4 acc[FM][FN] = {};
    const int rm = (wid / WC) * (FM * 16), cn = (wid % WC) * (FN * 16);
    const int lr = l & 15, hi = l >> 4;
    const int srl = t / LPR, sc = t % LPR;

    auto stage = [&](int k0, int pb) {
#pragma unroll
        for (int i = 0; i < BM / RPI; ++i) {
            int row = i * RPI + srl;
            gl_lds16(A + (size_t)(m0 + row) * lda + k0 + swz<BK>(sc, row) * 8,
                     &Asl[pb][i * 2048 + t * 8]);
        }
#pragma unroll
        for (int i = 0; i < BN / RPI; ++i) {
            int row = i * RPI + srl;
            gl_lds16(B + (size_t)(n0 + row) * ldb + k0 + swz<BK>(sc, row) * 8,
                     &Bsl[pb][i * 2048 + t * 8]);
        }
    };
    auto compute = [&](int pb) {
#pragma unroll
        for (int kk = 0; kk < BK / 32; ++kk) {
            s16x8 av[FM], bv[FN];
#pragma unroll
            for (int fm = 0; fm < FM; ++fm)
                av[fm] = *(const s16x8*)&Asl[pb][(rm + fm * 16 + lr) * BK + swz<BK>(kk * 4 + hi, lr) * 8];
#pragma unroll
            for (int fn = 0; fn < FN; ++fn)
                bv[fn] = *(const s16x8*)&Bsl[pb][(cn + fn * 16 + lr) * BK + swz<BK>(kk * 4 + hi, lr) * 8];
#pragma unroll
            for (int fm = 0; fm < FM; ++fm)
#pragma unroll
                for (int fn = 0; fn < FN; ++fn)
                    acc[fm][fn] = __builtin_amdgcn_mfma_f32_16x16x32_bf16(av[fm], bv[fn], acc[fm][fn], 0, 0, 0);
        }
    };

    const int nst = K / BK;
    stage(0, 0);
    if (nst > 1) stage(BK, 1);
    int rd = 0, wr = 2;
    for (int s = 0; s < nst; ++s) {
        if (s < nst - 1)
            asm volatile("s_waitcnt vmcnt(%0)" :: "i"(NISS) : "memory");
        else
            asm volatile("s_waitcnt vmcnt(0)" ::: "memory");
        __builtin_amdgcn_s_barrier();
        __builtin_amdgcn_sched_barrier(0);
        compute(rd);
        if (s + 2 < nst) stage((s + 2) * BK, wr);
        rd = (rd + 1 == 3) ? 0 : rd + 1;
        wr = (wr + 1 == 3) ? 0 : wr + 1;
    }

    // epilogue
    const int qb = lr & 3, qi = lr >> 2;
#pragma unroll
    for (int fm = 0; fm < FM; ++fm)
#pragma unroll
        for (int fn = 0; fn < FN; ++fn) {
            const int gm = m0 + rm + fm * 16 + hi * 4 + qb;
            const int gn0 = n0 + cn + fn * 16 + qi * 4;
            const size_t idx0 = (size_t)gm * ldc + gn0;
            if constexpr (EPI == E_QKV3) {
                const int gnf = n0 + cn + fn * 16;
                const int sel = gnf >> 9;
                if (sel < 2) {
                    f32x4 v = xpose4(acc[fm][fn], qb);
                    f32x4 bv4 = *(const f32x4*)&bias[gn0];
#pragma unroll
                    for (int j = 0; j < 4; ++j) v[j] += bv4[j];
                    int b = gm >> 9, s = gm & (S_ - 1);
                    int d9 = gn0 & 511, h = d9 >> 6, d = d9 & 63;
                    u16* dst = (sel == 0) ? Cb : Cb2;
                    *(u16x4*)&dst[(((size_t)(b * H_ + h) * S_ + s) << 6) + d] = pack4(v);
                } else {
                    const int gnl = gnf + lr;
                    const int gm0 = m0 + rm + fm * 16 + hi * 4;
                    int b = gm0 >> 9, s0 = gm0 & (S_ - 1);
                    int d9 = gnl & 511, h = d9 >> 6, d = d9 & 63;
                    float bb = bias[gnl];
                    f32x4 v = acc[fm][fn];
#pragma unroll
                    for (int j = 0; j < 4; ++j) v[j] += bb;
                    *(u16x4*)&Cb3[((((size_t)(b * H_ + h)) << 6) + d) * S_ + s0] = pack4(v);
                }
            } else {
                f32x4 v = xpose4(acc[fm][fn], qb);
                if constexpr (EPI == E_F32) {
#pragma unroll
                    for (int j = 0; j < 4; ++j) v[j] *= alpha;
                    if (bias) {
                        f32x4 bv4 = *(const f32x4*)&bias[gn0];
#pragma unroll
                        for (int j = 0; j < 4; ++j) v[j] += bv4[j];
                    }
                    *(f32x4*)&Cf[idx0] = v;
                    if (Cb) *(u16x4*)&Cb[idx0] = pack4(v);
                } else if constexpr (EPI == E_OUT) {
                    f32x4 bv4 = *(const f32x4*)&bias[gn0];
#pragma unroll
                    for (int j = 0; j < 4; ++j) v[j] += bv4[j];
                    *(f32x4*)&Cf[idx0] = v;
                } else if constexpr (EPI == E_GELU) {
                    f32x4 bv4 = *(const f32x4*)&bias[gn0];
#pragma unroll
                    for (int j = 0; j < 4; ++j) v[j] = gelu_f(v[j] + bv4[j]);
                    *(u16x4*)&Cb[idx0] = pack4(v);
                } else if constexpr (EPI == E_TD) {
                    const int tc = tcl[gm];
                    f32x4 cv4 = *(const f32x4*)&cvec[gn0];
                    f32x4 ba4 = *(const f32x4*)&base[idx0];
                    u16x4 gv = *(const u16x4*)&woutTb[(size_t)tc * D_ + gn0];
                    f32x4 dlt, o2;
#pragma unroll
                    for (int j = 0; j < 4; ++j)
                        dlt[j] = GAMMA_ * (v[j] + cv4[j] - b2f(gv[j]));
                    if (subv) {
                        f32x4 sv4 = *(const f32x4*)&subv[idx0];
#pragma unroll
                        for (int j = 0; j < 4; ++j) dlt[j] -= GAMMA_ * sv4[j];
                    }
#pragma unroll
                    for (int j = 0; j < 4; ++j) o2[j] = ba4[j] + dlt[j];
                    if (Cf) *(f32x4*)&Cf[idx0] = o2;
                    *(u16x4*)&Cb[idx0] = pack4(o2);
                    if (ebF) *(f32x4*)&ebF[idx0] = dlt;
                    if (ebB) *(u16x4*)&ebB[idx0] = pack4(dlt);
                } else if constexpr (EPI == E_EC2) {
                    f32x4 ba4 = *(const f32x4*)&base[idx0];
                    f32x4 sv4 = *(const f32x4*)&subv[idx0];
#pragma unroll
                    for (int j = 0; j < 4; ++j) v[j] = ba4[j] - sv4[j] - GAMMA_ * v[j];
                    *(f32x4*)&Cf[idx0] = v;
                } else if constexpr (EPI == E_BF16) {
                    *(u16x4*)&Cb[idx0] = pack4(v);
                }
            }
        }
}

// ======== fused causal flash attention: QBLK=32, 2 waves, grid (S/32, B*H) ========
__global__ __launch_bounds__(128)
void flash_attn(const u16* __restrict__ q, const u16* __restrict__ k,
                const u16* __restrict__ vT, u16* __restrict__ ctx)
{
    __shared__ __align__(16) u16 Ks[3][64 * 64];
    __shared__ __align__(16) u16 Vs[3][64 * 64];
    __shared__ __align__(16) u16 Ps[2][16 * 64];
    const int t = threadIdx.x, l = t & 63, w = t >> 6;   // 2 waves
    const int qt = blockIdx.x, z = blockIdx.y;
    const int bb = z >> 3, hh = z & 7;
    const int lr = l & 15, hi = l >> 4;
    const u16* qp = q + (((size_t)z * S_ + qt * 32 + w * 16) << 6);
    const u16* kp = k + ((size_t)z * S_ << 6);
    const u16* vp = vT + (((size_t)z) << 6) * S_;

    const s16x8 aq0 = *(const s16x8*)&qp[lr * 64 + hi * 8];
    const s16x8 aq1 = *(const s16x8*)&qp[lr * 64 + 32 + hi * 8];

    f32x4 o[4] = {};
    float m[4], ls[4];
#pragma unroll
    for (int r = 0; r < 4; ++r) { m[r] = -3.0e38f; ls[r] = 0.f; }
    const int qrow = qt * 32 + w * 16 + hi * 4;
    const int srow = t >> 3, scl = t & 7;                // srow in [0,16)
    const int cg = (scl ^ (srow & 7)) * 8;               // (row+16i)&7 == row&7
    const int sw7 = (lr & 7);
    const int jmax = qt >> 1;

    auto stage = [&](int j, int pb) {
#pragma unroll
        for (int i = 0; i < 4; ++i)
            gl_lds16(kp + ((size_t)(j * 64 + i * 16 + srow) << 6) + cg,
                     &Ks[pb][i * 1024 + t * 8]);
#pragma unroll
        for (int i = 0; i < 4; ++i)
            gl_lds16(vp + (size_t)(i * 16 + srow) * S_ + j * 64 + cg,
                     &Vs[pb][i * 1024 + t * 8]);
    };

    stage(0, 0);
    if (jmax > 0) stage(1, 1);
    int rd = 0, wr = 2;
    for (int j = 0; j <= jmax; ++j) {
        if (j < jmax) asm volatile("s_waitcnt vmcnt(8)" ::: "memory");
        else          asm volatile("s_waitcnt vmcnt(0)" ::: "memory");
        __builtin_amdgcn_s_barrier();
        __builtin_amdgcn_sched_barrier(0);

        float pv[4][4];
#pragma unroll
        for (int fn = 0; fn < 4; ++fn) {
            f32x4 acc = {};
            acc = __builtin_amdgcn_mfma_f32_16x16x32_bf16(aq0,
                    *(const s16x8*)&Ks[rd][((fn * 16 + lr) << 6) + ((hi ^ sw7) * 8)], acc, 0, 0, 0);
            acc = __builtin_amdgcn_mfma_f32_16x16x32_bf16(aq1,
                    *(const s16x8*)&Ks[rd][((fn * 16 + lr) << 6) + (((hi + 4) ^ sw7) * 8)], acc, 0, 0, 0);
#pragma unroll
            for (int r = 0; r < 4; ++r) pv[fn][r] = acc[r] * 0.125f;
        }
        if (j == jmax) {
#pragma unroll
            for (int fn = 0; fn < 4; ++fn) {
                int col = j * 64 + fn * 16 + lr;
#pragma unroll
                for (int r = 0; r < 4; ++r)
                    if (col > qrow + r) pv[fn][r] = -3.0e38f;
            }
        }
        float sc[4], rs[4];
#pragma unroll
        for (int r = 0; r < 4; ++r) {
            float x = fmaxf(fmaxf(pv[0][r], pv[1][r]), fmaxf(pv[2][r], pv[3][r]));
#pragma unroll
            for (int off = 1; off < 16; off <<= 1) x = fmaxf(x, __shfl_xor(x, off, 64));
            float nm = fmaxf(m[r], x);
            sc[r] = expf(m[r] - nm);
            m[r] = nm;
            rs[r] = 0.f;
        }
#pragma unroll
        for (int fn = 0; fn < 4; ++fn)
#pragma unroll
            for (int r = 0; r < 4; ++r) {
                float p = expf(pv[fn][r] - m[r]);
                pv[fn][r] = p;
                rs[r] += p;
            }
#pragma unroll
        for (int r = 0; r < 4; ++r) {
#pragma unroll
            for (int off = 1; off < 16; off <<= 1) rs[r] += __shfl_xor(rs[r], off, 64);
            ls[r] = ls[r] * sc[r] + rs[r];
        }
#pragma unroll
        for (int fn = 0; fn < 4; ++fn)
#pragma unroll
            for (int r = 0; r < 4; ++r) o[fn][r] *= sc[r];
        // P bounce via per-wave LDS (swizzled both sides, wave-local RAW)
#pragma unroll
        for (int fn = 0; fn < 4; ++fn)
#pragma unroll
            for (int r = 0; r < 4; ++r) {
                int qr = hi * 4 + r;
                int ci = (2 * fn + (lr >> 3)) ^ (qr & 7);
                Ps[w][qr * 64 + ci * 8 + (lr & 7)] = f2b(pv[fn][r]);
            }
#pragma unroll
        for (int ks = 0; ks < 2; ++ks) {
            const s16x8 pa = *(const s16x8*)&Ps[w][lr * 64 + (((4 * ks + hi) ^ sw7) * 8)];
#pragma unroll
            for (int fn = 0; fn < 4; ++fn)
                o[fn] = __builtin_amdgcn_mfma_f32_16x16x32_bf16(pa,
                        *(const s16x8*)&Vs[rd][((fn * 16 + lr) << 6) + (((hi + 4 * ks) ^ sw7) * 8)], o[fn], 0, 0, 0);
        }
        if (j + 2 <= jmax) stage(j + 2, wr);
        rd = (rd + 1 == 3) ? 0 : rd + 1;
        wr = (wr + 1 == 3) ? 0 : wr + 1;
    }
    float inv[4];
#pragma unroll
    for (int r = 0; r < 4; ++r) inv[r] = 1.f / ls[r];
    u16* cp = ctx + ((size_t)(bb * S_ + qt * 32 + w * 16) * D_) + hh * 64;
    const int qb = lr & 3, qi = lr >> 2;
#pragma unroll
    for (int fn = 0; fn < 4; ++fn) {
        f32x4 v = o[fn];
#pragma unroll
        for (int r = 0; r < 4; ++r) v[r] *= inv[r];
        v = xpose4(v, qb);
        *(u16x4*)&cp[(size_t)(hi * 4 + qb) * D_ + fn * 16 + qi * 4] = pack4(v);
    }
}

// ============ mega precompute: 64x64 tiles, u16x8 stores, fused casts + misc ============
__global__ __launch_bounds__(256)
void mega_prep(const float* __restrict__ Wq, const float* __restrict__ Wk,
               const float* __restrict__ Wv, const float* __restrict__ Wo,
               const float* __restrict__ W1, const float* __restrict__ W2,
               const float* __restrict__ Wout,
               const float* __restrict__ bq, const float* __restrict__ bk,
               const float* __restrict__ bv, const int* __restrict__ target_ids,
               u16* __restrict__ wqkvT, u16* __restrict__ woT, u16* __restrict__ w1T,
               u16* __restrict__ w2T, u16* __restrict__ woutT,
               u16* __restrict__ woutD, float* __restrict__ qkvb, int* __restrict__ tcl)
{
    __shared__ float tile[64][65];
    const int g = blockIdx.x, t = threadIdx.x;

    const float* in = nullptr;
    u16 *outT = nullptr, *outC = nullptr;
    int R = 512, C = 512, tx = 0, ty = 0;

    if (g < 768) {
        int sel = g / 256, rem = g % 256, zz = rem >> 6, tl = rem & 63;
        in = (sel == 0 ? Wq : sel == 1 ? Wk : Wv) + (size_t)zz * 262144;
        outT = wqkvT + (size_t)zz * 786432 + sel * 262144;
        tx = tl & 7; ty = tl >> 3;
    } else if (g < 1024) {
        int rem = g - 768, zz = rem >> 6, tl = rem & 63;
        in = Wo + (size_t)zz * 262144; outT = woT + (size_t)zz * 262144;
        tx = tl & 7; ty = tl >> 3;
    } else if (g < 2048) {
        int rem = g - 1024, zz = rem >> 8, tl = rem & 255;
        in = W1 + (size_t)zz * 1048576; outT = w1T + (size_t)zz * 1048576;
        C = 2048; tx = tl & 31; ty = tl >> 5;
    } else if (g < 3072) {
        int rem = g - 2048, zz = rem >> 8, tl = rem & 255;
        in = W2 + (size_t)zz * 1048576; outT = w2T + (size_t)zz * 1048576;
        R = 2048; tx = tl & 7; ty = tl >> 3;
    } else if (g < 5120) {
        int tl = g - 3072;
        in = Wout; outT = woutT; outC = woutD;
        C = 16384; tx = tl & 255; ty = tl >> 8;
    } else {        // misc: tclip + qkv bias pack
        for (int i = t; i < M_; i += 256) {
            int v = target_ids[i];
            tcl[i] = v < 0 ? 0 : (v > V_ - 1 ? V_ - 1 : v);
        }
        for (int i = t; i < 4 * 1536; i += 256) {
            int b = i / 1536, j = i - b * 1536;
            qkvb[i] = (j < 512) ? bq[b * 512 + j]
                    : (j < 1024) ? bk[b * 512 + j - 512] : bv[b * 512 + j - 1024];
        }
        return;
    }

    const int r0 = ty * 64, c0 = tx * 64;
#pragma unroll
    for (int p = 0; p < 4; ++p) {
        int row = p * 16 + (t >> 4), col = (t & 15) * 4;
        float4 v = *(const float4*)&in[(size_t)(r0 + row) * C + c0 + col];
        tile[row][col] = v.x; tile[row][col + 1] = v.y;
        tile[row][col + 2] = v.z; tile[row][col + 3] = v.w;
        if (outC) {
            f32x4 fv; fv[0] = v.x; fv[1] = v.y; fv[2] = v.z; fv[3] = v.w;
            *(u16x4*)&outC[(size_t)(r0 + row) * C + c0 + col] = pack4(fv);
        }
    }
    __syncthreads();
#pragma unroll
    for (int p = 0; p < 2; ++p) {
        int orow = p * 32 + (t >> 3), oc = (t & 7) * 8;
        u16x8 o;
#pragma unroll
        for (int j = 0; j < 8; ++j) o[j] = f2b(tile[oc + j][orow]);
        *(u16x8*)&outT[(size_t)(c0 + orow) * R + r0 + oc] = o;
    }
}

// ============ gred (G partial reduce) + cvec (Wout @ bout) in one dispatch ============
__global__ __launch_bounds__(256)
void gredcvec(const float* __restrict__ P, u16* __restrict__ G,
              const u16* __restrict__ woutD, const float* __restrict__ bout,
              float* __restrict__ cvec)
{
    const int blk = blockIdx.x;
    if (blk < 1024) {
        int i = blk * 256 + threadIdx.x;
        float s = 0.f;
#pragma unroll
        for (int zz = 0; zz < 16; ++zz) s += P[(size_t)zz * D_ * D_ + i];
        G[i] = f2b(s);
    } else {
        const int w = threadIdx.x >> 6, l = threadIdx.x & 63;
        const int d = (blk - 1024) * 4 + w;
        float s = 0.f;
        for (int it = 0; it < 32; ++it) {
            int base = it * 512 + l * 8;
            u16x8 wv = *(const u16x8*)&woutD[(size_t)d * V_ + base];
            float4 b0 = *(const float4*)&bout[base];
            float4 b1 = *(const float4*)&bout[base + 4];
            s += b2f(wv[0]) * b0.x + b2f(wv[1]) * b0.y + b2f(wv[2]) * b0.z + b2f(wv[3]) * b0.w
               + b2f(wv[4]) * b1.x + b2f(wv[5]) * b1.y + b2f(wv[6]) * b1.z + b2f(wv[7]) * b1.w;
        }
        s = wave_sum(s);
        if (l == 0) cvec[d] = s;
    }
}

__global__ void embed_kernel(const float4* __restrict__ we, const float4* __restrict__ pe,
                             const int* __restrict__ ids, float4* __restrict__ o)
{
    int t = blockIdx.x * blockDim.x + threadIdx.x;
    int d4 = t & 127, row = t >> 7;
    int ss = row & (S_ - 1);
    int id = ids[row];
    id = id < 0 ? 0 : (id > V_ - 1 ? V_ - 1 : id);
    float4 a = we[(size_t)id * 128 + d4];
    float4 b = pe[(size_t)ss * 128 + d4];
    o[(size_t)row * 128 + d4] = make_float4(a.x + b.x, a.y + b.y, a.z + b.z, a.w + b.w);
}

// LayerNorm: wave-per-row; grid = M/4, block = 256
__global__ __launch_bounds__(256)
void ln_fwd_kernel(const float* __restrict__ x, const float* __restrict__ s,
                   const float* __restrict__ bb, u16* __restrict__ h)
{
    const int l = threadIdx.x & 63, w = threadIdx.x >> 6;
    const int row = blockIdx.x * 4 + w;
    const float* xr = x + (size_t)row * D_;
    const int c0 = l * 8;
    float4 a = *(const float4*)&xr[c0];
    float4 b = *(const float4*)&xr[c0 + 4];
    float sum = a.x + a.y + a.z + a.w + b.x + b.y + b.z + b.w;
    float mu = wave_sum(sum) * (1.f / D_);
    float d0 = a.x - mu, d1 = a.y - mu, d2 = a.z - mu, d3 = a.w - mu;
    float d4 = b.x - mu, d5 = b.y - mu, d6 = b.z - mu, d7 = b.w - mu;
    float vs = d0*d0 + d1*d1 + d2*d2 + d3*d3 + d4*d4 + d5*d5 + d6*d6 + d7*d7;
    float var = wave_sum(vs) * (1.f / D_);
    float r = rsqrtf(var + 1e-5f);
    float4 s0 = *(const float4*)&s[c0], s1 = *(const float4*)&s[c0 + 4];
    float4 b0 = *(const float4*)&bb[c0], b1 = *(const float4*)&bb[c0 + 4];
    u16* hr = h + (size_t)row * D_;
    f32x4 o0, o1;
    o0[0] = d0 * r * s0.x + b0.x; o0[1] = d1 * r * s0.y + b0.y;
    o0[2] = d2 * r * s0.z + b0.z; o0[3] = d3 * r * s0.w + b0.w;
    o1[0] = d4 * r * s1.x + b1.x; o1[1] = d5 * r * s1.y + b1.y;
    o1[2] = d6 * r * s1.z + b1.z; o1[3] = d7 * r * s1.w + b1.w;
    *(u16x4*)&hr[c0] = pack4(o0);
    *(u16x4*)&hr[c0 + 4] = pack4(o1);
}

// ================= host =================
extern "C" void kernel_launch(void* const* d_in, const int* in_sizes, int n_in,
                              void* d_out, int out_size, void* d_ws, size_t ws_size,
                              hipStream_t stream)
{
    (void)in_sizes; (void)n_in; (void)out_size;
    const float* Wq  = (const float*)d_in[2];
    const float* Wk  = (const float*)d_in[3];
    const float* Wv  = (const float*)d_in[4];
    const float* bq  = (const float*)d_in[5];
    const float* bk  = (const float*)d_in[6];
    const float* bv  = (const float*)d_in[7];
    const float* Wo  = (const float*)d_in[8];
    const float* bo  = (const float*)d_in[9];
    const float* ln1_s = (const float*)d_in[10];
    const float* ln1_b = (const float*)d_in[11];
    const float* ln2_s = (const float*)d_in[12];
    const float* ln2_b = (const float*)d_in[13];
    const float* W1  = (const float*)d_in[14];
    const float* b1  = (const float*)d_in[15];
    const float* W2  = (const float*)d_in[16];
    const float* b2  = (const float*)d_in[17];
    const float* Wout = (const float*)d_in[18];
    const float* bout = (const float*)d_in[19];
    const int* input_ids  = (const int*)d_in[20];
    const int* target_ids = (const int*)d_in[21];
    float* out = (float*)d_out;

    // ---- workspace carve ----
    char* wsb = (char*)d_ws;
    size_t off = 0;
    auto alloc = [&](size_t bytes) -> void* {
        off = (off + 255) & ~(size_t)255;
        void* p = wsb + off; off += bytes; return p;
    };
    u16* wqkvT = (u16*)alloc((size_t)4 * 1536 * D_ * 2);
    u16* woT   = (u16*)alloc((size_t)4 * D_ * D_ * 2);
    u16* w1T   = (u16*)alloc((size_t)4 * D_ * F_ * 2);
    u16* w2T   = (u16*)alloc((size_t)4 * D_ * F_ * 2);
    u16* woutT = (u16*)alloc((size_t)V_ * D_ * 2);
    u16* G_b   = (u16*)alloc((size_t)D_ * D_ * 2);
    u16* H2_b  = (u16*)alloc((size_t)D_ * D_ * 2);
    float* qkvb = (float*)alloc((size_t)4 * 1536 * 4);
    float* bufB = (float*)alloc((size_t)MD_ * 4);
    u16* h_b    = (u16*)alloc((size_t)MD_ * 2);
    u16* gelu_b = (u16*)alloc((size_t)MF_ * 2);
    u16* x16_b  = (u16*)alloc((size_t)MD_ * 2);
    float* cvec = (float*)alloc(D_ * 4);
    int* tcl    = (int*)alloc(M_ * 4);
    size_t uStart = (off + 255) & ~(size_t)255;
    // phase G (precompute)
    off = uStart;
    u16* woutD   = (u16*)alloc((size_t)V_ * D_ * 2);
    float* Gpart = (float*)alloc((size_t)16 * D_ * D_ * 4);
    size_t endG = off;
    // phase attention
    off = uStart;
    u16* q_b   = (u16*)alloc((size_t)MD_ * 2);
    u16* k_b   = (u16*)alloc((size_t)MD_ * 2);
    u16* v_b   = (u16*)alloc((size_t)MD_ * 2);
    u16* ctx_b = (u16*)alloc((size_t)MD_ * 2);
    size_t endA = off;
    // phase tail
    off = uStart;
    float* xA  = (float*)alloc((size_t)MD_ * 4);
    float* xB  = (float*)alloc((size_t)MD_ * 4);
    float* eb  = (float*)alloc((size_t)MD_ * 4);
    float* ec  = (float*)alloc((size_t)MD_ * 4);
    u16* xA_b  = (u16*)alloc((size_t)MD_ * 2);
    u16* xB_b  = (u16*)alloc((size_t)MD_ * 2);
    u16* xC_b  = (u16*)alloc((size_t)MD_ * 2);
    u16* eb_b  = (u16*)alloc((size_t)MD_ * 2);
    size_t endT = off;
    size_t need = endG > endA ? endG : endA;
    if (endT > need) need = endT;
    if (need > ws_size) return;

    dim3 blk(256);
    const long NL = 0;
    #define GZ nullptr, nullptr, nullptr, nullptr, nullptr, nullptr, nullptr

    // ---- precompute ----
    mega_prep<<<dim3(5121), blk, 0, stream>>>(Wq, Wk, Wv, Wo, W1, W2, Wout,
        bq, bk, bv, target_ids, wqkvT, woT, w1T, w2T, woutT, woutD, qkvb, tcl);
    // G = Wout @ Wout^T, split-K 16 x 1024
    mfma_gemm<128, 128, 64, 4, 4, E_F32><<<dim3(4, 4, 16), blk, 0, stream>>>(
        woutD, woutD, Gpart, nullptr, nullptr, nullptr, nullptr, 1024, V_, V_, D_,
        (long)D_ * D_, 1024, 1.f, GZ);
    gredcvec<<<dim3(1152), blk, 0, stream>>>(Gpart, G_b, woutD, bout, cvec);
    // H2 = W2[3]^T @ W2[3]  (from w2T, NT form)
    mfma_gemm<32, 64, 64, 1, 2, E_BF16><<<dim3(8, 16, 1), blk, 0, stream>>>(
        w2T + (size_t)3 * D_ * F_, w2T + (size_t)3 * D_ * F_, nullptr, H2_b,
        nullptr, nullptr, nullptr, F_, F_, F_, D_, NL, NL, 1.f, GZ);

    // ---- forward sweep ----
    embed_kernel<<<dim3(512), blk, 0, stream>>>((const float4*)d_in[0], (const float4*)d_in[1],
                                                input_ids, (float4*)bufB);
    for (int b = 0; b < 4; ++b) {
        const size_t wDD = (size_t)b * D_ * D_, wDF = (size_t)b * D_ * F_;
        ln_fwd_kernel<<<dim3(M_ / 4), blk, 0, stream>>>(bufB, ln1_s + b * D_, ln1_b + b * D_, h_b);
        mfma_gemm<64, 64, 64, 2, 2, E_QKV3><<<dim3(24, 16, 1), blk, 0, stream>>>(
            h_b, wqkvT + (size_t)b * 1536 * 512, nullptr, q_b, k_b, v_b,
            qkvb + b * 1536, D_, D_, D_, 0, NL, NL, 1.f, GZ);
        flash_attn<<<dim3(16, 16), dim3(128), 0, stream>>>(q_b, k_b, v_b, ctx_b);
        mfma_gemm<32, 64, 64, 1, 2, E_F32><<<dim3(8, 32, 1), blk, 0, stream>>>(
            ctx_b, woT + wDD, bufB, nullptr, nullptr, nullptr, bo + b * D_,
            D_, D_, D_, D_, NL, NL, 1.f, GZ);
        ln_fwd_kernel<<<dim3(M_ / 4), blk, 0, stream>>>(bufB, ln2_s + b * D_, ln2_b + b * D_, h_b);
        mfma_gemm<64, 64, 64, 2, 2, E_GELU><<<dim3(32, 16, 1), blk, 0, stream>>>(
            h_b, w1T + wDF, nullptr, gelu_b, nullptr, nullptr, b1 + b * F_,
            D_, D_, D_, F_, NL, NL, 1.f, GZ);
        mfma_gemm<32, 64, 64, 1, 2, E_F32><<<dim3(8, 32, 1), blk, 0, stream>>>(
            gelu_b, w2T + wDF, bufB, (b == 3) ? x16_b : nullptr, nullptr, nullptr, b2 + b * D_,
            F_, F_, F_, D_, NL, NL, 1.f, GZ);
    }
    // x16 f32 = bufB, x16 bf16 = x16_b

    // ---- PC tail ----
    mfma_gemm<32, 64, 64, 1, 2, E_TD><<<dim3(8, 32, 1), blk, 0, stream>>>(
        x16_b, G_b, xA, xA_b, nullptr, nullptr, nullptr, D_, D_, D_, D_, NL, NL, 1.f,
        bufB, nullptr, cvec, woutT, tcl, eb, eb_b);
    mfma_gemm<32, 64, 64, 1, 2, E_TD><<<dim3(8, 32, 1), blk, 0, stream>>>(
        xA_b, G_b, xB, xB_b, nullptr, nullptr, nullptr, D_, D_, D_, D_, NL, NL, 1.f,
        xA, eb, cvec, woutT, tcl, nullptr, nullptr);
    mfma_gemm<32, 64, 64, 1, 2, E_EC2><<<dim3(8, 32, 1), blk, 0, stream>>>(
        eb_b, H2_b, ec, nullptr, nullptr, nullptr, nullptr, D_, D_, D_, D_, NL, NL, 1.f,
        xB, bufB, nullptr, nullptr, nullptr, nullptr, nullptr);
    mfma_gemm<32, 64, 64, 1, 2, E_TD><<<dim3(8, 32, 1), blk, 0, stream>>>(
        xB_b, G_b, nullptr, xC_b, nullptr, nullptr, nullptr, D_, D_, D_, D_, NL, NL, 1.f,
        xB, ec, cvec, woutT, tcl, nullptr, nullptr);
    // final: out = xC @ Wout + bout (128x128 tile, BK=32, 1024 blocks, 3/CU)
    mfma_gemm<128, 128, 32, 4, 4, E_OUT><<<dim3(128, 8, 1), blk, 0, stream>>>(
        xC_b, woutT, out, nullptr, nullptr, nullptr, bout, D_, D_, D_, V_, NL, NL, 1.f, GZ);
    #undef GZ
}